// Round 4
// baseline (3384.179 us; speedup 1.0000x reference)
//
#include <hip/hip_runtime.h>
#include <hip/hip_bf16.h>
#include <math.h>

// Problem dims (fixed)
#define BDIM 4
#define TDIM 1024
#define DDIM 1024
#define DH   128
#define NELEM ((size_t)BDIM * TDIM * DDIM)   // 4,194,304

// ---------------------------------------------------------------------------
// GEMM: C[4096 x 1024] = A[4096 x 1024] @ B[1024 x 1024], all row-major.
// fp32/u8 data, fp64 accumulation (downstream spike thresholds are
// flip-sensitive; f64 puts us ~1e-13 from exact, inside the refs' agreement).
// BM=128 BN=64 BK=16, 256 threads, 8x4 micro-tile. EPI=1 -> C += A@B.
// AU8=1 -> A is uint8 (spike matrix, values 0/1).
// ---------------------------------------------------------------------------
constexpr int GM = 4096, GN = 1024, GK = 1024;
constexpr int BM = 128, BN = 64, BK = 16;

template<int EPI, int AU8>
__global__ __launch_bounds__(256)
void gemm_k(const void* __restrict__ Av, const float* __restrict__ Bm,
            float* __restrict__ C) {
  __shared__ float As[BK][BM + 4];   // transposed A tile
  __shared__ float Bs[BK][BN + 4];
  const int tid  = threadIdx.x;
  const int row0 = blockIdx.y * BM;
  const int col0 = blockIdx.x * BN;

  const int arow = tid >> 2;          // 0..63
  const int ak   = (tid & 3) << 2;    // 0,4,8,12
  const int brow = tid >> 4;          // 0..15
  const int bc   = (tid & 15) << 2;   // 0..60
  const int ty   = tid >> 4;          // 0..15
  const int tx   = tid & 15;          // 0..15

  double acc[8][4];
#pragma unroll
  for (int i = 0; i < 8; ++i)
#pragma unroll
    for (int j = 0; j < 4; ++j) acc[i][j] = 0.0;

  const float* Bp = Bm + (size_t)brow * GN + col0 + bc;

  for (int k0 = 0; k0 < GK; k0 += BK) {
    float4 a0, a1;
    if (AU8) {
      const uint8_t* Ap = (const uint8_t*)Av + (size_t)(row0 + arow) * GK + ak + k0;
      const uchar4 u0 = *(const uchar4*)Ap;
      const uchar4 u1 = *(const uchar4*)(Ap + (size_t)64 * GK);
      a0 = make_float4((float)u0.x, (float)u0.y, (float)u0.z, (float)u0.w);
      a1 = make_float4((float)u1.x, (float)u1.y, (float)u1.z, (float)u1.w);
    } else {
      const float* Ap = (const float*)Av + (size_t)(row0 + arow) * GK + ak + k0;
      a0 = *(const float4*)Ap;
      a1 = *(const float4*)(Ap + (size_t)64 * GK);
    }
    const float4 b0 = *(const float4*)(Bp + (size_t)k0 * GN);
    __syncthreads();
    As[ak + 0][arow] = a0.x; As[ak + 1][arow] = a0.y;
    As[ak + 2][arow] = a0.z; As[ak + 3][arow] = a0.w;
    As[ak + 0][arow + 64] = a1.x; As[ak + 1][arow + 64] = a1.y;
    As[ak + 2][arow + 64] = a1.z; As[ak + 3][arow + 64] = a1.w;
    *(float4*)&Bs[brow][bc] = b0;
    __syncthreads();
#pragma unroll
    for (int kk = 0; kk < BK; ++kk) {
      const float4 a0r = *(const float4*)&As[kk][ty * 8];
      const float4 a1r = *(const float4*)&As[kk][ty * 8 + 4];
      const float4 brr = *(const float4*)&Bs[kk][tx * 4];
      const double da[8] = {(double)a0r.x, (double)a0r.y, (double)a0r.z, (double)a0r.w,
                            (double)a1r.x, (double)a1r.y, (double)a1r.z, (double)a1r.w};
      const double db[4] = {(double)brr.x, (double)brr.y, (double)brr.z, (double)brr.w};
#pragma unroll
      for (int i = 0; i < 8; ++i)
#pragma unroll
        for (int j = 0; j < 4; ++j)
          acc[i][j] = fma(da[i], db[j], acc[i][j]);
    }
  }
#pragma unroll
  for (int i = 0; i < 8; ++i) {
    float* cp = C + (size_t)(row0 + ty * 8 + i) * GN + col0 + tx * 4;
    float4 v;
    if (EPI == 1) {
      const float4 o = *(const float4*)cp;
      v.x = (float)(acc[i][0] + (double)o.x);
      v.y = (float)(acc[i][1] + (double)o.y);
      v.z = (float)(acc[i][2] + (double)o.z);
      v.w = (float)(acc[i][3] + (double)o.w);
    } else {
      v.x = (float)acc[i][0]; v.y = (float)acc[i][1];
      v.z = (float)acc[i][2]; v.w = (float)acc[i][3];
    }
    *(float4*)cp = v;
  }
}

// ---------------------------------------------------------------------------
// Elementwise kernels (float4, 1 f4/thread, grid = NELEM/4/256 = 4096)
// ---------------------------------------------------------------------------
__device__ __forceinline__ float sigf(float z) { return 1.0f / (1.0f + expf(-z)); }

// gated = x * (0.5*sigmoid(L + bg) + 0.5)
__global__ __launch_bounds__(256)
void gate_kernel(const float* __restrict__ x, const float* __restrict__ L,
                 const float* __restrict__ bg, float* __restrict__ out) {
  const int i4 = blockIdx.x * 256 + threadIdx.x;
  const float4 xv = ((const float4*)x)[i4];
  const float4 lv = ((const float4*)L)[i4];
  const float4 bv = ((const float4*)bg)[i4 & 255];
  float4 r;
  r.x = xv.x * (0.5f * sigf(lv.x + bv.x) + 0.5f);
  r.y = xv.y * (0.5f * sigf(lv.y + bv.y) + 0.5f);
  r.z = xv.z * (0.5f * sigf(lv.z + bv.z) + 0.5f);
  r.w = xv.w * (0.5f * sigf(lv.w + bv.w) + 0.5f);
  ((float4*)out)[i4] = r;
}

// out = a * (1 + tanh(c))
__global__ __launch_bounds__(256)
void mod_kernel(const float* __restrict__ a, const float* __restrict__ c,
                float* __restrict__ out) {
  const int i4 = blockIdx.x * 256 + threadIdx.x;
  const float4 av = ((const float4*)a)[i4];
  const float4 cv = ((const float4*)c)[i4];
  float4 r;
  r.x = av.x * (1.0f + tanhf(cv.x));
  r.y = av.y * (1.0f + tanhf(cv.y));
  r.z = av.z * (1.0f + tanhf(cv.z));
  r.w = av.w * (1.0f + tanhf(cv.w));
  ((float4*)out)[i4] = r;
}

// out = sigmoid(r) * wkv   (out may alias wkv: same-index elementwise)
__global__ __launch_bounds__(256)
void rmul_kernel(const float* __restrict__ rr, const float* __restrict__ wkv,
                 float* __restrict__ out) {
  const int i4 = blockIdx.x * 256 + threadIdx.x;
  const float4 rv = ((const float4*)rr)[i4];
  const float4 wv = ((const float4*)wkv)[i4];
  float4 r;
  r.x = sigf(rv.x) * wv.x;
  r.y = sigf(rv.y) * wv.y;
  r.z = sigf(rv.z) * wv.z;
  r.w = sigf(rv.w) * wv.w;
  ((float4*)out)[i4] = r;
}

// ---------------------------------------------------------------------------
// LIF scans: one thread per (b,d) channel, serial over T. Soft reset.
// f32 with the reference's exact op order. Two variants:
//   lif_u8: spikes -> uint8 buffer (stage 2)
//   lif_ip: spikes -> f32, in-place over the input (stage 6)
// ---------------------------------------------------------------------------
__global__ __launch_bounds__(256)
void lif_u8_kernel(const float* __restrict__ x, uint8_t* __restrict__ s) {
  const int c = blockIdx.x * 256 + threadIdx.x;      // 0..4095
  const size_t off = (size_t)(c >> 10) * TDIM * DDIM + (c & 1023);
  const float* xp = x + off;
  uint8_t* sp = s + off;
  float u = 0.f;
  for (int t = 0; t < TDIM; ++t) {
    const float xt = xp[(size_t)t * DDIM];
    u = __fadd_rn(__fmul_rn(0.9f, u), xt);
    const bool fire = (u >= 1.0f);
    sp[(size_t)t * DDIM] = fire ? 1 : 0;
    if (fire) u -= 1.0f;
  }
}

__global__ __launch_bounds__(256)
void lif_ip_kernel(float* __restrict__ x) {
  const int c = blockIdx.x * 256 + threadIdx.x;
  const size_t off = (size_t)(c >> 10) * TDIM * DDIM + (c & 1023);
  float* xp = x + off;
  float u = 0.f;
  for (int t = 0; t < TDIM; ++t) {
    const float xt = xp[(size_t)t * DDIM];
    u = __fadd_rn(__fmul_rn(0.9f, u), xt);
    const float sv = (u >= 1.0f) ? 1.0f : 0.0f;
    xp[(size_t)t * DDIM] = sv;
    u -= sv;
  }
}

// ---------------------------------------------------------------------------
// RWKV numerically-stable recurrence: one thread per (b,d) channel, f32.
// out may alias k (each element read before written by the same thread).
// ---------------------------------------------------------------------------
__global__ __launch_bounds__(256)
void rwkv_kernel(const float* __restrict__ k, const float* __restrict__ v,
                 const float* __restrict__ wd, const float* __restrict__ uf,
                 float* __restrict__ out) {
  const int c = blockIdx.x * 256 + threadIdx.x;
  const int d = c & 1023;
  const size_t off = (size_t)(c >> 10) * TDIM * DDIM + d;
  const float* kp = k + off;
  const float* vp = v + off;
  float* op = out + off;
  const float w = expf(wd[d]);
  const float u = uf[d];
  float aa = 0.f, bb = 0.f, pp = -1e30f;
  for (int t = 0; t < TDIM; ++t) {
    const float kt = kp[(size_t)t * DDIM];
    const float vt = vp[(size_t)t * DDIM];
    const float ww = __fadd_rn(u, kt);
    const float p  = fmaxf(pp, ww);
    float e1 = expf(__fsub_rn(pp, p));
    float e2 = expf(__fsub_rn(ww, p));
    const float num = __fadd_rn(__fmul_rn(e1, aa), __fmul_rn(e2, vt));
    const float den = __fadd_rn(__fmul_rn(e1, bb), e2);
    op[(size_t)t * DDIM] = num / den;
    const float ww2 = __fsub_rn(pp, w);
    const float p2  = fmaxf(ww2, kt);
    e1 = expf(__fsub_rn(ww2, p2));
    e2 = expf(__fsub_rn(kt, p2));
    aa = __fadd_rn(__fmul_rn(e1, aa), __fmul_rn(e2, vt));
    bb = __fadd_rn(__fmul_rn(e1, bb), e2);
    pp = p2;
  }
}

// ---------------------------------------------------------------------------
// Flash attention (fp32 data, fp64 dot-product accumulation, non-causal).
// Grid (qtiles=16, H=8, B=4), 256 threads. Layout: [b][t][h*128 + d].
// O MAY ALIAS Q: each block reads only its own Q region (staged fully into
// LDS in the prologue) and writes exactly that region in the epilogue;
// K/V are separate buffers.
// ---------------------------------------------------------------------------
__global__ __launch_bounds__(256)
void flash_attn(const float* __restrict__ Q, const float* __restrict__ K,
                const float* __restrict__ V, float* __restrict__ O) {
  __shared__ float Qs[64][DH + 4];
  __shared__ float Ks[64][DH + 4];
  __shared__ float Vs[64][DH + 4];
  __shared__ float Ps[64][64 + 4];
  const int tid = threadIdx.x;
  const int qt = blockIdx.x, h = blockIdx.y, b = blockIdx.z;
  const size_t base = ((size_t)b * TDIM) * DDIM + (size_t)h * DH;
  const float* Qg = Q + base + (size_t)(qt * 64) * DDIM;
#pragma unroll
  for (int q2 = 0; q2 < 8; ++q2) {
    const int f = tid + q2 * 256;
    const int r = f >> 5, c4 = (f & 31) << 2;
    *(float4*)&Qs[r][c4] = *(const float4*)(Qg + (size_t)r * DDIM + c4);
  }
  const int ty = tid >> 4, tx = tid & 15;
  const int r0 = ty * 4;          // 4 query rows per thread
  const int cx = tx * 8;          // 8 output cols per thread
  float m[4] = {-INFINITY, -INFINITY, -INFINITY, -INFINITY};
  float l[4] = {0.f, 0.f, 0.f, 0.f};
  double o[4][8];
#pragma unroll
  for (int i = 0; i < 4; ++i)
#pragma unroll
    for (int j = 0; j < 8; ++j) o[i][j] = 0.0;
  const float SQRTDH = 11.313708498984761f;   // sqrt(128), ref divides by this

  for (int kt0 = 0; kt0 < TDIM; kt0 += 64) {
    __syncthreads();              // prev PV done (and Qs staged on iter 0)
    const float* Kg = K + base + (size_t)kt0 * DDIM;
    const float* Vg = V + base + (size_t)kt0 * DDIM;
#pragma unroll
    for (int q2 = 0; q2 < 8; ++q2) {
      const int f = tid + q2 * 256;
      const int r = f >> 5, c4 = (f & 31) << 2;
      *(float4*)&Ks[r][c4] = *(const float4*)(Kg + (size_t)r * DDIM + c4);
      *(float4*)&Vs[r][c4] = *(const float4*)(Vg + (size_t)r * DDIM + c4);
    }
    __syncthreads();
    // S = Q K^T : thread owns rows r0..r0+3, cols {tx, tx+16, tx+32, tx+48}
    double s[4][4];
#pragma unroll
    for (int i = 0; i < 4; ++i)
#pragma unroll
      for (int j = 0; j < 4; ++j) s[i][j] = 0.0;
    for (int kd = 0; kd < DH; kd += 4) {
      float4 qa[4], kb[4];
#pragma unroll
      for (int i = 0; i < 4; ++i) qa[i] = *(const float4*)&Qs[r0 + i][kd];
#pragma unroll
      for (int j = 0; j < 4; ++j) kb[j] = *(const float4*)&Ks[tx + 16 * j][kd];
#pragma unroll
      for (int i = 0; i < 4; ++i) {
        const double qx = qa[i].x, qy = qa[i].y, qz = qa[i].z, qw = qa[i].w;
#pragma unroll
        for (int j = 0; j < 4; ++j) {
          s[i][j] = fma(qx, (double)kb[j].x, s[i][j]);
          s[i][j] = fma(qy, (double)kb[j].y, s[i][j]);
          s[i][j] = fma(qz, (double)kb[j].z, s[i][j]);
          s[i][j] = fma(qw, (double)kb[j].w, s[i][j]);
        }
      }
    }
    // online softmax in f32 (matches ref's f32 softmax given accurate scores)
#pragma unroll
    for (int i = 0; i < 4; ++i) {
      const float sc0 = (float)s[i][0] / SQRTDH, sc1 = (float)s[i][1] / SQRTDH;
      const float sc2 = (float)s[i][2] / SQRTDH, sc3 = (float)s[i][3] / SQRTDH;
      float mx = fmaxf(fmaxf(sc0, sc1), fmaxf(sc2, sc3));
      mx = fmaxf(mx, __shfl_xor(mx, 1, 16));
      mx = fmaxf(mx, __shfl_xor(mx, 2, 16));
      mx = fmaxf(mx, __shfl_xor(mx, 4, 16));
      mx = fmaxf(mx, __shfl_xor(mx, 8, 16));
      const float mn = fmaxf(m[i], mx);
      const float rf = expf(m[i] - mn);       // exp(-inf)=0 on first tile
      const float p0 = expf(sc0 - mn), p1 = expf(sc1 - mn);
      const float p2 = expf(sc2 - mn), p3 = expf(sc3 - mn);
      float ps = (p0 + p1) + (p2 + p3);
      ps += __shfl_xor(ps, 1, 16);
      ps += __shfl_xor(ps, 2, 16);
      ps += __shfl_xor(ps, 4, 16);
      ps += __shfl_xor(ps, 8, 16);
      l[i] = l[i] * rf + ps;
      m[i] = mn;
      const double rfd = (double)rf;
#pragma unroll
      for (int jj = 0; jj < 8; ++jj) o[i][jj] *= rfd;
      Ps[r0 + i][tx]      = p0;
      Ps[r0 + i][tx + 16] = p1;
      Ps[r0 + i][tx + 32] = p2;
      Ps[r0 + i][tx + 48] = p3;
    }
    __syncthreads();
    // O += P @ V (f64 accumulate)
    for (int s4 = 0; s4 < 64; s4 += 4) {
      double pav[4][4];
#pragma unroll
      for (int i = 0; i < 4; ++i) {
        const float4 pa = *(const float4*)&Ps[r0 + i][s4];
        pav[i][0] = pa.x; pav[i][1] = pa.y; pav[i][2] = pa.z; pav[i][3] = pa.w;
      }
#pragma unroll
      for (int u2 = 0; u2 < 4; ++u2) {
        const float4 v0 = *(const float4*)&Vs[s4 + u2][cx];
        const float4 v1 = *(const float4*)&Vs[s4 + u2][cx + 4];
        const double vx0 = v0.x, vy0 = v0.y, vz0 = v0.z, vw0 = v0.w;
        const double vx1 = v1.x, vy1 = v1.y, vz1 = v1.z, vw1 = v1.w;
#pragma unroll
        for (int i = 0; i < 4; ++i) {
          const double p_ = pav[i][u2];
          o[i][0] = fma(p_, vx0, o[i][0]);
          o[i][1] = fma(p_, vy0, o[i][1]);
          o[i][2] = fma(p_, vz0, o[i][2]);
          o[i][3] = fma(p_, vw0, o[i][3]);
          o[i][4] = fma(p_, vx1, o[i][4]);
          o[i][5] = fma(p_, vy1, o[i][5]);
          o[i][6] = fma(p_, vz1, o[i][6]);
          o[i][7] = fma(p_, vw1, o[i][7]);
        }
      }
    }
  }
  float* Og = O + base + (size_t)(qt * 64) * DDIM;
#pragma unroll
  for (int i = 0; i < 4; ++i) {
    const double invl = 1.0 / (double)l[i];
    float4 v0, v1;
    v0.x = (float)(o[i][0] * invl); v0.y = (float)(o[i][1] * invl);
    v0.z = (float)(o[i][2] * invl); v0.w = (float)(o[i][3] * invl);
    v1.x = (float)(o[i][4] * invl); v1.y = (float)(o[i][5] * invl);
    v1.z = (float)(o[i][6] * invl); v1.w = (float)(o[i][7] * invl);
    *(float4*)(Og + (size_t)(r0 + i) * DDIM + cx)     = v0;
    *(float4*)(Og + (size_t)(r0 + i) * DDIM + cx + 4) = v1;
  }
}

// ---------------------------------------------------------------------------
// Final: y = lif2(f32) + spikes2(u8); LayerNorm; ***float32*** store.
// (Reference output dtype is float32 — the earlier bf16 store half-filled
//  d_out and was the bit-identical absmax=8.205 failure across rounds 1-3.)
// One block (256 thr) per (b,t) row.
// ---------------------------------------------------------------------------
__global__ __launch_bounds__(256)
void ln_kernel(const float* __restrict__ a, const uint8_t* __restrict__ s8,
               const float* __restrict__ gamma, const float* __restrict__ beta,
               float* __restrict__ out) {
  const int row = blockIdx.x;
  const int tid = threadIdx.x;
  const size_t base = (size_t)row * DDIM;
  const float4 av = *(const float4*)(a + base + tid * 4);
  const uchar4 sv = *(const uchar4*)(s8 + base + tid * 4);
  const float y0 = av.x + (float)sv.x, y1 = av.y + (float)sv.y;
  const float y2 = av.z + (float)sv.z, y3 = av.w + (float)sv.w;
  float s = (y0 + y1) + (y2 + y3);
  float q = (y0 * y0 + y1 * y1) + (y2 * y2 + y3 * y3);
#pragma unroll
  for (int off = 1; off < 64; off <<= 1) {
    s += __shfl_xor(s, off);
    q += __shfl_xor(q, off);
  }
  __shared__ float red[8];
  const int wid = tid >> 6;
  if ((tid & 63) == 0) { red[wid * 2] = s; red[wid * 2 + 1] = q; }
  __syncthreads();
  const float ts = (red[0] + red[2]) + (red[4] + red[6]);
  const float tq = (red[1] + red[3]) + (red[5] + red[7]);
  const float mu  = ts * (1.0f / 1024.0f);
  const float var = tq * (1.0f / 1024.0f) - mu * mu;
  const float rs  = 1.0f / sqrtf(var + 1e-5f);
  const int d = tid * 4;
  const float4 gv  = *(const float4*)(gamma + d);
  const float4 btv = *(const float4*)(beta + d);
  float4 r;
  r.x = (y0 - mu) * rs * gv.x + btv.x;
  r.y = (y1 - mu) * rs * gv.y + btv.y;
  r.z = (y2 - mu) * rs * gv.z + btv.z;
  r.w = (y3 - mu) * rs * gv.w + btv.w;
  *(float4*)(out + base + d) = r;
}

// ---------------------------------------------------------------------------
// Workspace budget: 3 f32 buffers (A,C,D) + 1 u8 spike buffer = 54.5 MB.
// ---------------------------------------------------------------------------
extern "C" void kernel_launch(void* const* d_in, const int* in_sizes, int n_in,
                              void* d_out, int out_size, void* d_ws, size_t ws_size,
                              hipStream_t stream) {
  const float* x       = (const float*)d_in[0];
  const float* context = (const float*)d_in[1];
  const float* Wg  = (const float*)d_in[2];
  const float* bg  = (const float*)d_in[3];
  const float* Wc  = (const float*)d_in[4];
  const float* Wq  = (const float*)d_in[5];
  const float* Wk  = (const float*)d_in[6];
  const float* Wv  = (const float*)d_in[7];
  const float* Wo  = (const float*)d_in[8];
  const float* Wm  = (const float*)d_in[9];
  const float* rWk = (const float*)d_in[10];
  const float* rWv = (const float*)d_in[11];
  const float* rWr = (const float*)d_in[12];
  const float* rWo = (const float*)d_in[13];
  const float* wd  = (const float*)d_in[14];
  const float* uf  = (const float*)d_in[15];
  const float* gamma = (const float*)d_in[16];
  const float* beta  = (const float*)d_in[17];
  float* out = (float*)d_out;   // reference output dtype = float32

  float* w  = (float*)d_ws;
  float*   bA = w;                          // f32 scratch
  float*   bC = w + 1 * NELEM;              // f32 scratch
  float*   bD = w + 2 * NELEM;              // f32 scratch
  uint8_t* bS = (uint8_t*)(w + 3 * NELEM);  // spikes2 as u8 (live to the end)

  const dim3 gg(GN / BN, GM / BM);   // (16, 32)
  const dim3 ew(4096);               // elementwise: NELEM/4/256
  const dim3 fa(16, 8, 4);

  // Stage 1: thalamic gate
  gemm_k<0,0><<<gg, 256, 0, stream>>>(x, Wg, bA);
  gemm_k<1,0><<<gg, 256, 0, stream>>>(context, Wc, bA);
  gate_kernel<<<ew, 256, 0, stream>>>(x, bA, bg, bA);
  // Stage 2: LIF -> spikes2 (u8)
  lif_u8_kernel<<<16, 256, 0, stream>>>(bA, bS);
  // Stage 3: spike self-attention (O written in-place over Q)
  gemm_k<0,1><<<gg, 256, 0, stream>>>(bS, Wq, bA);
  gemm_k<0,1><<<gg, 256, 0, stream>>>(bS, Wk, bC);
  gemm_k<0,1><<<gg, 256, 0, stream>>>(bS, Wv, bD);
  flash_attn<<<fa, 256, 0, stream>>>(bA, bC, bD, bA);
  gemm_k<0,0><<<gg, 256, 0, stream>>>(bA, Wo, bC);         // bC = attn_out@Wo
  // Stage 4: apical modulation
  gemm_k<0,0><<<gg, 256, 0, stream>>>(context, Wm, bA);
  mod_kernel<<<ew, 256, 0, stream>>>(bC, bA, bD);          // bD = modulated
  // Stage 5: RWKV
  gemm_k<0,0><<<gg, 256, 0, stream>>>(bD, rWk, bA);        // bA = k
  gemm_k<0,0><<<gg, 256, 0, stream>>>(bD, rWv, bC);        // bC = v
  rwkv_kernel<<<16, 256, 0, stream>>>(bA, bC, wd, uf, bA); // bA = wkv (in-place)
  gemm_k<0,0><<<gg, 256, 0, stream>>>(bD, rWr, bC);        // bC = r (pre-sigmoid)
  rmul_kernel<<<ew, 256, 0, stream>>>(bC, bA, bA);         // bA = sig(r)*wkv
  gemm_k<0,0><<<gg, 256, 0, stream>>>(bA, rWo, bC);        // bC = recurrent
  // Stage 6: output LIF (in-place) + residual + LayerNorm
  lif_ip_kernel<<<16, 256, 0, stream>>>(bC);
  ln_kernel<<<4096, 256, 0, stream>>>(bC, bS, gamma, beta, out);
}

// Round 5
// 2220.493 us; speedup vs baseline: 1.5241x; 1.5241x over previous
//
#include <hip/hip_runtime.h>
#include <hip/hip_bf16.h>
#include <math.h>

// Problem dims (fixed)
#define BDIM 4
#define TDIM 1024
#define DDIM 1024
#define DH   128
#define NELEM ((size_t)BDIM * TDIM * DDIM)   // 4,194,304

// ---------------------------------------------------------------------------
// GEMM: C[4096 x 1024] = A[4096 x 1024] @ B[1024 x 1024], all row-major.
// f32 data & accumulation (sequential fmaf over k — bit-identical op order to
// the round-1 kernel, which produced spike-identical results to f64: all
// threshold margins > ~1e-4, so f32 is flip-safe).
// BM=BN=128, BK=16, 256 threads, 8x8 micro-tile, register-prefetch staging.
// EPI=1 -> C += A@B.  AU8=1 -> A is uint8 (spike matrix, 0/1).
// ---------------------------------------------------------------------------
constexpr int GM = 4096, GN = 1024, GK = 1024;
constexpr int BM = 128, BN = 128, BK = 16;

template<int EPI, int AU8>
__global__ __launch_bounds__(256)
void gemm_k(const void* __restrict__ Av, const float* __restrict__ Bm,
            float* __restrict__ C) {
  __shared__ float As[BK][BM + 4];   // transposed A tile
  __shared__ float Bs[BK][BN + 4];
  const int tid  = threadIdx.x;
  const int row0 = blockIdx.y * BM;
  const int col0 = blockIdx.x * BN;

  const int arow = tid >> 1;          // 0..127
  const int ak   = (tid & 1) << 3;    // 0 or 8
  const int brow = tid >> 4;          // 0..15
  const int bc   = (tid & 15) << 3;   // 0..120
  const int ty   = tid >> 4;          // 0..15
  const int tx   = tid & 15;          // 0..15

  float acc[8][8];
#pragma unroll
  for (int i = 0; i < 8; ++i)
#pragma unroll
    for (int j = 0; j < 8; ++j) acc[i][j] = 0.f;

  const float* Bp = Bm + (size_t)brow * GN + col0 + bc;

  // prefetch k0 = 0
  float4 a0, a1, b0, b1;
  {
    if (AU8) {
      const uint8_t* Ap = (const uint8_t*)Av + (size_t)(row0 + arow) * GK + ak;
      const uchar4 u0 = *(const uchar4*)Ap;
      const uchar4 u1 = *(const uchar4*)(Ap + 4);
      a0 = make_float4((float)u0.x, (float)u0.y, (float)u0.z, (float)u0.w);
      a1 = make_float4((float)u1.x, (float)u1.y, (float)u1.z, (float)u1.w);
    } else {
      const float* Ap = (const float*)Av + (size_t)(row0 + arow) * GK + ak;
      a0 = *(const float4*)Ap;
      a1 = *(const float4*)(Ap + 4);
    }
    b0 = *(const float4*)(Bp);
    b1 = *(const float4*)(Bp + 4);
  }

  for (int k0 = 0; k0 < GK; k0 += BK) {
    __syncthreads();                    // previous compute done
    As[ak + 0][arow] = a0.x; As[ak + 1][arow] = a0.y;
    As[ak + 2][arow] = a0.z; As[ak + 3][arow] = a0.w;
    As[ak + 4][arow] = a1.x; As[ak + 5][arow] = a1.y;
    As[ak + 6][arow] = a1.z; As[ak + 7][arow] = a1.w;
    *(float4*)&Bs[brow][bc]     = b0;
    *(float4*)&Bs[brow][bc + 4] = b1;
    __syncthreads();
    const int kn = k0 + BK;
    if (kn < GK) {                      // issue next-tile loads; latency hides
      if (AU8) {                        // under the 16x64-FMA compute below
        const uint8_t* Ap = (const uint8_t*)Av + (size_t)(row0 + arow) * GK + kn + ak;
        const uchar4 u0 = *(const uchar4*)Ap;
        const uchar4 u1 = *(const uchar4*)(Ap + 4);
        a0 = make_float4((float)u0.x, (float)u0.y, (float)u0.z, (float)u0.w);
        a1 = make_float4((float)u1.x, (float)u1.y, (float)u1.z, (float)u1.w);
      } else {
        const float* Ap = (const float*)Av + (size_t)(row0 + arow) * GK + kn + ak;
        a0 = *(const float4*)Ap;
        a1 = *(const float4*)(Ap + 4);
      }
      b0 = *(const float4*)(Bp + (size_t)kn * GN);
      b1 = *(const float4*)(Bp + (size_t)kn * GN + 4);
    }
#pragma unroll
    for (int kk = 0; kk < BK; ++kk) {
      const float4 ra0 = *(const float4*)&As[kk][ty * 8];
      const float4 ra1 = *(const float4*)&As[kk][ty * 8 + 4];
      const float4 rb0 = *(const float4*)&Bs[kk][tx * 8];
      const float4 rb1 = *(const float4*)&Bs[kk][tx * 8 + 4];
      const float ra[8] = {ra0.x, ra0.y, ra0.z, ra0.w, ra1.x, ra1.y, ra1.z, ra1.w};
      const float rb[8] = {rb0.x, rb0.y, rb0.z, rb0.w, rb1.x, rb1.y, rb1.z, rb1.w};
#pragma unroll
      for (int i = 0; i < 8; ++i)
#pragma unroll
        for (int j = 0; j < 8; ++j)
          acc[i][j] = fmaf(ra[i], rb[j], acc[i][j]);
    }
  }
#pragma unroll
  for (int i = 0; i < 8; ++i) {
    float* cp = C + (size_t)(row0 + ty * 8 + i) * GN + col0 + tx * 8;
    float4 v0, v1;
    v0.x = acc[i][0]; v0.y = acc[i][1]; v0.z = acc[i][2]; v0.w = acc[i][3];
    v1.x = acc[i][4]; v1.y = acc[i][5]; v1.z = acc[i][6]; v1.w = acc[i][7];
    if (EPI == 1) {
      const float4 o0 = *(const float4*)cp;
      const float4 o1 = *(const float4*)(cp + 4);
      v0.x += o0.x; v0.y += o0.y; v0.z += o0.z; v0.w += o0.w;
      v1.x += o1.x; v1.y += o1.y; v1.z += o1.z; v1.w += o1.w;
    }
    *(float4*)cp       = v0;
    *(float4*)(cp + 4) = v1;
  }
}

// ---------------------------------------------------------------------------
// Elementwise kernels (float4, 1 f4/thread, grid = NELEM/4/256 = 4096)
// ---------------------------------------------------------------------------
__device__ __forceinline__ float sigf(float z) { return 1.0f / (1.0f + expf(-z)); }

// gated = x * (0.5*sigmoid(L + bg) + 0.5)
__global__ __launch_bounds__(256)
void gate_kernel(const float* __restrict__ x, const float* __restrict__ L,
                 const float* __restrict__ bg, float* __restrict__ out) {
  const int i4 = blockIdx.x * 256 + threadIdx.x;
  const float4 xv = ((const float4*)x)[i4];
  const float4 lv = ((const float4*)L)[i4];
  const float4 bv = ((const float4*)bg)[i4 & 255];
  float4 r;
  r.x = xv.x * (0.5f * sigf(lv.x + bv.x) + 0.5f);
  r.y = xv.y * (0.5f * sigf(lv.y + bv.y) + 0.5f);
  r.z = xv.z * (0.5f * sigf(lv.z + bv.z) + 0.5f);
  r.w = xv.w * (0.5f * sigf(lv.w + bv.w) + 0.5f);
  ((float4*)out)[i4] = r;
}

// out = a * (1 + tanh(c))
__global__ __launch_bounds__(256)
void mod_kernel(const float* __restrict__ a, const float* __restrict__ c,
                float* __restrict__ out) {
  const int i4 = blockIdx.x * 256 + threadIdx.x;
  const float4 av = ((const float4*)a)[i4];
  const float4 cv = ((const float4*)c)[i4];
  float4 r;
  r.x = av.x * (1.0f + tanhf(cv.x));
  r.y = av.y * (1.0f + tanhf(cv.y));
  r.z = av.z * (1.0f + tanhf(cv.z));
  r.w = av.w * (1.0f + tanhf(cv.w));
  ((float4*)out)[i4] = r;
}

// out = sigmoid(r) * wkv   (out may alias wkv: same-index elementwise)
__global__ __launch_bounds__(256)
void rmul_kernel(const float* __restrict__ rr, const float* __restrict__ wkv,
                 float* __restrict__ out) {
  const int i4 = blockIdx.x * 256 + threadIdx.x;
  const float4 rv = ((const float4*)rr)[i4];
  const float4 wv = ((const float4*)wkv)[i4];
  float4 r;
  r.x = sigf(rv.x) * wv.x;
  r.y = sigf(rv.y) * wv.y;
  r.z = sigf(rv.z) * wv.z;
  r.w = sigf(rv.w) * wv.w;
  ((float4*)out)[i4] = r;
}

// ---------------------------------------------------------------------------
// LIF scans: one thread per (b,d) channel, serial over T. Soft reset.
// f32 with the reference's exact op order.
// ---------------------------------------------------------------------------
__global__ __launch_bounds__(256)
void lif_u8_kernel(const float* __restrict__ x, uint8_t* __restrict__ s) {
  const int c = blockIdx.x * 256 + threadIdx.x;      // 0..4095
  const size_t off = (size_t)(c >> 10) * TDIM * DDIM + (c & 1023);
  const float* xp = x + off;
  uint8_t* sp = s + off;
  float u = 0.f;
  for (int t = 0; t < TDIM; ++t) {
    const float xt = xp[(size_t)t * DDIM];
    u = __fadd_rn(__fmul_rn(0.9f, u), xt);
    const bool fire = (u >= 1.0f);
    sp[(size_t)t * DDIM] = fire ? 1 : 0;
    if (fire) u -= 1.0f;
  }
}

__global__ __launch_bounds__(256)
void lif_ip_kernel(float* __restrict__ x) {
  const int c = blockIdx.x * 256 + threadIdx.x;
  const size_t off = (size_t)(c >> 10) * TDIM * DDIM + (c & 1023);
  float* xp = x + off;
  float u = 0.f;
  for (int t = 0; t < TDIM; ++t) {
    const float xt = xp[(size_t)t * DDIM];
    u = __fadd_rn(__fmul_rn(0.9f, u), xt);
    const float sv = (u >= 1.0f) ? 1.0f : 0.0f;
    xp[(size_t)t * DDIM] = sv;
    u -= sv;
  }
}

// ---------------------------------------------------------------------------
// RWKV numerically-stable recurrence: one thread per (b,d) channel, f32.
// out may alias k (each element read before written by the same thread).
// ---------------------------------------------------------------------------
__global__ __launch_bounds__(256)
void rwkv_kernel(const float* __restrict__ k, const float* __restrict__ v,
                 const float* __restrict__ wd, const float* __restrict__ uf,
                 float* __restrict__ out) {
  const int c = blockIdx.x * 256 + threadIdx.x;
  const int d = c & 1023;
  const size_t off = (size_t)(c >> 10) * TDIM * DDIM + d;
  const float* kp = k + off;
  const float* vp = v + off;
  float* op = out + off;
  const float w = expf(wd[d]);
  const float u = uf[d];
  float aa = 0.f, bb = 0.f, pp = -1e30f;
  for (int t = 0; t < TDIM; ++t) {
    const float kt = kp[(size_t)t * DDIM];
    const float vt = vp[(size_t)t * DDIM];
    const float ww = __fadd_rn(u, kt);
    const float p  = fmaxf(pp, ww);
    float e1 = expf(__fsub_rn(pp, p));
    float e2 = expf(__fsub_rn(ww, p));
    const float num = __fadd_rn(__fmul_rn(e1, aa), __fmul_rn(e2, vt));
    const float den = __fadd_rn(__fmul_rn(e1, bb), e2);
    op[(size_t)t * DDIM] = num / den;
    const float ww2 = __fsub_rn(pp, w);
    const float p2  = fmaxf(ww2, kt);
    e1 = expf(__fsub_rn(ww2, p2));
    e2 = expf(__fsub_rn(kt, p2));
    aa = __fadd_rn(__fmul_rn(e1, aa), __fmul_rn(e2, vt));
    bb = __fadd_rn(__fmul_rn(e1, bb), e2);
    pp = p2;
  }
}

// ---------------------------------------------------------------------------
// Flash attention, f32 throughout, non-causal. Grid (16, 8, 4), 256 threads.
// Layout: [b][t][h*128 + d]. KT=32 k/v-tiles -> LDS 76.8 KB -> 2 blocks/CU.
// Next K/V tile prefetched into registers during compute.
// O MAY ALIAS Q (each block consumes only its own Q rows, staged in LDS).
// ---------------------------------------------------------------------------
#define KT 32
__global__ __launch_bounds__(256)
void flash_attn(const float* __restrict__ Q, const float* __restrict__ K,
                const float* __restrict__ V, float* __restrict__ O) {
  __shared__ float Qs[64][DH + 4];
  __shared__ float Ks[KT][DH + 4];
  __shared__ float Vs[KT][DH + 4];
  __shared__ float Ps[64][KT + 4];
  const int tid = threadIdx.x;
  const int qt = blockIdx.x, h = blockIdx.y, b = blockIdx.z;
  const size_t base = ((size_t)b * TDIM) * DDIM + (size_t)h * DH;
  const float* Qg = Q + base + (size_t)(qt * 64) * DDIM;
#pragma unroll
  for (int q2 = 0; q2 < 8; ++q2) {
    const int f = tid + q2 * 256;
    const int r = f >> 5, c4 = (f & 31) << 2;
    *(float4*)&Qs[r][c4] = *(const float4*)(Qg + (size_t)r * DDIM + c4);
  }
  // prefetch K/V tile 0 into regs: 32x128 floats / 256 thr = 4 float4 each
  const int sr = tid >> 3;            // 0..31 (row)
  const int sc = (tid & 7) << 4;      // 0,16,...,112 (col base, 4 float4)
  float4 kr[4], vr[4];
  {
    const float* Kg = K + base;
    const float* Vg = V + base;
#pragma unroll
    for (int j = 0; j < 4; ++j) {
      kr[j] = *(const float4*)(Kg + (size_t)sr * DDIM + sc + j * 4);
      vr[j] = *(const float4*)(Vg + (size_t)sr * DDIM + sc + j * 4);
    }
  }
  const int ty = tid >> 4, tx = tid & 15;
  const int r0 = ty * 4;          // 4 query rows per thread
  const int cx = tx * 8;          // 8 output cols per thread
  float m[4] = {-INFINITY, -INFINITY, -INFINITY, -INFINITY};
  float l[4] = {0.f, 0.f, 0.f, 0.f};
  float o[4][8];
#pragma unroll
  for (int i = 0; i < 4; ++i)
#pragma unroll
    for (int j = 0; j < 8; ++j) o[i][j] = 0.f;
  const float SQRTDH = 11.313708498984761f;   // sqrt(128), ref divides by this

  for (int kt0 = 0; kt0 < TDIM; kt0 += KT) {
    __syncthreads();              // prev PV done with Ks/Vs (& Qs staged)
#pragma unroll
    for (int j = 0; j < 4; ++j) {
      *(float4*)&Ks[sr][sc + j * 4] = kr[j];
      *(float4*)&Vs[sr][sc + j * 4] = vr[j];
    }
    __syncthreads();
    if (kt0 + KT < TDIM) {        // prefetch next tile; hides under compute
      const float* Kg = K + base + (size_t)(kt0 + KT) * DDIM;
      const float* Vg = V + base + (size_t)(kt0 + KT) * DDIM;
#pragma unroll
      for (int j = 0; j < 4; ++j) {
        kr[j] = *(const float4*)(Kg + (size_t)sr * DDIM + sc + j * 4);
        vr[j] = *(const float4*)(Vg + (size_t)sr * DDIM + sc + j * 4);
      }
    }
    // S = Q K^T : thread owns rows r0..r0+3, cols {tx, tx+16}
    float s[4][2];
#pragma unroll
    for (int i = 0; i < 4; ++i) { s[i][0] = 0.f; s[i][1] = 0.f; }
    for (int kd = 0; kd < DH; kd += 4) {
      float4 qa[4];
#pragma unroll
      for (int i = 0; i < 4; ++i) qa[i] = *(const float4*)&Qs[r0 + i][kd];
      const float4 kb0 = *(const float4*)&Ks[tx][kd];
      const float4 kb1 = *(const float4*)&Ks[tx + 16][kd];
#pragma unroll
      for (int i = 0; i < 4; ++i) {
        s[i][0] = fmaf(qa[i].x, kb0.x, s[i][0]);
        s[i][0] = fmaf(qa[i].y, kb0.y, s[i][0]);
        s[i][0] = fmaf(qa[i].z, kb0.z, s[i][0]);
        s[i][0] = fmaf(qa[i].w, kb0.w, s[i][0]);
        s[i][1] = fmaf(qa[i].x, kb1.x, s[i][1]);
        s[i][1] = fmaf(qa[i].y, kb1.y, s[i][1]);
        s[i][1] = fmaf(qa[i].z, kb1.z, s[i][1]);
        s[i][1] = fmaf(qa[i].w, kb1.w, s[i][1]);
      }
    }
    // online softmax (rows live in 16-lane shuffle groups)
#pragma unroll
    for (int i = 0; i < 4; ++i) {
      const float sc0 = s[i][0] / SQRTDH, sc1 = s[i][1] / SQRTDH;
      float mx = fmaxf(sc0, sc1);
      mx = fmaxf(mx, __shfl_xor(mx, 1, 16));
      mx = fmaxf(mx, __shfl_xor(mx, 2, 16));
      mx = fmaxf(mx, __shfl_xor(mx, 4, 16));
      mx = fmaxf(mx, __shfl_xor(mx, 8, 16));
      const float mn = fmaxf(m[i], mx);
      const float rf = expf(m[i] - mn);       // exp(-inf)=0 on first tile
      const float p0 = expf(sc0 - mn), p1 = expf(sc1 - mn);
      float ps = p0 + p1;
      ps += __shfl_xor(ps, 1, 16);
      ps += __shfl_xor(ps, 2, 16);
      ps += __shfl_xor(ps, 4, 16);
      ps += __shfl_xor(ps, 8, 16);
      l[i] = l[i] * rf + ps;
      m[i] = mn;
#pragma unroll
      for (int jj = 0; jj < 8; ++jj) o[i][jj] *= rf;
      Ps[r0 + i][tx]      = p0;
      Ps[r0 + i][tx + 16] = p1;
    }
    __syncthreads();
    // O += P @ V
#pragma unroll
    for (int s4 = 0; s4 < KT; s4 += 4) {
      float pav[4][4];
#pragma unroll
      for (int i = 0; i < 4; ++i) {
        const float4 pa = *(const float4*)&Ps[r0 + i][s4];
        pav[i][0] = pa.x; pav[i][1] = pa.y; pav[i][2] = pa.z; pav[i][3] = pa.w;
      }
#pragma unroll
      for (int u2 = 0; u2 < 4; ++u2) {
        const float4 v0 = *(const float4*)&Vs[s4 + u2][cx];
        const float4 v1 = *(const float4*)&Vs[s4 + u2][cx + 4];
#pragma unroll
        for (int i = 0; i < 4; ++i) {
          const float p_ = pav[i][u2];
          o[i][0] = fmaf(p_, v0.x, o[i][0]);
          o[i][1] = fmaf(p_, v0.y, o[i][1]);
          o[i][2] = fmaf(p_, v0.z, o[i][2]);
          o[i][3] = fmaf(p_, v0.w, o[i][3]);
          o[i][4] = fmaf(p_, v1.x, o[i][4]);
          o[i][5] = fmaf(p_, v1.y, o[i][5]);
          o[i][6] = fmaf(p_, v1.z, o[i][6]);
          o[i][7] = fmaf(p_, v1.w, o[i][7]);
        }
      }
    }
  }
  float* Og = O + base + (size_t)(qt * 64) * DDIM;
#pragma unroll
  for (int i = 0; i < 4; ++i) {
    const float invl = 1.0f / l[i];
    float4 v0, v1;
    v0.x = o[i][0] * invl; v0.y = o[i][1] * invl;
    v0.z = o[i][2] * invl; v0.w = o[i][3] * invl;
    v1.x = o[i][4] * invl; v1.y = o[i][5] * invl;
    v1.z = o[i][6] * invl; v1.w = o[i][7] * invl;
    *(float4*)(Og + (size_t)(r0 + i) * DDIM + cx)     = v0;
    *(float4*)(Og + (size_t)(r0 + i) * DDIM + cx + 4) = v1;
  }
}

// ---------------------------------------------------------------------------
// Final: y = lif2(f32) + spikes2(u8); LayerNorm; float32 store.
// One block (256 thr) per (b,t) row.
// ---------------------------------------------------------------------------
__global__ __launch_bounds__(256)
void ln_kernel(const float* __restrict__ a, const uint8_t* __restrict__ s8,
               const float* __restrict__ gamma, const float* __restrict__ beta,
               float* __restrict__ out) {
  const int row = blockIdx.x;
  const int tid = threadIdx.x;
  const size_t base = (size_t)row * DDIM;
  const float4 av = *(const float4*)(a + base + tid * 4);
  const uchar4 sv = *(const uchar4*)(s8 + base + tid * 4);
  const float y0 = av.x + (float)sv.x, y1 = av.y + (float)sv.y;
  const float y2 = av.z + (float)sv.z, y3 = av.w + (float)sv.w;
  float s = (y0 + y1) + (y2 + y3);
  float q = (y0 * y0 + y1 * y1) + (y2 * y2 + y3 * y3);
#pragma unroll
  for (int off = 1; off < 64; off <<= 1) {
    s += __shfl_xor(s, off);
    q += __shfl_xor(q, off);
  }
  __shared__ float red[8];
  const int wid = tid >> 6;
  if ((tid & 63) == 0) { red[wid * 2] = s; red[wid * 2 + 1] = q; }
  __syncthreads();
  const float ts = (red[0] + red[2]) + (red[4] + red[6]);
  const float tq = (red[1] + red[3]) + (red[5] + red[7]);
  const float mu  = ts * (1.0f / 1024.0f);
  const float var = tq * (1.0f / 1024.0f) - mu * mu;
  const float rs  = 1.0f / sqrtf(var + 1e-5f);
  const int d = tid * 4;
  const float4 gv  = *(const float4*)(gamma + d);
  const float4 btv = *(const float4*)(beta + d);
  float4 r;
  r.x = (y0 - mu) * rs * gv.x + btv.x;
  r.y = (y1 - mu) * rs * gv.y + btv.y;
  r.z = (y2 - mu) * rs * gv.z + btv.z;
  r.w = (y3 - mu) * rs * gv.w + btv.w;
  *(float4*)(out + base + d) = r;
}

// ---------------------------------------------------------------------------
// Workspace budget: 3 f32 buffers (A,C,D) + 1 u8 spike buffer = 54.5 MB.
// ---------------------------------------------------------------------------
extern "C" void kernel_launch(void* const* d_in, const int* in_sizes, int n_in,
                              void* d_out, int out_size, void* d_ws, size_t ws_size,
                              hipStream_t stream) {
  const float* x       = (const float*)d_in[0];
  const float* context = (const float*)d_in[1];
  const float* Wg  = (const float*)d_in[2];
  const float* bg  = (const float*)d_in[3];
  const float* Wc  = (const float*)d_in[4];
  const float* Wq  = (const float*)d_in[5];
  const float* Wk  = (const float*)d_in[6];
  const float* Wv  = (const float*)d_in[7];
  const float* Wo  = (const float*)d_in[8];
  const float* Wm  = (const float*)d_in[9];
  const float* rWk = (const float*)d_in[10];
  const float* rWv = (const float*)d_in[11];
  const float* rWr = (const float*)d_in[12];
  const float* rWo = (const float*)d_in[13];
  const float* wd  = (const float*)d_in[14];
  const float* uf  = (const float*)d_in[15];
  const float* gamma = (const float*)d_in[16];
  const float* beta  = (const float*)d_in[17];
  float* out = (float*)d_out;   // reference output dtype = float32

  float* w  = (float*)d_ws;
  float*   bA = w;                          // f32 scratch
  float*   bC = w + 1 * NELEM;              // f32 scratch
  float*   bD = w + 2 * NELEM;              // f32 scratch
  uint8_t* bS = (uint8_t*)(w + 3 * NELEM);  // spikes2 as u8 (live to the end)

  const dim3 gg(GN / BN, GM / BM);   // (8, 32) = 256 blocks
  const dim3 ew(4096);               // elementwise: NELEM/4/256
  const dim3 fa(16, 8, 4);

  // Stage 1: thalamic gate
  gemm_k<0,0><<<gg, 256, 0, stream>>>(x, Wg, bA);
  gemm_k<1,0><<<gg, 256, 0, stream>>>(context, Wc, bA);
  gate_kernel<<<ew, 256, 0, stream>>>(x, bA, bg, bA);
  // Stage 2: LIF -> spikes2 (u8)
  lif_u8_kernel<<<16, 256, 0, stream>>>(bA, bS);
  // Stage 3: spike self-attention (O written in-place over Q)
  gemm_k<0,1><<<gg, 256, 0, stream>>>(bS, Wq, bA);
  gemm_k<0,1><<<gg, 256, 0, stream>>>(bS, Wk, bC);
  gemm_k<0,1><<<gg, 256, 0, stream>>>(bS, Wv, bD);
  flash_attn<<<fa, 256, 0, stream>>>(bA, bC, bD, bA);
  gemm_k<0,0><<<gg, 256, 0, stream>>>(bA, Wo, bC);         // bC = attn_out@Wo
  // Stage 4: apical modulation
  gemm_k<0,0><<<gg, 256, 0, stream>>>(context, Wm, bA);
  mod_kernel<<<ew, 256, 0, stream>>>(bC, bA, bD);          // bD = modulated
  // Stage 5: RWKV
  gemm_k<0,0><<<gg, 256, 0, stream>>>(bD, rWk, bA);        // bA = k
  gemm_k<0,0><<<gg, 256, 0, stream>>>(bD, rWv, bC);        // bC = v
  rwkv_kernel<<<16, 256, 0, stream>>>(bA, bC, wd, uf, bA); // bA = wkv (in-place)
  gemm_k<0,0><<<gg, 256, 0, stream>>>(bD, rWr, bC);        // bC = r (pre-sigmoid)
  rmul_kernel<<<ew, 256, 0, stream>>>(bC, bA, bA);         // bA = sig(r)*wkv
  gemm_k<0,0><<<gg, 256, 0, stream>>>(bA, rWo, bC);        // bC = recurrent
  // Stage 6: output LIF (in-place) + residual + LayerNorm
  lif_ip_kernel<<<16, 256, 0, stream>>>(bC);
  ln_kernel<<<4096, 256, 0, stream>>>(bC, bS, gamma, beta, out);
}

// Round 6
// 2182.128 us; speedup vs baseline: 1.5509x; 1.0176x over previous
//
#include <hip/hip_runtime.h>
#include <hip/hip_bf16.h>
#include <math.h>

// Problem dims (fixed)
#define BDIM 4
#define TDIM 1024
#define DDIM 1024
#define DH   128
#define NELEM ((size_t)BDIM * TDIM * DDIM)   // 4,194,304

// ---------------------------------------------------------------------------
// GEMM: C[4096 x 1024] = A[4096 x 1024] @ B[1024 x 1024], all row-major.
// f32 data & accumulation (sequential fmaf over k — op order identical to the
// round-1 kernel, spike-identical to f64: margins > ~1e-4, f32 is flip-safe).
// BM=BN=128, BK=16, 256 threads, 8x8 micro-tile.
// Double-buffered LDS: ONE barrier per K-step; global loads issued one full
// iteration before their ds_write (latency fully covered by compute).
// XCD swizzle: blocks on XCD x handle by in [4x,4x+4) -> A-slice 2MB + B 4MB
// mostly L2-resident per XCD.
// EPI=1 -> C += A@B.  AU8=1 -> A is uint8 (spike matrix, 0/1).
// ---------------------------------------------------------------------------
constexpr int GM = 4096, GN = 1024, GK = 1024;
constexpr int BM = 128, BN = 128, BK = 16;

template<int EPI, int AU8>
__global__ __launch_bounds__(256)
void gemm_k(const void* __restrict__ Av, const float* __restrict__ Bm,
            float* __restrict__ C) {
  __shared__ float As[2][BK][BM + 4];   // transposed A tiles (double buffer)
  __shared__ float Bs[2][BK][BN + 4];
  const int tid = threadIdx.x;
  // XCD-aware decode: n = xcd + 8*(bx + 8*t), by = xcd*4 + t
  const int n  = blockIdx.x;            // 0..255
  const int by = (n & 7) * 4 + (n >> 6);
  const int bx = (n >> 3) & 7;
  const int row0 = by * BM;
  const int col0 = bx * BN;

  const int arow = tid >> 1;          // 0..127
  const int ak   = (tid & 1) << 3;    // 0 or 8
  const int brow = tid >> 4;          // 0..15
  const int bc   = (tid & 15) << 3;   // 0..120
  const int ty   = tid >> 4;          // 0..15
  const int tx   = tid & 15;          // 0..15

  float acc[8][8];
#pragma unroll
  for (int i = 0; i < 8; ++i)
#pragma unroll
    for (int j = 0; j < 8; ++j) acc[i][j] = 0.f;

  const float* Bp = Bm + (size_t)brow * GN + col0 + bc;
  float4 a0, a1, b0, b1;

#define GLOAD(K0)                                                              \
  if (AU8) {                                                                   \
    const uint8_t* Ap = (const uint8_t*)Av + (size_t)(row0 + arow) * GK + (K0) + ak; \
    const uchar4 u0 = *(const uchar4*)Ap;                                      \
    const uchar4 u1 = *(const uchar4*)(Ap + 4);                                \
    a0 = make_float4((float)u0.x, (float)u0.y, (float)u0.z, (float)u0.w);      \
    a1 = make_float4((float)u1.x, (float)u1.y, (float)u1.z, (float)u1.w);      \
  } else {                                                                     \
    const float* Ap = (const float*)Av + (size_t)(row0 + arow) * GK + (K0) + ak; \
    a0 = *(const float4*)Ap;                                                   \
    a1 = *(const float4*)(Ap + 4);                                             \
  }                                                                            \
  b0 = *(const float4*)(Bp + (size_t)(K0) * GN);                               \
  b1 = *(const float4*)(Bp + (size_t)(K0) * GN + 4);

#define SWRITE(NB)                                                             \
  As[NB][ak + 0][arow] = a0.x; As[NB][ak + 1][arow] = a0.y;                    \
  As[NB][ak + 2][arow] = a0.z; As[NB][ak + 3][arow] = a0.w;                    \
  As[NB][ak + 4][arow] = a1.x; As[NB][ak + 5][arow] = a1.y;                    \
  As[NB][ak + 6][arow] = a1.z; As[NB][ak + 7][arow] = a1.w;                    \
  *(float4*)&Bs[NB][brow][bc]     = b0;                                        \
  *(float4*)&Bs[NB][brow][bc + 4] = b1;

  // prologue: tile0 -> buf0; tile1 loads in flight
  GLOAD(0);
  SWRITE(0);
  GLOAD(BK);

  int cur = 0;
  for (int k0 = 0; k0 < GK; k0 += BK) {
    __syncthreads();                    // buf[cur] visible to all
#pragma unroll
    for (int kk = 0; kk < BK; ++kk) {
      const float4 ra0 = *(const float4*)&As[cur][kk][ty * 8];
      const float4 ra1 = *(const float4*)&As[cur][kk][ty * 8 + 4];
      const float4 rb0 = *(const float4*)&Bs[cur][kk][tx * 8];
      const float4 rb1 = *(const float4*)&Bs[cur][kk][tx * 8 + 4];
      const float ra[8] = {ra0.x, ra0.y, ra0.z, ra0.w, ra1.x, ra1.y, ra1.z, ra1.w};
      const float rb[8] = {rb0.x, rb0.y, rb0.z, rb0.w, rb1.x, rb1.y, rb1.z, rb1.w};
#pragma unroll
      for (int i = 0; i < 8; ++i)
#pragma unroll
        for (int j = 0; j < 8; ++j)
          acc[i][j] = fmaf(ra[i], rb[j], acc[i][j]);
    }
    const int kw = k0 + BK;             // tile whose data sits in regs
    if (kw < GK) {
      SWRITE(cur ^ 1);                  // write next buf (disjoint from cur)
      const int kn = k0 + 2 * BK;
      if (kn < GK) { GLOAD(kn); }       // lands during next compute
    }
    cur ^= 1;
  }
#undef GLOAD
#undef SWRITE

#pragma unroll
  for (int i = 0; i < 8; ++i) {
    float* cp = C + (size_t)(row0 + ty * 8 + i) * GN + col0 + tx * 8;
    float4 v0, v1;
    v0.x = acc[i][0]; v0.y = acc[i][1]; v0.z = acc[i][2]; v0.w = acc[i][3];
    v1.x = acc[i][4]; v1.y = acc[i][5]; v1.z = acc[i][6]; v1.w = acc[i][7];
    if (EPI == 1) {
      const float4 o0 = *(const float4*)cp;
      const float4 o1 = *(const float4*)(cp + 4);
      v0.x += o0.x; v0.y += o0.y; v0.z += o0.z; v0.w += o0.w;
      v1.x += o1.x; v1.y += o1.y; v1.z += o1.z; v1.w += o1.w;
    }
    *(float4*)cp       = v0;
    *(float4*)(cp + 4) = v1;
  }
}

// ---------------------------------------------------------------------------
// Elementwise kernels (float4, 1 f4/thread, grid = NELEM/4/256 = 4096)
// ---------------------------------------------------------------------------
__device__ __forceinline__ float sigf(float z) { return 1.0f / (1.0f + expf(-z)); }

__global__ __launch_bounds__(256)
void gate_kernel(const float* __restrict__ x, const float* __restrict__ L,
                 const float* __restrict__ bg, float* __restrict__ out) {
  const int i4 = blockIdx.x * 256 + threadIdx.x;
  const float4 xv = ((const float4*)x)[i4];
  const float4 lv = ((const float4*)L)[i4];
  const float4 bv = ((const float4*)bg)[i4 & 255];
  float4 r;
  r.x = xv.x * (0.5f * sigf(lv.x + bv.x) + 0.5f);
  r.y = xv.y * (0.5f * sigf(lv.y + bv.y) + 0.5f);
  r.z = xv.z * (0.5f * sigf(lv.z + bv.z) + 0.5f);
  r.w = xv.w * (0.5f * sigf(lv.w + bv.w) + 0.5f);
  ((float4*)out)[i4] = r;
}

__global__ __launch_bounds__(256)
void mod_kernel(const float* __restrict__ a, const float* __restrict__ c,
                float* __restrict__ out) {
  const int i4 = blockIdx.x * 256 + threadIdx.x;
  const float4 av = ((const float4*)a)[i4];
  const float4 cv = ((const float4*)c)[i4];
  float4 r;
  r.x = av.x * (1.0f + tanhf(cv.x));
  r.y = av.y * (1.0f + tanhf(cv.y));
  r.z = av.z * (1.0f + tanhf(cv.z));
  r.w = av.w * (1.0f + tanhf(cv.w));
  ((float4*)out)[i4] = r;
}

__global__ __launch_bounds__(256)
void rmul_kernel(const float* __restrict__ rr, const float* __restrict__ wkv,
                 float* __restrict__ out) {
  const int i4 = blockIdx.x * 256 + threadIdx.x;
  const float4 rv = ((const float4*)rr)[i4];
  const float4 wv = ((const float4*)wkv)[i4];
  float4 r;
  r.x = sigf(rv.x) * wv.x;
  r.y = sigf(rv.y) * wv.y;
  r.z = sigf(rv.z) * wv.z;
  r.w = sigf(rv.w) * wv.w;
  ((float4*)out)[i4] = r;
}

// ---------------------------------------------------------------------------
// LIF scans: one thread per (b,d) channel, serial over T. Soft reset.
// f32 with the reference's exact op order.
// ---------------------------------------------------------------------------
__global__ __launch_bounds__(256)
void lif_u8_kernel(const float* __restrict__ x, uint8_t* __restrict__ s) {
  const int c = blockIdx.x * 256 + threadIdx.x;      // 0..4095
  const size_t off = (size_t)(c >> 10) * TDIM * DDIM + (c & 1023);
  const float* xp = x + off;
  uint8_t* sp = s + off;
  float u = 0.f;
#pragma unroll 4
  for (int t = 0; t < TDIM; ++t) {
    const float xt = xp[(size_t)t * DDIM];
    u = __fadd_rn(__fmul_rn(0.9f, u), xt);
    const bool fire = (u >= 1.0f);
    sp[(size_t)t * DDIM] = fire ? 1 : 0;
    if (fire) u -= 1.0f;
  }
}

__global__ __launch_bounds__(256)
void lif_ip_kernel(float* __restrict__ x) {
  const int c = blockIdx.x * 256 + threadIdx.x;
  const size_t off = (size_t)(c >> 10) * TDIM * DDIM + (c & 1023);
  float* xp = x + off;
  float u = 0.f;
#pragma unroll 4
  for (int t = 0; t < TDIM; ++t) {
    const float xt = xp[(size_t)t * DDIM];
    u = __fadd_rn(__fmul_rn(0.9f, u), xt);
    const float sv = (u >= 1.0f) ? 1.0f : 0.0f;
    xp[(size_t)t * DDIM] = sv;
    u -= sv;
  }
}

// ---------------------------------------------------------------------------
// RWKV numerically-stable recurrence: one thread per (b,d) channel, f32.
// out may alias k (each element read before written by the same thread).
// ---------------------------------------------------------------------------
__global__ __launch_bounds__(256)
void rwkv_kernel(const float* __restrict__ k, const float* __restrict__ v,
                 const float* __restrict__ wd, const float* __restrict__ uf,
                 float* __restrict__ out) {
  const int c = blockIdx.x * 256 + threadIdx.x;
  const int d = c & 1023;
  const size_t off = (size_t)(c >> 10) * TDIM * DDIM + d;
  const float* kp = k + off;
  const float* vp = v + off;
  float* op = out + off;
  const float w = expf(wd[d]);
  const float u = uf[d];
  float aa = 0.f, bb = 0.f, pp = -1e30f;
  for (int t = 0; t < TDIM; ++t) {
    const float kt = kp[(size_t)t * DDIM];
    const float vt = vp[(size_t)t * DDIM];
    const float ww = __fadd_rn(u, kt);
    const float p  = fmaxf(pp, ww);
    float e1 = expf(__fsub_rn(pp, p));
    float e2 = expf(__fsub_rn(ww, p));
    const float num = __fadd_rn(__fmul_rn(e1, aa), __fmul_rn(e2, vt));
    const float den = __fadd_rn(__fmul_rn(e1, bb), e2);
    op[(size_t)t * DDIM] = num / den;
    const float ww2 = __fsub_rn(pp, w);
    const float p2  = fmaxf(ww2, kt);
    e1 = expf(__fsub_rn(ww2, p2));
    e2 = expf(__fsub_rn(kt, p2));
    aa = __fadd_rn(__fmul_rn(e1, aa), __fmul_rn(e2, vt));
    bb = __fadd_rn(__fmul_rn(e1, bb), e2);
    pp = p2;
  }
}

// ---------------------------------------------------------------------------
// Flash attention, f32, non-causal. Grid 512 x 256 thr. KT=32 tiles.
// LDS 76.8 KB -> 2 blocks/CU (latency hidden by cross-block TLP; NO held
// register prefetch — round-5's caused ~370 MB of scratch-spill writes).
// XCD swizzle: the 16 q-tile blocks sharing one (b,h)'s K/V land on one XCD.
// O MAY ALIAS Q (each block consumes only its own Q rows, staged in LDS).
// ---------------------------------------------------------------------------
#define KT 32
__global__ __launch_bounds__(256)
void flash_attn(const float* __restrict__ Q, const float* __restrict__ K,
                const float* __restrict__ V, float* __restrict__ O) {
  __shared__ float Qs[64][DH + 4];
  __shared__ float Ks[KT][DH + 4];
  __shared__ float Vs[KT][DH + 4];
  __shared__ float Ps[64][KT + 4];
  const int tid = threadIdx.x;
  // decode: n = xcd + 8*(qt + 16*grp4); (b,h) = p = grp4*8 + xcd
  const int n    = blockIdx.x;          // 0..511
  const int xcd  = n & 7;
  const int idx  = n >> 3;              // 0..63
  const int qt   = idx & 15;
  const int grp4 = idx >> 4;            // 0..3
  const int p    = grp4 * 8 + xcd;      // 0..31
  const int b    = p >> 3, h = p & 7;
  const size_t base = ((size_t)b * TDIM) * DDIM + (size_t)h * DH;
  const float* Qg = Q + base + (size_t)(qt * 64) * DDIM;
#pragma unroll
  for (int q2 = 0; q2 < 8; ++q2) {
    const int f = tid + q2 * 256;
    const int r = f >> 5, c4 = (f & 31) << 2;
    *(float4*)&Qs[r][c4] = *(const float4*)(Qg + (size_t)r * DDIM + c4);
  }
  const int ty = tid >> 4, tx = tid & 15;
  const int r0 = ty * 4;          // 4 query rows per thread
  const int cx = tx * 8;          // 8 output cols per thread
  float m[4] = {-INFINITY, -INFINITY, -INFINITY, -INFINITY};
  float l[4] = {0.f, 0.f, 0.f, 0.f};
  float o[4][8];
#pragma unroll
  for (int i = 0; i < 4; ++i)
#pragma unroll
    for (int j = 0; j < 8; ++j) o[i][j] = 0.f;
  const float ISC = 0.08838834764831845f;  // 1/sqrt(128); mul ~= ref's div
                                           // (delta ~1e-7 << 1e-4 spike margin)

  for (int kt0 = 0; kt0 < TDIM; kt0 += KT) {
    __syncthreads();              // prev tile's PV done with Ks/Vs/Ps
    {                             // stage K/V tile (short-lived regs only)
      const float* Kg = K + base + (size_t)kt0 * DDIM;
      const float* Vg = V + base + (size_t)kt0 * DDIM;
#pragma unroll
      for (int i = 0; i < 4; ++i) {
        const int f = tid + i * 256;
        const int rr = f >> 5, c4 = (f & 31) << 2;
        *(float4*)&Ks[rr][c4] = *(const float4*)(Kg + (size_t)rr * DDIM + c4);
        *(float4*)&Vs[rr][c4] = *(const float4*)(Vg + (size_t)rr * DDIM + c4);
      }
    }
    __syncthreads();
    // S = Q K^T : thread owns rows r0..r0+3, cols {tx, tx+16}
    float s[4][2];
#pragma unroll
    for (int i = 0; i < 4; ++i) { s[i][0] = 0.f; s[i][1] = 0.f; }
    for (int kd = 0; kd < DH; kd += 4) {
      float4 qa[4];
#pragma unroll
      for (int i = 0; i < 4; ++i) qa[i] = *(const float4*)&Qs[r0 + i][kd];
      const float4 kb0 = *(const float4*)&Ks[tx][kd];
      const float4 kb1 = *(const float4*)&Ks[tx + 16][kd];
#pragma unroll
      for (int i = 0; i < 4; ++i) {
        s[i][0] = fmaf(qa[i].x, kb0.x, s[i][0]);
        s[i][0] = fmaf(qa[i].y, kb0.y, s[i][0]);
        s[i][0] = fmaf(qa[i].z, kb0.z, s[i][0]);
        s[i][0] = fmaf(qa[i].w, kb0.w, s[i][0]);
        s[i][1] = fmaf(qa[i].x, kb1.x, s[i][1]);
        s[i][1] = fmaf(qa[i].y, kb1.y, s[i][1]);
        s[i][1] = fmaf(qa[i].z, kb1.z, s[i][1]);
        s[i][1] = fmaf(qa[i].w, kb1.w, s[i][1]);
      }
    }
    // online softmax (rows live in 16-lane shuffle groups)
#pragma unroll
    for (int i = 0; i < 4; ++i) {
      const float sc0 = s[i][0] * ISC, sc1 = s[i][1] * ISC;
      float mx = fmaxf(sc0, sc1);
      mx = fmaxf(mx, __shfl_xor(mx, 1, 16));
      mx = fmaxf(mx, __shfl_xor(mx, 2, 16));
      mx = fmaxf(mx, __shfl_xor(mx, 4, 16));
      mx = fmaxf(mx, __shfl_xor(mx, 8, 16));
      const float mn = fmaxf(m[i], mx);
      const float rf = expf(m[i] - mn);       // exp(-inf)=0 on first tile
      const float p0 = expf(sc0 - mn), p1 = expf(sc1 - mn);
      float ps = p0 + p1;
      ps += __shfl_xor(ps, 1, 16);
      ps += __shfl_xor(ps, 2, 16);
      ps += __shfl_xor(ps, 4, 16);
      ps += __shfl_xor(ps, 8, 16);
      l[i] = l[i] * rf + ps;
      m[i] = mn;
#pragma unroll
      for (int jj = 0; jj < 8; ++jj) o[i][jj] *= rf;
      Ps[r0 + i][tx]      = p0;
      Ps[r0 + i][tx + 16] = p1;
    }
    __syncthreads();
    // O += P @ V
#pragma unroll
    for (int s4 = 0; s4 < KT; s4 += 4) {
      float pav[4][4];
#pragma unroll
      for (int i = 0; i < 4; ++i) {
        const float4 pa = *(const float4*)&Ps[r0 + i][s4];
        pav[i][0] = pa.x; pav[i][1] = pa.y; pav[i][2] = pa.z; pav[i][3] = pa.w;
      }
#pragma unroll
      for (int u2 = 0; u2 < 4; ++u2) {
        const float4 v0 = *(const float4*)&Vs[s4 + u2][cx];
        const float4 v1 = *(const float4*)&Vs[s4 + u2][cx + 4];
#pragma unroll
        for (int i = 0; i < 4; ++i) {
          const float p_ = pav[i][u2];
          o[i][0] = fmaf(p_, v0.x, o[i][0]);
          o[i][1] = fmaf(p_, v0.y, o[i][1]);
          o[i][2] = fmaf(p_, v0.z, o[i][2]);
          o[i][3] = fmaf(p_, v0.w, o[i][3]);
          o[i][4] = fmaf(p_, v1.x, o[i][4]);
          o[i][5] = fmaf(p_, v1.y, o[i][5]);
          o[i][6] = fmaf(p_, v1.z, o[i][6]);
          o[i][7] = fmaf(p_, v1.w, o[i][7]);
        }
      }
    }
  }
  float* Og = O + base + (size_t)(qt * 64) * DDIM;
#pragma unroll
  for (int i = 0; i < 4; ++i) {
    const float invl = 1.0f / l[i];
    float4 v0, v1;
    v0.x = o[i][0] * invl; v0.y = o[i][1] * invl;
    v0.z = o[i][2] * invl; v0.w = o[i][3] * invl;
    v1.x = o[i][4] * invl; v1.y = o[i][5] * invl;
    v1.z = o[i][6] * invl; v1.w = o[i][7] * invl;
    *(float4*)(Og + (size_t)(r0 + i) * DDIM + cx)     = v0;
    *(float4*)(Og + (size_t)(r0 + i) * DDIM + cx + 4) = v1;
  }
}

// ---------------------------------------------------------------------------
// Final: y = lif2(f32) + spikes2(u8); LayerNorm; float32 store.
// ---------------------------------------------------------------------------
__global__ __launch_bounds__(256)
void ln_kernel(const float* __restrict__ a, const uint8_t* __restrict__ s8,
               const float* __restrict__ gamma, const float* __restrict__ beta,
               float* __restrict__ out) {
  const int row = blockIdx.x;
  const int tid = threadIdx.x;
  const size_t base = (size_t)row * DDIM;
  const float4 av = *(const float4*)(a + base + tid * 4);
  const uchar4 sv = *(const uchar4*)(s8 + base + tid * 4);
  const float y0 = av.x + (float)sv.x, y1 = av.y + (float)sv.y;
  const float y2 = av.z + (float)sv.z, y3 = av.w + (float)sv.w;
  float s = (y0 + y1) + (y2 + y3);
  float q = (y0 * y0 + y1 * y1) + (y2 * y2 + y3 * y3);
#pragma unroll
  for (int off = 1; off < 64; off <<= 1) {
    s += __shfl_xor(s, off);
    q += __shfl_xor(q, off);
  }
  __shared__ float red[8];
  const int wid = tid >> 6;
  if ((tid & 63) == 0) { red[wid * 2] = s; red[wid * 2 + 1] = q; }
  __syncthreads();
  const float ts = (red[0] + red[2]) + (red[4] + red[6]);
  const float tq = (red[1] + red[3]) + (red[5] + red[7]);
  const float mu  = ts * (1.0f / 1024.0f);
  const float var = tq * (1.0f / 1024.0f) - mu * mu;
  const float rs  = 1.0f / sqrtf(var + 1e-5f);
  const int d = tid * 4;
  const float4 gv  = *(const float4*)(gamma + d);
  const float4 btv = *(const float4*)(beta + d);
  float4 r;
  r.x = (y0 - mu) * rs * gv.x + btv.x;
  r.y = (y1 - mu) * rs * gv.y + btv.y;
  r.z = (y2 - mu) * rs * gv.z + btv.z;
  r.w = (y3 - mu) * rs * gv.w + btv.w;
  *(float4*)(out + base + d) = r;
}

// ---------------------------------------------------------------------------
// Workspace budget: 3 f32 buffers (A,C,D) + 1 u8 spike buffer = 54.5 MB.
// ---------------------------------------------------------------------------
extern "C" void kernel_launch(void* const* d_in, const int* in_sizes, int n_in,
                              void* d_out, int out_size, void* d_ws, size_t ws_size,
                              hipStream_t stream) {
  const float* x       = (const float*)d_in[0];
  const float* context = (const float*)d_in[1];
  const float* Wg  = (const float*)d_in[2];
  const float* bg  = (const float*)d_in[3];
  const float* Wc  = (const float*)d_in[4];
  const float* Wq  = (const float*)d_in[5];
  const float* Wk  = (const float*)d_in[6];
  const float* Wv  = (const float*)d_in[7];
  const float* Wo  = (const float*)d_in[8];
  const float* Wm  = (const float*)d_in[9];
  const float* rWk = (const float*)d_in[10];
  const float* rWv = (const float*)d_in[11];
  const float* rWr = (const float*)d_in[12];
  const float* rWo = (const float*)d_in[13];
  const float* wd  = (const float*)d_in[14];
  const float* uf  = (const float*)d_in[15];
  const float* gamma = (const float*)d_in[16];
  const float* beta  = (const float*)d_in[17];
  float* out = (float*)d_out;   // reference output dtype = float32

  float* w  = (float*)d_ws;
  float*   bA = w;                          // f32 scratch
  float*   bC = w + 1 * NELEM;              // f32 scratch
  float*   bD = w + 2 * NELEM;              // f32 scratch
  uint8_t* bS = (uint8_t*)(w + 3 * NELEM);  // spikes2 as u8 (live to the end)

  const dim3 ew(4096);               // elementwise: NELEM/4/256

  // Stage 1: thalamic gate
  gemm_k<0,0><<<256, 256, 0, stream>>>(x, Wg, bA);
  gemm_k<1,0><<<256, 256, 0, stream>>>(context, Wc, bA);
  gate_kernel<<<ew, 256, 0, stream>>>(x, bA, bg, bA);
  // Stage 2: LIF -> spikes2 (u8)
  lif_u8_kernel<<<16, 256, 0, stream>>>(bA, bS);
  // Stage 3: spike self-attention (O written in-place over Q)
  gemm_k<0,1><<<256, 256, 0, stream>>>(bS, Wq, bA);
  gemm_k<0,1><<<256, 256, 0, stream>>>(bS, Wk, bC);
  gemm_k<0,1><<<256, 256, 0, stream>>>(bS, Wv, bD);
  flash_attn<<<512, 256, 0, stream>>>(bA, bC, bD, bA);
  gemm_k<0,0><<<256, 256, 0, stream>>>(bA, Wo, bC);         // bC = attn_out@Wo
  // Stage 4: apical modulation
  gemm_k<0,0><<<256, 256, 0, stream>>>(context, Wm, bA);
  mod_kernel<<<ew, 256, 0, stream>>>(bC, bA, bD);           // bD = modulated
  // Stage 5: RWKV
  gemm_k<0,0><<<256, 256, 0, stream>>>(bD, rWk, bA);        // bA = k
  gemm_k<0,0><<<256, 256, 0, stream>>>(bD, rWv, bC);        // bC = v
  rwkv_kernel<<<16, 256, 0, stream>>>(bA, bC, wd, uf, bA);  // bA = wkv (in-place)
  gemm_k<0,0><<<256, 256, 0, stream>>>(bD, rWr, bC);        // bC = r (pre-sigmoid)
  rmul_kernel<<<ew, 256, 0, stream>>>(bC, bA, bA);          // bA = sig(r)*wkv
  gemm_k<0,0><<<256, 256, 0, stream>>>(bA, rWo, bC);        // bC = recurrent
  // Stage 6: output LIF (in-place) + residual + LayerNorm
  lif_ip_kernel<<<16, 256, 0, stream>>>(bC);
  ln_kernel<<<4096, 256, 0, stream>>>(bC, bS, gamma, beta, out);
}

// Round 8
// 2008.562 us; speedup vs baseline: 1.6849x; 1.0864x over previous
//
#include <hip/hip_runtime.h>
#include <hip/hip_bf16.h>
#include <math.h>

// Problem dims (fixed)
#define BDIM 4
#define TDIM 1024
#define DDIM 1024
#define DH   128
#define NELEM ((size_t)BDIM * TDIM * DDIM)   // 4,194,304

typedef __attribute__((ext_vector_type(8))) short bfrag;   // 8 bf16 (4 VGPR)
typedef __attribute__((ext_vector_type(4))) float facc;    // 4 f32 acc

__device__ __forceinline__ ushort f2bf(float x) {          // f32 -> bf16 RNE
  union { float f; uint u; } v; v.f = x;
  const uint r = v.u + 0x7FFFu + ((v.u >> 16) & 1u);
  return (ushort)(r >> 16);
}
__device__ __forceinline__ float bf2f(ushort h) {
  union { uint u; float f; } v; v.u = ((uint)h) << 16; return v.f;
}

constexpr int GM = 4096, GN = 1024, GK = 1024;
constexpr int BM = 128, BN = 128, BK = 32;
constexpr int BKP = 40;                    // padded LDS k-dim (80 B rows)
constexpr int PSTR = 1024 * 1024;          // ushorts per B plane

// ---------------------------------------------------------------------------
// cvt_b3t: W[K=1024][N=1024] f32 -> 3 bf16 planes P + p*PSTR in blocked-
// transposed layout [K/32][N][32] (so GEMM B-staging is fully coalesced).
// 3-way split: W = b1 + b2 + b3 (8+8+8 mantissa bits, residual ~2^-26).
// ---------------------------------------------------------------------------
__global__ __launch_bounds__(256)
void cvt_b3t(const float* __restrict__ W, ushort* __restrict__ P) {
  __shared__ float Ls[64][68];
  const int t = threadIdx.x;
  const int k0 = blockIdx.x * 64, n0 = blockIdx.y * 64;
  const int r = t >> 4, c4 = (t & 15) << 2;
#pragma unroll
  for (int i = 0; i < 4; ++i)
    *(float4*)&Ls[r + i * 16][c4] =
        *(const float4*)(W + (size_t)(k0 + r + i * 16) * GN + n0 + c4);
  __syncthreads();
  const int n = t >> 2, kc = (t & 3) << 4;
  uint p1[8], p2[8], p3[8];
#pragma unroll
  for (int jj = 0; jj < 8; ++jj) {
    const float x0 = Ls[kc + 2 * jj][n], x1 = Ls[kc + 2 * jj + 1][n];
    const ushort a1 = f2bf(x0); float ra = x0 - bf2f(a1);
    const ushort b1 = f2bf(ra); ra = ra - bf2f(b1);
    const ushort c1 = f2bf(ra);
    const ushort a2 = f2bf(x1); float rb = x1 - bf2f(a2);
    const ushort b2 = f2bf(rb); rb = rb - bf2f(b2);
    const ushort c2 = f2bf(rb);
    p1[jj] = (uint)a1 | ((uint)a2 << 16);
    p2[jj] = (uint)b1 | ((uint)b2 << 16);
    p3[jj] = (uint)c1 | ((uint)c2 << 16);
  }
  const int kk = k0 + kc;
  ushort* d = P + (size_t)(kk >> 5) * (GN * 32) + (size_t)(n0 + n) * 32 + (kk & 31);
  *(uint4*)(d)             = *(uint4*)&p1[0];
  *(uint4*)(d + 8)         = *(uint4*)&p1[4];
  *(uint4*)(d + PSTR)      = *(uint4*)&p2[0];
  *(uint4*)(d + PSTR + 8)  = *(uint4*)&p2[4];
  *(uint4*)(d + 2 * PSTR)     = *(uint4*)&p3[0];
  *(uint4*)(d + 2 * PSTR + 8) = *(uint4*)&p3[4];
}

// ---------------------------------------------------------------------------
// GEMM via 3-way-split bf16 MFMA: C = A @ B (+C if EPI).
// A f32 (or u8 spikes, AU8=1) converted in-kernel to 3 (1) bf16 LDS planes;
// B staged from pre-converted planes. Passes: accM += a1*b1 (main, own
// accumulator -> short rounding chain); accC += a2*b1 + a3*b1 + a1*b2 +
// a2*b2 + a1*b3. Total noise ~3e-7 < proven-safe f32-chain (~5e-7, R5/R6).
// Tile 128x128, BK=32, 4 waves, 4x4 16x16x32 frags/wave. XCD-swizzled grid.
// ---------------------------------------------------------------------------
template<int EPI, int AU8>
__global__ __launch_bounds__(256)
void gemm_k(const void* __restrict__ Av, const ushort* __restrict__ pB,
            float* __restrict__ C) {
  __shared__ ushort As[3][BM][BKP];
  __shared__ ushort Bs[3][BN][BKP];
  const int tid = threadIdx.x;
  const int n  = blockIdx.x;              // 0..255; XCD = n & 7
  const int by = (n & 7) * 4 + (n >> 6);
  const int bx = (n >> 3) & 7;
  const int row0 = by * BM;
  const int col0 = bx * BN;

  const int sm  = tid & 127;              // staged A-row
  const int sk0 = (tid >> 7) << 4;        // 0 or 16

  const int wave = tid >> 6;
  const int lane = tid & 63;
  const int wrow = (wave >> 1) * 64;
  const int wcol = (wave & 1) * 64;
  const int lrow = lane & 15;
  const int kof  = (lane >> 4) * 8;

  facc accM[4][4], accC[4][4];
#pragma unroll
  for (int i = 0; i < 4; ++i)
#pragma unroll
    for (int j = 0; j < 4; ++j) { accM[i][j] = (facc)0.f; accC[i][j] = (facc)0.f; }

  float av[16];
  uint4 a8raw;
  uint4 bregs[6];

#define GLOADA(K0)                                                             \
  if (AU8) {                                                                   \
    a8raw = *(const uint4*)((const uint8_t*)Av + (size_t)(row0 + sm) * GK + (K0) + sk0); \
  } else {                                                                     \
    const float* Ap = (const float*)Av + (size_t)(row0 + sm) * GK + (K0) + sk0; \
    *(float4*)&av[0]  = *(const float4*)(Ap);                                  \
    *(float4*)&av[4]  = *(const float4*)(Ap + 4);                              \
    *(float4*)&av[8]  = *(const float4*)(Ap + 8);                              \
    *(float4*)&av[12] = *(const float4*)(Ap + 12);                             \
  }

#define GLOADB(K0) {                                                           \
  const int kb = (K0) >> 5;                                                    \
  _Pragma("unroll")                                                            \
  for (int j = 0; j < 3; ++j) {                                                \
    const int u = tid + 256 * j;                                               \
    const int h = u & 1, nn = (u >> 1) & 127, p = u >> 8;                      \
    const ushort* sp = pB + (size_t)p * PSTR + (size_t)kb * (GN * 32)          \
                     + (size_t)(col0 + nn) * 32 + h * 16;                      \
    bregs[2 * j]     = *(const uint4*)sp;                                      \
    bregs[2 * j + 1] = *(const uint4*)(sp + 8);                                \
  }                                                                            \
}

#define SWRITE() {                                                             \
  if (AU8) {                                                                   \
    const uint w4[4] = {a8raw.x, a8raw.y, a8raw.z, a8raw.w};                   \
    uint pk[8];                                                                \
    _Pragma("unroll")                                                          \
    for (int i = 0; i < 8; ++i) {                                              \
      const uint b0 = (w4[i >> 1] >> ((i & 1) * 16)) & 0xFFu;                  \
      const uint b1 = (w4[i >> 1] >> ((i & 1) * 16 + 8)) & 0xFFu;              \
      pk[i] = (b0 * 0x3F80u) | ((b1 * 0x3F80u) << 16);                         \
    }                                                                          \
    *(uint4*)&As[0][sm][sk0]     = *(uint4*)&pk[0];                            \
    *(uint4*)&As[0][sm][sk0 + 8] = *(uint4*)&pk[4];                            \
  } else {                                                                     \
    uint q1[8], q2[8], q3[8];                                                  \
    _Pragma("unroll")                                                          \
    for (int i = 0; i < 8; ++i) {                                              \
      const float x0 = av[2 * i], x1 = av[2 * i + 1];                          \
      const ushort a1 = f2bf(x0); float ra = x0 - bf2f(a1);                    \
      const ushort b1 = f2bf(ra); ra = ra - bf2f(b1);                          \
      const ushort c1 = f2bf(ra);                                              \
      const ushort a2 = f2bf(x1); float rb = x1 - bf2f(a2);                    \
      const ushort b2 = f2bf(rb); rb = rb - bf2f(b2);                          \
      const ushort c2 = f2bf(rb);                                              \
      q1[i] = (uint)a1 | ((uint)a2 << 16);                                     \
      q2[i] = (uint)b1 | ((uint)b2 << 16);                                     \
      q3[i] = (uint)c1 | ((uint)c2 << 16);                                     \
    }                                                                          \
    *(uint4*)&As[0][sm][sk0]     = *(uint4*)&q1[0];                            \
    *(uint4*)&As[0][sm][sk0 + 8] = *(uint4*)&q1[4];                            \
    *(uint4*)&As[1][sm][sk0]     = *(uint4*)&q2[0];                            \
    *(uint4*)&As[1][sm][sk0 + 8] = *(uint4*)&q2[4];                            \
    *(uint4*)&As[2][sm][sk0]     = *(uint4*)&q3[0];                            \
    *(uint4*)&As[2][sm][sk0 + 8] = *(uint4*)&q3[4];                            \
  }                                                                            \
  _Pragma("unroll")                                                            \
  for (int j = 0; j < 3; ++j) {                                                \
    const int u = tid + 256 * j;                                               \
    const int h = u & 1, nn = (u >> 1) & 127, p = u >> 8;                      \
    *(uint4*)&Bs[p][nn][h * 16]     = bregs[2 * j];                            \
    *(uint4*)&Bs[p][nn][h * 16 + 8] = bregs[2 * j + 1];                        \
  }                                                                            \
}

  GLOADA(0); GLOADB(0);
  for (int k0 = 0; k0 < GK; k0 += BK) {
    __syncthreads();                      // previous compute done with LDS
    SWRITE();
    const int kn = k0 + BK;
    if (kn < GK) { GLOADA(kn); GLOADB(kn); }   // lands during compute
    __syncthreads();
    bfrag fb0[4], fb1[4], fb2[4];
#pragma unroll
    for (int f = 0; f < 4; ++f) {
      fb0[f] = *(const bfrag*)&Bs[0][wcol + f * 16 + lrow][kof];
      fb1[f] = *(const bfrag*)&Bs[1][wcol + f * 16 + lrow][kof];
      fb2[f] = *(const bfrag*)&Bs[2][wcol + f * 16 + lrow][kof];
    }
    // pass group b1: main (a1*b1 -> accM) + corrections a2*b1, a3*b1
#pragma unroll
    for (int mi = 0; mi < 4; ++mi) {
      const bfrag a1 = *(const bfrag*)&As[0][wrow + mi * 16 + lrow][kof];
      bfrag a2, a3;
      if (!AU8) {
        a2 = *(const bfrag*)&As[1][wrow + mi * 16 + lrow][kof];
        a3 = *(const bfrag*)&As[2][wrow + mi * 16 + lrow][kof];
      }
#pragma unroll
      for (int ni = 0; ni < 4; ++ni) {
        accM[mi][ni] = __builtin_amdgcn_mfma_f32_16x16x32_bf16(a1, fb0[ni], accM[mi][ni], 0, 0, 0);
        if (!AU8) {
          accC[mi][ni] = __builtin_amdgcn_mfma_f32_16x16x32_bf16(a2, fb0[ni], accC[mi][ni], 0, 0, 0);
          accC[mi][ni] = __builtin_amdgcn_mfma_f32_16x16x32_bf16(a3, fb0[ni], accC[mi][ni], 0, 0, 0);
        }
      }
    }
    // pass group b2: a1*b2 (+ a2*b2)
#pragma unroll
    for (int mi = 0; mi < 4; ++mi) {
      const bfrag a1 = *(const bfrag*)&As[0][wrow + mi * 16 + lrow][kof];
      bfrag a2;
      if (!AU8) a2 = *(const bfrag*)&As[1][wrow + mi * 16 + lrow][kof];
#pragma unroll
      for (int ni = 0; ni < 4; ++ni) {
        accC[mi][ni] = __builtin_amdgcn_mfma_f32_16x16x32_bf16(a1, fb1[ni], accC[mi][ni], 0, 0, 0);
        if (!AU8)
          accC[mi][ni] = __builtin_amdgcn_mfma_f32_16x16x32_bf16(a2, fb1[ni], accC[mi][ni], 0, 0, 0);
      }
    }
    // pass group b3: a1*b3
#pragma unroll
    for (int mi = 0; mi < 4; ++mi) {
      const bfrag a1 = *(const bfrag*)&As[0][wrow + mi * 16 + lrow][kof];
#pragma unroll
      for (int ni = 0; ni < 4; ++ni)
        accC[mi][ni] = __builtin_amdgcn_mfma_f32_16x16x32_bf16(a1, fb2[ni], accC[mi][ni], 0, 0, 0);
    }
  }
#undef GLOADA
#undef GLOADB
#undef SWRITE

  // epilogue: D frag col = lane&15, row = (lane>>4)*4 + reg (m89/m91).
#pragma unroll
  for (int mi = 0; mi < 4; ++mi) {
#pragma unroll
    for (int ni = 0; ni < 4; ++ni) {
      const int rbase = row0 + wrow + mi * 16 + (lane >> 4) * 4;
      const int cc    = col0 + wcol + ni * 16 + lrow;
      float* cp = C + (size_t)rbase * GN + cc;
#pragma unroll
      for (int r = 0; r < 4; ++r) {
        float v = accM[mi][ni][r] + accC[mi][ni][r];
        if (EPI == 1) v += cp[(size_t)r * GN];
        cp[(size_t)r * GN] = v;
      }
    }
  }
}

// ---------------------------------------------------------------------------
// Elementwise kernels (float4, 1 f4/thread, grid = NELEM/4/256 = 4096)
// ---------------------------------------------------------------------------
__device__ __forceinline__ float sigf(float z) { return 1.0f / (1.0f + expf(-z)); }

__global__ __launch_bounds__(256)
void gate_kernel(const float* __restrict__ x, const float* __restrict__ L,
                 const float* __restrict__ bg, float* __restrict__ out) {
  const int i4 = blockIdx.x * 256 + threadIdx.x;
  const float4 xv = ((const float4*)x)[i4];
  const float4 lv = ((const float4*)L)[i4];
  const float4 bv = ((const float4*)bg)[i4 & 255];
  float4 r;
  r.x = xv.x * (0.5f * sigf(lv.x + bv.x) + 0.5f);
  r.y = xv.y * (0.5f * sigf(lv.y + bv.y) + 0.5f);
  r.z = xv.z * (0.5f * sigf(lv.z + bv.z) + 0.5f);
  r.w = xv.w * (0.5f * sigf(lv.w + bv.w) + 0.5f);
  ((float4*)out)[i4] = r;
}

__global__ __launch_bounds__(256)
void mod_kernel(const float* __restrict__ a, const float* __restrict__ c,
                float* __restrict__ out) {
  const int i4 = blockIdx.x * 256 + threadIdx.x;
  const float4 av = ((const float4*)a)[i4];
  const float4 cv = ((const float4*)c)[i4];
  float4 r;
  r.x = av.x * (1.0f + tanhf(cv.x));
  r.y = av.y * (1.0f + tanhf(cv.y));
  r.z = av.z * (1.0f + tanhf(cv.z));
  r.w = av.w * (1.0f + tanhf(cv.w));
  ((float4*)out)[i4] = r;
}

__global__ __launch_bounds__(256)
void rmul_kernel(const float* __restrict__ rr, const float* __restrict__ wkv,
                 float* __restrict__ out) {
  const int i4 = blockIdx.x * 256 + threadIdx.x;
  const float4 rv = ((const float4*)rr)[i4];
  const float4 wv = ((const float4*)wkv)[i4];
  float4 r;
  r.x = sigf(rv.x) * wv.x;
  r.y = sigf(rv.y) * wv.y;
  r.z = sigf(rv.z) * wv.z;
  r.w = sigf(rv.w) * wv.w;
  ((float4*)out)[i4] = r;
}

// ---------------------------------------------------------------------------
// LIF scans: one thread per (b,d) channel, serial over T. Soft reset.
// ---------------------------------------------------------------------------
__global__ __launch_bounds__(256)
void lif_u8_kernel(const float* __restrict__ x, uint8_t* __restrict__ s) {
  const int c = blockIdx.x * 256 + threadIdx.x;
  const size_t off = (size_t)(c >> 10) * TDIM * DDIM + (c & 1023);
  const float* xp = x + off;
  uint8_t* sp = s + off;
  float u = 0.f;
#pragma unroll 4
  for (int t = 0; t < TDIM; ++t) {
    const float xt = xp[(size_t)t * DDIM];
    u = __fadd_rn(__fmul_rn(0.9f, u), xt);
    const bool fire = (u >= 1.0f);
    sp[(size_t)t * DDIM] = fire ? 1 : 0;
    if (fire) u -= 1.0f;
  }
}

__global__ __launch_bounds__(256)
void lif_ip_kernel(float* __restrict__ x) {
  const int c = blockIdx.x * 256 + threadIdx.x;
  const size_t off = (size_t)(c >> 10) * TDIM * DDIM + (c & 1023);
  float* xp = x + off;
  float u = 0.f;
#pragma unroll 4
  for (int t = 0; t < TDIM; ++t) {
    const float xt = xp[(size_t)t * DDIM];
    u = __fadd_rn(__fmul_rn(0.9f, u), xt);
    const float sv = (u >= 1.0f) ? 1.0f : 0.0f;
    xp[(size_t)t * DDIM] = sv;
    u -= sv;
  }
}

// ---------------------------------------------------------------------------
// RWKV numerically-stable recurrence: one thread per (b,d) channel, f32.
// ---------------------------------------------------------------------------
__global__ __launch_bounds__(256)
void rwkv_kernel(const float* __restrict__ k, const float* __restrict__ v,
                 const float* __restrict__ wd, const float* __restrict__ uf,
                 float* __restrict__ out) {
  const int c = blockIdx.x * 256 + threadIdx.x;
  const int d = c & 1023;
  const size_t off = (size_t)(c >> 10) * TDIM * DDIM + d;
  const float* kp = k + off;
  const float* vp = v + off;
  float* op = out + off;
  const float w = expf(wd[d]);
  const float u = uf[d];
  float aa = 0.f, bb = 0.f, pp = -1e30f;
  for (int t = 0; t < TDIM; ++t) {
    const float kt = kp[(size_t)t * DDIM];
    const float vt = vp[(size_t)t * DDIM];
    const float ww = __fadd_rn(u, kt);
    const float p  = fmaxf(pp, ww);
    float e1 = expf(__fsub_rn(pp, p));
    float e2 = expf(__fsub_rn(ww, p));
    const float num = __fadd_rn(__fmul_rn(e1, aa), __fmul_rn(e2, vt));
    const float den = __fadd_rn(__fmul_rn(e1, bb), e2);
    op[(size_t)t * DDIM] = num / den;
    const float ww2 = __fsub_rn(pp, w);
    const float p2  = fmaxf(ww2, kt);
    e1 = expf(__fsub_rn(ww2, p2));
    e2 = expf(__fsub_rn(kt, p2));
    aa = __fadd_rn(__fmul_rn(e1, aa), __fmul_rn(e2, vt));
    bb = __fadd_rn(__fmul_rn(e1, bb), e2);
    pp = p2;
  }
}

// ---------------------------------------------------------------------------
// Flash attention, f32, non-causal (unchanged from round 6 — proven).
// ---------------------------------------------------------------------------
#define KT 32
__global__ __launch_bounds__(256)
void flash_attn(const float* __restrict__ Q, const float* __restrict__ K,
                const float* __restrict__ V, float* __restrict__ O) {
  __shared__ float Qs[64][DH + 4];
  __shared__ float Ks[KT][DH + 4];
  __shared__ float Vs[KT][DH + 4];
  __shared__ float Ps[64][KT + 4];
  const int tid = threadIdx.x;
  const int n    = blockIdx.x;
  const int xcd  = n & 7;
  const int idx  = n >> 3;
  const int qt   = idx & 15;
  const int grp4 = idx >> 4;
  const int p    = grp4 * 8 + xcd;
  const int b    = p >> 3, h = p & 7;
  const size_t base = ((size_t)b * TDIM) * DDIM + (size_t)h * DH;
  const float* Qg = Q + base + (size_t)(qt * 64) * DDIM;
#pragma unroll
  for (int q2 = 0; q2 < 8; ++q2) {
    const int f = tid + q2 * 256;
    const int r = f >> 5, c4 = (f & 31) << 2;
    *(float4*)&Qs[r][c4] = *(const float4*)(Qg + (size_t)r * DDIM + c4);
  }
  const int ty = tid >> 4, tx = tid & 15;
  const int r0 = ty * 4;
  const int cx = tx * 8;
  float m[4] = {-INFINITY, -INFINITY, -INFINITY, -INFINITY};
  float l[4] = {0.f, 0.f, 0.f, 0.f};
  float o[4][8];
#pragma unroll
  for (int i = 0; i < 4; ++i)
#pragma unroll
    for (int j = 0; j < 8; ++j) o[i][j] = 0.f;
  const float ISC = 0.08838834764831845f;

  for (int kt0 = 0; kt0 < TDIM; kt0 += KT) {
    __syncthreads();
    {
      const float* Kg = K + base + (size_t)kt0 * DDIM;
      const float* Vg = V + base + (size_t)kt0 * DDIM;
#pragma unroll
      for (int i = 0; i < 4; ++i) {
        const int f = tid + i * 256;
        const int rr = f >> 5, c4 = (f & 31) << 2;
        *(float4*)&Ks[rr][c4] = *(const float4*)(Kg + (size_t)rr * DDIM + c4);
        *(float4*)&Vs[rr][c4] = *(const float4*)(Vg + (size_t)rr * DDIM + c4);
      }
    }
    __syncthreads();
    float s[4][2];
#pragma unroll
    for (int i = 0; i < 4; ++i) { s[i][0] = 0.f; s[i][1] = 0.f; }
    for (int kd = 0; kd < DH; kd += 4) {
      float4 qa[4];
#pragma unroll
      for (int i = 0; i < 4; ++i) qa[i] = *(const float4*)&Qs[r0 + i][kd];
      const float4 kb0 = *(const float4*)&Ks[tx][kd];
      const float4 kb1 = *(const float4*)&Ks[tx + 16][kd];
#pragma unroll
      for (int i = 0; i < 4; ++i) {
        s[i][0] = fmaf(qa[i].x, kb0.x, s[i][0]);
        s[i][0] = fmaf(qa[i].y, kb0.y, s[i][0]);
        s[i][0] = fmaf(qa[i].z, kb0.z, s[i][0]);
        s[i][0] = fmaf(qa[i].w, kb0.w, s[i][0]);
        s[i][1] = fmaf(qa[i].x, kb1.x, s[i][1]);
        s[i][1] = fmaf(qa[i].y, kb1.y, s[i][1]);
        s[i][1] = fmaf(qa[i].z, kb1.z, s[i][1]);
        s[i][1] = fmaf(qa[i].w, kb1.w, s[i][1]);
      }
    }
#pragma unroll
    for (int i = 0; i < 4; ++i) {
      const float sc0 = s[i][0] * ISC, sc1 = s[i][1] * ISC;
      float mx = fmaxf(sc0, sc1);
      mx = fmaxf(mx, __shfl_xor(mx, 1, 16));
      mx = fmaxf(mx, __shfl_xor(mx, 2, 16));
      mx = fmaxf(mx, __shfl_xor(mx, 4, 16));
      mx = fmaxf(mx, __shfl_xor(mx, 8, 16));
      const float mn = fmaxf(m[i], mx);
      const float rf = expf(m[i] - mn);
      const float p0 = expf(sc0 - mn), p1 = expf(sc1 - mn);
      float ps = p0 + p1;
      ps += __shfl_xor(ps, 1, 16);
      ps += __shfl_xor(ps, 2, 16);
      ps += __shfl_xor(ps, 4, 16);
      ps += __shfl_xor(ps, 8, 16);
      l[i] = l[i] * rf + ps;
      m[i] = mn;
#pragma unroll
      for (int jj = 0; jj < 8; ++jj) o[i][jj] *= rf;
      Ps[r0 + i][tx]      = p0;
      Ps[r0 + i][tx + 16] = p1;
    }
    __syncthreads();
#pragma unroll
    for (int s4 = 0; s4 < KT; s4 += 4) {
      float pav[4][4];
#pragma unroll
      for (int i = 0; i < 4; ++i) {
        const float4 pa = *(const float4*)&Ps[r0 + i][s4];
        pav[i][0] = pa.x; pav[i][1] = pa.y; pav[i][2] = pa.z; pav[i][3] = pa.w;
      }
#pragma unroll
      for (int u2 = 0; u2 < 4; ++u2) {
        const float4 v0 = *(const float4*)&Vs[s4 + u2][cx];
        const float4 v1 = *(const float4*)&Vs[s4 + u2][cx + 4];
#pragma unroll
        for (int i = 0; i < 4; ++i) {
          const float p_ = pav[i][u2];
          o[i][0] = fmaf(p_, v0.x, o[i][0]);
          o[i][1] = fmaf(p_, v0.y, o[i][1]);
          o[i][2] = fmaf(p_, v0.z, o[i][2]);
          o[i][3] = fmaf(p_, v0.w, o[i][3]);
          o[i][4] = fmaf(p_, v1.x, o[i][4]);
          o[i][5] = fmaf(p_, v1.y, o[i][5]);
          o[i][6] = fmaf(p_, v1.z, o[i][6]);
          o[i][7] = fmaf(p_, v1.w, o[i][7]);
        }
      }
    }
  }
  float* Og = O + base + (size_t)(qt * 64) * DDIM;
#pragma unroll
  for (int i = 0; i < 4; ++i) {
    const float invl = 1.0f / l[i];
    float4 v0, v1;
    v0.x = o[i][0] * invl; v0.y = o[i][1] * invl;
    v0.z = o[i][2] * invl; v0.w = o[i][3] * invl;
    v1.x = o[i][4] * invl; v1.y = o[i][5] * invl;
    v1.z = o[i][6] * invl; v1.w = o[i][7] * invl;
    *(float4*)(Og + (size_t)(r0 + i) * DDIM + cx)     = v0;
    *(float4*)(Og + (size_t)(r0 + i) * DDIM + cx + 4) = v1;
  }
}

// ---------------------------------------------------------------------------
// Final: y = lif2(f32) + spikes2(u8); LayerNorm; float32 store.
// ---------------------------------------------------------------------------
__global__ __launch_bounds__(256)
void ln_kernel(const float* __restrict__ a, const uint8_t* __restrict__ s8,
               const float* __restrict__ gamma, const float* __restrict__ beta,
               float* __restrict__ out) {
  const int row = blockIdx.x;
  const int tid = threadIdx.x;
  const size_t base = (size_t)row * DDIM;
  const float4 av = *(const float4*)(a + base + tid * 4);
  const uchar4 sv = *(const uchar4*)(s8 + base + tid * 4);
  const float y0 = av.x + (float)sv.x, y1 = av.y + (float)sv.y;
  const float y2 = av.z + (float)sv.z, y3 = av.w + (float)sv.w;
  float s = (y0 + y1) + (y2 + y3);
  float q = (y0 * y0 + y1 * y1) + (y2 * y2 + y3 * y3);
#pragma unroll
  for (int off = 1; off < 64; off <<= 1) {
    s += __shfl_xor(s, off);
    q += __shfl_xor(q, off);
  }
  __shared__ float red[8];
  const int wid = tid >> 6;
  if ((tid & 63) == 0) { red[wid * 2] = s; red[wid * 2 + 1] = q; }
  __syncthreads();
  const float ts = (red[0] + red[2]) + (red[4] + red[6]);
  const float tq = (red[1] + red[3]) + (red[5] + red[7]);
  const float mu  = ts * (1.0f / 1024.0f);
  const float var = tq * (1.0f / 1024.0f) - mu * mu;
  const float rs  = 1.0f / sqrtf(var + 1e-5f);
  const int d = tid * 4;
  const float4 gv  = *(const float4*)(gamma + d);
  const float4 btv = *(const float4*)(beta + d);
  float4 r;
  r.x = (y0 - mu) * rs * gv.x + btv.x;
  r.y = (y1 - mu) * rs * gv.y + btv.y;
  r.z = (y2 - mu) * rs * gv.z + btv.z;
  r.w = (y3 - mu) * rs * gv.w + btv.w;
  *(float4*)(out + base + d) = r;
}

// ---------------------------------------------------------------------------
// Workspace: 3 f32 (A,C,D) + u8 spikes + 3 bf16 B-planes = 60.8 MB.
// ---------------------------------------------------------------------------
extern "C" void kernel_launch(void* const* d_in, const int* in_sizes, int n_in,
                              void* d_out, int out_size, void* d_ws, size_t ws_size,
                              hipStream_t stream) {
  const float* x       = (const float*)d_in[0];
  const float* context = (const float*)d_in[1];
  const float* Wg  = (const float*)d_in[2];
  const float* bg  = (const float*)d_in[3];
  const float* Wc  = (const float*)d_in[4];
  const float* Wq  = (const float*)d_in[5];
  const float* Wk  = (const float*)d_in[6];
  const float* Wv  = (const float*)d_in[7];
  const float* Wo  = (const float*)d_in[8];
  const float* Wm  = (const float*)d_in[9];
  const float* rWk = (const float*)d_in[10];
  const float* rWv = (const float*)d_in[11];
  const float* rWr = (const float*)d_in[12];
  const float* rWo = (const float*)d_in[13];
  const float* wd  = (const float*)d_in[14];
  const float* uf  = (const float*)d_in[15];
  const float* gamma = (const float*)d_in[16];
  const float* beta  = (const float*)d_in[17];
  float* out = (float*)d_out;   // reference output dtype = float32

  float* w  = (float*)d_ws;
  float*   bA = w;
  float*   bC = w + 1 * NELEM;
  float*   bD = w + 2 * NELEM;
  uint8_t* bS = (uint8_t*)(w + 3 * NELEM);           // u8 spikes
  ushort*  pB = (ushort*)((uint8_t*)d_ws + 3 * NELEM * 4 + NELEM); // B planes

  const dim3 ew(4096);
  const dim3 cg(16, 16);

  // Stage 1: thalamic gate
  cvt_b3t<<<cg, 256, 0, stream>>>(Wg, pB);
  gemm_k<0,0><<<256, 256, 0, stream>>>(x, pB, bA);
  cvt_b3t<<<cg, 256, 0, stream>>>(Wc, pB);
  gemm_k<1,0><<<256, 256, 0, stream>>>(context, pB, bA);
  gate_kernel<<<ew, 256, 0, stream>>>(x, bA, bg, bA);
  // Stage 2: LIF -> spikes2 (u8)
  lif_u8_kernel<<<16, 256, 0, stream>>>(bA, bS);
  // Stage 3: spike self-attention (O written in-place over Q)
  cvt_b3t<<<cg, 256, 0, stream>>>(Wq, pB);
  gemm_k<0,1><<<256, 256, 0, stream>>>(bS, pB, bA);
  cvt_b3t<<<cg, 256, 0, stream>>>(Wk, pB);
  gemm_k<0,1><<<256, 256, 0, stream>>>(bS, pB, bC);
  cvt_b3t<<<cg, 256, 0, stream>>>(Wv, pB);
  gemm_k<0,1><<<256, 256, 0, stream>>>(bS, pB, bD);
  flash_attn<<<512, 256, 0, stream>>>(bA, bC, bD, bA);
  cvt_b3t<<<cg, 256, 0, stream>>>(Wo, pB);
  gemm_k<0,0><<<256, 256, 0, stream>>>(bA, pB, bC);        // bC = attn_out@Wo
  // Stage 4: apical modulation
  cvt_b3t<<<cg, 256, 0, stream>>>(Wm, pB);
  gemm_k<0,0><<<256, 256, 0, stream>>>(context, pB, bA);
  mod_kernel<<<ew, 256, 0, stream>>>(bC, bA, bD);          // bD = modulated
  // Stage 5: RWKV
  cvt_b3t<<<cg, 256, 0, stream>>>(rWk, pB);
  gemm_k<0,0><<<256, 256, 0, stream>>>(bD, pB, bA);        // bA = k
  cvt_b3t<<<cg, 256, 0, stream>>>(rWv, pB);
  gemm_k<0,0><<<256, 256, 0, stream>>>(bD, pB, bC);        // bC = v
  rwkv_kernel<<<16, 256, 0, stream>>>(bA, bC, wd, uf, bA); // bA = wkv
  cvt_b3t<<<cg, 256, 0, stream>>>(rWr, pB);
  gemm_k<0,0><<<256, 256, 0, stream>>>(bD, pB, bC);        // bC = r
  rmul_kernel<<<ew, 256, 0, stream>>>(bC, bA, bA);         // bA = sig(r)*wkv
  cvt_b3t<<<cg, 256, 0, stream>>>(rWo, pB);
  gemm_k<0,0><<<256, 256, 0, stream>>>(bA, pB, bC);        // bC = recurrent
  // Stage 6: output LIF (in-place) + residual + LayerNorm
  lif_ip_kernel<<<16, 256, 0, stream>>>(bC);
  ln_kernel<<<4096, 256, 0, stream>>>(bC, bS, gamma, beta, out);
}

// Round 9
// 1883.647 us; speedup vs baseline: 1.7966x; 1.0663x over previous
//
#include <hip/hip_runtime.h>
#include <hip/hip_bf16.h>
#include <math.h>

// Problem dims (fixed)
#define BDIM 4
#define TDIM 1024
#define DDIM 1024
#define DH   128
#define NELEM ((size_t)BDIM * TDIM * DDIM)   // 4,194,304

typedef __attribute__((ext_vector_type(8))) short bfrag;   // 8 bf16 (4 VGPR)
typedef __attribute__((ext_vector_type(4))) float facc;    // 4 f32 acc

__device__ __forceinline__ ushort f2bf(float x) {          // f32 -> bf16 RNE
  union { float f; uint u; } v; v.f = x;
  const uint r = v.u + 0x7FFFu + ((v.u >> 16) & 1u);
  return (ushort)(r >> 16);
}
__device__ __forceinline__ float bf2f(ushort h) {
  union { uint u; float f; } v; v.u = ((uint)h) << 16; return v.f;
}

constexpr int GM = 4096, GN = 1024, GK = 1024;
constexpr int BM = 128, BN = 128, BK = 32;
constexpr int BKP = 40;                    // padded LDS k-dim (80 B rows)
constexpr int PSTR = 1024 * 1024;          // ushorts per B plane

// ---------------------------------------------------------------------------
// cvt_b3t: W[K][N] f32 -> 3 bf16 planes, blocked-transposed [K/32][N][32].
// ---------------------------------------------------------------------------
__global__ __launch_bounds__(256)
void cvt_b3t(const float* __restrict__ W, ushort* __restrict__ P) {
  __shared__ float Ls[64][68];
  const int t = threadIdx.x;
  const int k0 = blockIdx.x * 64, n0 = blockIdx.y * 64;
  const int r = t >> 4, c4 = (t & 15) << 2;
#pragma unroll
  for (int i = 0; i < 4; ++i)
    *(float4*)&Ls[r + i * 16][c4] =
        *(const float4*)(W + (size_t)(k0 + r + i * 16) * GN + n0 + c4);
  __syncthreads();
  const int n = t >> 2, kc = (t & 3) << 4;
  uint p1[8], p2[8], p3[8];
#pragma unroll
  for (int jj = 0; jj < 8; ++jj) {
    const float x0 = Ls[kc + 2 * jj][n], x1 = Ls[kc + 2 * jj + 1][n];
    const ushort a1 = f2bf(x0); float ra = x0 - bf2f(a1);
    const ushort b1 = f2bf(ra); ra = ra - bf2f(b1);
    const ushort c1 = f2bf(ra);
    const ushort a2 = f2bf(x1); float rb = x1 - bf2f(a2);
    const ushort b2 = f2bf(rb); rb = rb - bf2f(b2);
    const ushort c2 = f2bf(rb);
    p1[jj] = (uint)a1 | ((uint)a2 << 16);
    p2[jj] = (uint)b1 | ((uint)b2 << 16);
    p3[jj] = (uint)c1 | ((uint)c2 << 16);
  }
  const int kk = k0 + kc;
  ushort* d = P + (size_t)(kk >> 5) * (GN * 32) + (size_t)(n0 + n) * 32 + (kk & 31);
  *(uint4*)(d)             = *(uint4*)&p1[0];
  *(uint4*)(d + 8)         = *(uint4*)&p1[4];
  *(uint4*)(d + PSTR)      = *(uint4*)&p2[0];
  *(uint4*)(d + PSTR + 8)  = *(uint4*)&p2[4];
  *(uint4*)(d + 2 * PSTR)     = *(uint4*)&p3[0];
  *(uint4*)(d + 2 * PSTR + 8) = *(uint4*)&p3[4];
}

// ---------------------------------------------------------------------------
// GEMM via 3-way-split bf16 MFMA. 512 threads / 8 waves (2 waves/SIMD for
// latency hiding — R8 ran 1 wave/SIMD and sat at 4.4x the MFMA floor).
// Wave tile 64x32 (4x2 frags). Passes: accM += a1*b1; accC += a2*b1 + a3*b1
// + a1*b2 + a2*b2 + a1*b3 (all terms >= 2^-24 kept; noise ~3e-7, proven R8).
// AU8=1: A u8 spikes, exact bf16 -> 3 passes.
// ---------------------------------------------------------------------------
template<int EPI, int AU8>
__global__ __launch_bounds__(512)
void gemm_k(const void* __restrict__ Av, const ushort* __restrict__ pB,
            float* __restrict__ C) {
  __shared__ ushort As[3][BM][BKP];
  __shared__ ushort Bs[3][BN][BKP];
  const int tid = threadIdx.x;
  const int n  = blockIdx.x;              // 0..255; XCD = n & 7
  const int by = (n & 7) * 4 + (n >> 6);
  const int bx = (n >> 3) & 7;
  const int row0 = by * BM;
  const int col0 = bx * BN;

  const int sm  = tid & 127;              // staged A-row
  const int sk0 = (tid >> 7) << 3;        // 0,8,16,24

  const int wave = tid >> 6;              // 0..7
  const int lane = tid & 63;
  const int wrow = (wave >> 2) * 64;      // 0,64
  const int wcol = (wave & 3) * 32;       // 0,32,64,96
  const int lrow = lane & 15;
  const int kof  = (lane >> 4) * 8;

  facc accM[4][2], accC[4][2];
#pragma unroll
  for (int i = 0; i < 4; ++i)
#pragma unroll
    for (int j = 0; j < 2; ++j) { accM[i][j] = (facc)0.f; accC[i][j] = (facc)0.f; }

  float av[8];
  uint2 a8raw;
  uint4 bregs[3];

#define GLOADA(K0)                                                             \
  if (AU8) {                                                                   \
    a8raw = *(const uint2*)((const uint8_t*)Av + (size_t)(row0 + sm) * GK + (K0) + sk0); \
  } else {                                                                     \
    const float* Ap = (const float*)Av + (size_t)(row0 + sm) * GK + (K0) + sk0; \
    *(float4*)&av[0] = *(const float4*)(Ap);                                   \
    *(float4*)&av[4] = *(const float4*)(Ap + 4);                               \
  }

#define GLOADB(K0) {                                                           \
  const int kb = (K0) >> 5;                                                    \
  _Pragma("unroll")                                                            \
  for (int j = 0; j < 3; ++j) {                                                \
    const int u = tid + 512 * j;                                               \
    const int q = u & 3, nn = (u >> 2) & 127, p = u >> 9;                      \
    bregs[j] = *(const uint4*)(pB + (size_t)p * PSTR + (size_t)kb * (GN * 32)  \
                               + (size_t)(col0 + nn) * 32 + q * 8);            \
  }                                                                            \
}

#define SWRITE() {                                                             \
  if (AU8) {                                                                   \
    uint pk[4];                                                                \
    _Pragma("unroll")                                                          \
    for (int i = 0; i < 4; ++i) {                                              \
      const uint word = (i < 2) ? a8raw.x : a8raw.y;                           \
      const uint sh = (i & 1) * 16;                                            \
      const uint b0 = (word >> sh) & 0xFFu;                                    \
      const uint b1 = (word >> (sh + 8)) & 0xFFu;                              \
      pk[i] = (b0 * 0x3F80u) | ((b1 * 0x3F80u) << 16);                         \
    }                                                                          \
    *(uint4*)&As[0][sm][sk0] = *(uint4*)&pk[0];                                \
  } else {                                                                     \
    uint q1[4], q2[4], q3[4];                                                  \
    _Pragma("unroll")                                                          \
    for (int i = 0; i < 4; ++i) {                                              \
      const float x0 = av[2 * i], x1 = av[2 * i + 1];                          \
      const ushort a1 = f2bf(x0); float ra = x0 - bf2f(a1);                    \
      const ushort b1 = f2bf(ra); ra = ra - bf2f(b1);                          \
      const ushort c1 = f2bf(ra);                                              \
      const ushort a2 = f2bf(x1); float rb = x1 - bf2f(a2);                    \
      const ushort b2 = f2bf(rb); rb = rb - bf2f(b2);                          \
      const ushort c2 = f2bf(rb);                                              \
      q1[i] = (uint)a1 | ((uint)a2 << 16);                                     \
      q2[i] = (uint)b1 | ((uint)b2 << 16);                                     \
      q3[i] = (uint)c1 | ((uint)c2 << 16);                                     \
    }                                                                          \
    *(uint4*)&As[0][sm][sk0] = *(uint4*)&q1[0];                                \
    *(uint4*)&As[1][sm][sk0] = *(uint4*)&q2[0];                                \
    *(uint4*)&As[2][sm][sk0] = *(uint4*)&q3[0];                                \
  }                                                                            \
  _Pragma("unroll")                                                            \
  for (int j = 0; j < 3; ++j) {                                                \
    const int u = tid + 512 * j;                                               \
    const int q = u & 3, nn = (u >> 2) & 127, p = u >> 9;                      \
    *(uint4*)&Bs[p][nn][q * 8] = bregs[j];                                     \
  }                                                                            \
}

  GLOADA(0); GLOADB(0);
  for (int k0 = 0; k0 < GK; k0 += BK) {
    __syncthreads();                      // previous compute done with LDS
    SWRITE();
    const int kn = k0 + BK;
    if (kn < GK) { GLOADA(kn); GLOADB(kn); }   // lands during compute
    __syncthreads();
    bfrag fb0[2], fb1[2], fb2[2];
#pragma unroll
    for (int f = 0; f < 2; ++f) {
      fb0[f] = *(const bfrag*)&Bs[0][wcol + f * 16 + lrow][kof];
      fb1[f] = *(const bfrag*)&Bs[1][wcol + f * 16 + lrow][kof];
      fb2[f] = *(const bfrag*)&Bs[2][wcol + f * 16 + lrow][kof];
    }
#pragma unroll
    for (int mi = 0; mi < 4; ++mi) {
      const bfrag a1 = *(const bfrag*)&As[0][wrow + mi * 16 + lrow][kof];
      bfrag a2, a3;
      if (!AU8) {
        a2 = *(const bfrag*)&As[1][wrow + mi * 16 + lrow][kof];
        a3 = *(const bfrag*)&As[2][wrow + mi * 16 + lrow][kof];
      }
#pragma unroll
      for (int ni = 0; ni < 2; ++ni) {
        accM[mi][ni] = __builtin_amdgcn_mfma_f32_16x16x32_bf16(a1, fb0[ni], accM[mi][ni], 0, 0, 0);
        if (!AU8) {
          accC[mi][ni] = __builtin_amdgcn_mfma_f32_16x16x32_bf16(a2, fb0[ni], accC[mi][ni], 0, 0, 0);
          accC[mi][ni] = __builtin_amdgcn_mfma_f32_16x16x32_bf16(a3, fb0[ni], accC[mi][ni], 0, 0, 0);
        }
      }
#pragma unroll
      for (int ni = 0; ni < 2; ++ni) {
        accC[mi][ni] = __builtin_amdgcn_mfma_f32_16x16x32_bf16(a1, fb1[ni], accC[mi][ni], 0, 0, 0);
        if (!AU8)
          accC[mi][ni] = __builtin_amdgcn_mfma_f32_16x16x32_bf16(a2, fb1[ni], accC[mi][ni], 0, 0, 0);
      }
#pragma unroll
      for (int ni = 0; ni < 2; ++ni)
        accC[mi][ni] = __builtin_amdgcn_mfma_f32_16x16x32_bf16(a1, fb2[ni], accC[mi][ni], 0, 0, 0);
    }
  }
#undef GLOADA
#undef GLOADB
#undef SWRITE

  // epilogue: D frag col = lane&15, row = (lane>>4)*4 + reg (m89/m91).
#pragma unroll
  for (int mi = 0; mi < 4; ++mi) {
#pragma unroll
    for (int ni = 0; ni < 2; ++ni) {
      const int rbase = row0 + wrow + mi * 16 + (lane >> 4) * 4;
      const int cc    = col0 + wcol + ni * 16 + lrow;
      float* cp = C + (size_t)rbase * GN + cc;
#pragma unroll
      for (int r = 0; r < 4; ++r) {
        float v = accM[mi][ni][r] + accC[mi][ni][r];
        if (EPI == 1) v += cp[(size_t)r * GN];
        cp[(size_t)r * GN] = v;
      }
    }
  }
}

// ---------------------------------------------------------------------------
// Elementwise kernels (float4, 1 f4/thread, grid = NELEM/4/256 = 4096)
// ---------------------------------------------------------------------------
__device__ __forceinline__ float sigf(float z) { return 1.0f / (1.0f + expf(-z)); }

__global__ __launch_bounds__(256)
void gate_kernel(const float* __restrict__ x, const float* __restrict__ L,
                 const float* __restrict__ bg, float* __restrict__ out) {
  const int i4 = blockIdx.x * 256 + threadIdx.x;
  const float4 xv = ((const float4*)x)[i4];
  const float4 lv = ((const float4*)L)[i4];
  const float4 bv = ((const float4*)bg)[i4 & 255];
  float4 r;
  r.x = xv.x * (0.5f * sigf(lv.x + bv.x) + 0.5f);
  r.y = xv.y * (0.5f * sigf(lv.y + bv.y) + 0.5f);
  r.z = xv.z * (0.5f * sigf(lv.z + bv.z) + 0.5f);
  r.w = xv.w * (0.5f * sigf(lv.w + bv.w) + 0.5f);
  ((float4*)out)[i4] = r;
}

__global__ __launch_bounds__(256)
void mod_kernel(const float* __restrict__ a, const float* __restrict__ c,
                float* __restrict__ out) {
  const int i4 = blockIdx.x * 256 + threadIdx.x;
  const float4 av = ((const float4*)a)[i4];
  const float4 cv = ((const float4*)c)[i4];
  float4 r;
  r.x = av.x * (1.0f + tanhf(cv.x));
  r.y = av.y * (1.0f + tanhf(cv.y));
  r.z = av.z * (1.0f + tanhf(cv.z));
  r.w = av.w * (1.0f + tanhf(cv.w));
  ((float4*)out)[i4] = r;
}

__global__ __launch_bounds__(256)
void rmul_kernel(const float* __restrict__ rr, const float* __restrict__ wkv,
                 float* __restrict__ out) {
  const int i4 = blockIdx.x * 256 + threadIdx.x;
  const float4 rv = ((const float4*)rr)[i4];
  const float4 wv = ((const float4*)wkv)[i4];
  float4 r;
  r.x = sigf(rv.x) * wv.x;
  r.y = sigf(rv.y) * wv.y;
  r.z = sigf(rv.z) * wv.z;
  r.w = sigf(rv.w) * wv.w;
  ((float4*)out)[i4] = r;
}

// ---------------------------------------------------------------------------
// LIF scans: 1 thread/channel, 64 blocks x 64 thr (4x CU coverage vs R8's 16).
// ---------------------------------------------------------------------------
__global__ __launch_bounds__(64)
void lif_u8_kernel(const float* __restrict__ x, uint8_t* __restrict__ s) {
  const int c = blockIdx.x * 64 + threadIdx.x;       // 0..4095
  const size_t off = (size_t)(c >> 10) * TDIM * DDIM + (c & 1023);
  const float* xp = x + off;
  uint8_t* sp = s + off;
  float u = 0.f;
#pragma unroll 4
  for (int t = 0; t < TDIM; ++t) {
    const float xt = xp[(size_t)t * DDIM];
    u = __fadd_rn(__fmul_rn(0.9f, u), xt);
    const bool fire = (u >= 1.0f);
    sp[(size_t)t * DDIM] = fire ? 1 : 0;
    if (fire) u -= 1.0f;
  }
}

__global__ __launch_bounds__(64)
void lif_ip_kernel(float* __restrict__ x) {
  const int c = blockIdx.x * 64 + threadIdx.x;
  const size_t off = (size_t)(c >> 10) * TDIM * DDIM + (c & 1023);
  float* xp = x + off;
  float u = 0.f;
#pragma unroll 4
  for (int t = 0; t < TDIM; ++t) {
    const float xt = xp[(size_t)t * DDIM];
    u = __fadd_rn(__fmul_rn(0.9f, u), xt);
    const float sv = (u >= 1.0f) ? 1.0f : 0.0f;
    xp[(size_t)t * DDIM] = sv;
    u -= sv;
  }
}

// ---------------------------------------------------------------------------
// RWKV recurrence: 1 thread/channel, 64 blocks x 64 thr.
// ---------------------------------------------------------------------------
__global__ __launch_bounds__(64)
void rwkv_kernel(const float* __restrict__ k, const float* __restrict__ v,
                 const float* __restrict__ wd, const float* __restrict__ uf,
                 float* __restrict__ out) {
  const int c = blockIdx.x * 64 + threadIdx.x;
  const int d = c & 1023;
  const size_t off = (size_t)(c >> 10) * TDIM * DDIM + d;
  const float* kp = k + off;
  const float* vp = v + off;
  float* op = out + off;
  const float w = expf(wd[d]);
  const float u = uf[d];
  float aa = 0.f, bb = 0.f, pp = -1e30f;
  for (int t = 0; t < TDIM; ++t) {
    const float kt = kp[(size_t)t * DDIM];
    const float vt = vp[(size_t)t * DDIM];
    const float ww = __fadd_rn(u, kt);
    const float p  = fmaxf(pp, ww);
    float e1 = expf(__fsub_rn(pp, p));
    float e2 = expf(__fsub_rn(ww, p));
    const float num = __fadd_rn(__fmul_rn(e1, aa), __fmul_rn(e2, vt));
    const float den = __fadd_rn(__fmul_rn(e1, bb), e2);
    op[(size_t)t * DDIM] = num / den;
    const float ww2 = __fsub_rn(pp, w);
    const float p2  = fmaxf(ww2, kt);
    e1 = expf(__fsub_rn(ww2, p2));
    e2 = expf(__fsub_rn(kt, p2));
    aa = __fadd_rn(__fmul_rn(e1, aa), __fmul_rn(e2, vt));
    bb = __fadd_rn(__fmul_rn(e1, bb), e2);
    pp = p2;
  }
}

// ---------------------------------------------------------------------------
// Flash attention, f32, non-causal (unchanged — proven).
// ---------------------------------------------------------------------------
#define KT 32
__global__ __launch_bounds__(256)
void flash_attn(const float* __restrict__ Q, const float* __restrict__ K,
                const float* __restrict__ V, float* __restrict__ O) {
  __shared__ float Qs[64][DH + 4];
  __shared__ float Ks[KT][DH + 4];
  __shared__ float Vs[KT][DH + 4];
  __shared__ float Ps[64][KT + 4];
  const int tid = threadIdx.x;
  const int n    = blockIdx.x;
  const int xcd  = n & 7;
  const int idx  = n >> 3;
  const int qt   = idx & 15;
  const int grp4 = idx >> 4;
  const int p    = grp4 * 8 + xcd;
  const int b    = p >> 3, h = p & 7;
  const size_t base = ((size_t)b * TDIM) * DDIM + (size_t)h * DH;
  const float* Qg = Q + base + (size_t)(qt * 64) * DDIM;
#pragma unroll
  for (int q2 = 0; q2 < 8; ++q2) {
    const int f = tid + q2 * 256;
    const int r = f >> 5, c4 = (f & 31) << 2;
    *(float4*)&Qs[r][c4] = *(const float4*)(Qg + (size_t)r * DDIM + c4);
  }
  const int ty = tid >> 4, tx = tid & 15;
  const int r0 = ty * 4;
  const int cx = tx * 8;
  float m[4] = {-INFINITY, -INFINITY, -INFINITY, -INFINITY};
  float l[4] = {0.f, 0.f, 0.f, 0.f};
  float o[4][8];
#pragma unroll
  for (int i = 0; i < 4; ++i)
#pragma unroll
    for (int j = 0; j < 8; ++j) o[i][j] = 0.f;
  const float ISC = 0.08838834764831845f;

  for (int kt0 = 0; kt0 < TDIM; kt0 += KT) {
    __syncthreads();
    {
      const float* Kg = K + base + (size_t)kt0 * DDIM;
      const float* Vg = V + base + (size_t)kt0 * DDIM;
#pragma unroll
      for (int i = 0; i < 4; ++i) {
        const int f = tid + i * 256;
        const int rr = f >> 5, c4 = (f & 31) << 2;
        *(float4*)&Ks[rr][c4] = *(const float4*)(Kg + (size_t)rr * DDIM + c4);
        *(float4*)&Vs[rr][c4] = *(const float4*)(Vg + (size_t)rr * DDIM + c4);
      }
    }
    __syncthreads();
    float s[4][2];
#pragma unroll
    for (int i = 0; i < 4; ++i) { s[i][0] = 0.f; s[i][1] = 0.f; }
    for (int kd = 0; kd < DH; kd += 4) {
      float4 qa[4];
#pragma unroll
      for (int i = 0; i < 4; ++i) qa[i] = *(const float4*)&Qs[r0 + i][kd];
      const float4 kb0 = *(const float4*)&Ks[tx][kd];
      const float4 kb1 = *(const float4*)&Ks[tx + 16][kd];
#pragma unroll
      for (int i = 0; i < 4; ++i) {
        s[i][0] = fmaf(qa[i].x, kb0.x, s[i][0]);
        s[i][0] = fmaf(qa[i].y, kb0.y, s[i][0]);
        s[i][0] = fmaf(qa[i].z, kb0.z, s[i][0]);
        s[i][0] = fmaf(qa[i].w, kb0.w, s[i][0]);
        s[i][1] = fmaf(qa[i].x, kb1.x, s[i][1]);
        s[i][1] = fmaf(qa[i].y, kb1.y, s[i][1]);
        s[i][1] = fmaf(qa[i].z, kb1.z, s[i][1]);
        s[i][1] = fmaf(qa[i].w, kb1.w, s[i][1]);
      }
    }
#pragma unroll
    for (int i = 0; i < 4; ++i) {
      const float sc0 = s[i][0] * ISC, sc1 = s[i][1] * ISC;
      float mx = fmaxf(sc0, sc1);
      mx = fmaxf(mx, __shfl_xor(mx, 1, 16));
      mx = fmaxf(mx, __shfl_xor(mx, 2, 16));
      mx = fmaxf(mx, __shfl_xor(mx, 4, 16));
      mx = fmaxf(mx, __shfl_xor(mx, 8, 16));
      const float mn = fmaxf(m[i], mx);
      const float rf = expf(m[i] - mn);
      const float p0 = expf(sc0 - mn), p1 = expf(sc1 - mn);
      float ps = p0 + p1;
      ps += __shfl_xor(ps, 1, 16);
      ps += __shfl_xor(ps, 2, 16);
      ps += __shfl_xor(ps, 4, 16);
      ps += __shfl_xor(ps, 8, 16);
      l[i] = l[i] * rf + ps;
      m[i] = mn;
#pragma unroll
      for (int jj = 0; jj < 8; ++jj) o[i][jj] *= rf;
      Ps[r0 + i][tx]      = p0;
      Ps[r0 + i][tx + 16] = p1;
    }
    __syncthreads();
#pragma unroll
    for (int s4 = 0; s4 < KT; s4 += 4) {
      float pav[4][4];
#pragma unroll
      for (int i = 0; i < 4; ++i) {
        const float4 pa = *(const float4*)&Ps[r0 + i][s4];
        pav[i][0] = pa.x; pav[i][1] = pa.y; pav[i][2] = pa.z; pav[i][3] = pa.w;
      }
#pragma unroll
      for (int u2 = 0; u2 < 4; ++u2) {
        const float4 v0 = *(const float4*)&Vs[s4 + u2][cx];
        const float4 v1 = *(const float4*)&Vs[s4 + u2][cx + 4];
#pragma unroll
        for (int i = 0; i < 4; ++i) {
          const float p_ = pav[i][u2];
          o[i][0] = fmaf(p_, v0.x, o[i][0]);
          o[i][1] = fmaf(p_, v0.y, o[i][1]);
          o[i][2] = fmaf(p_, v0.z, o[i][2]);
          o[i][3] = fmaf(p_, v0.w, o[i][3]);
          o[i][4] = fmaf(p_, v1.x, o[i][4]);
          o[i][5] = fmaf(p_, v1.y, o[i][5]);
          o[i][6] = fmaf(p_, v1.z, o[i][6]);
          o[i][7] = fmaf(p_, v1.w, o[i][7]);
        }
      }
    }
  }
  float* Og = O + base + (size_t)(qt * 64) * DDIM;
#pragma unroll
  for (int i = 0; i < 4; ++i) {
    const float invl = 1.0f / l[i];
    float4 v0, v1;
    v0.x = o[i][0] * invl; v0.y = o[i][1] * invl;
    v0.z = o[i][2] * invl; v0.w = o[i][3] * invl;
    v1.x = o[i][4] * invl; v1.y = o[i][5] * invl;
    v1.z = o[i][6] * invl; v1.w = o[i][7] * invl;
    *(float4*)(Og + (size_t)(r0 + i) * DDIM + cx)     = v0;
    *(float4*)(Og + (size_t)(r0 + i) * DDIM + cx + 4) = v1;
  }
}

// ---------------------------------------------------------------------------
// Final: y = lif2(f32) + spikes2(u8); LayerNorm; float32 store.
// ---------------------------------------------------------------------------
__global__ __launch_bounds__(256)
void ln_kernel(const float* __restrict__ a, const uint8_t* __restrict__ s8,
               const float* __restrict__ gamma, const float* __restrict__ beta,
               float* __restrict__ out) {
  const int row = blockIdx.x;
  const int tid = threadIdx.x;
  const size_t base = (size_t)row * DDIM;
  const float4 av = *(const float4*)(a + base + tid * 4);
  const uchar4 sv = *(const uchar4*)(s8 + base + tid * 4);
  const float y0 = av.x + (float)sv.x, y1 = av.y + (float)sv.y;
  const float y2 = av.z + (float)sv.z, y3 = av.w + (float)sv.w;
  float s = (y0 + y1) + (y2 + y3);
  float q = (y0 * y0 + y1 * y1) + (y2 * y2 + y3 * y3);
#pragma unroll
  for (int off = 1; off < 64; off <<= 1) {
    s += __shfl_xor(s, off);
    q += __shfl_xor(q, off);
  }
  __shared__ float red[8];
  const int wid = tid >> 6;
  if ((tid & 63) == 0) { red[wid * 2] = s; red[wid * 2 + 1] = q; }
  __syncthreads();
  const float ts = (red[0] + red[2]) + (red[4] + red[6]);
  const float tq = (red[1] + red[3]) + (red[5] + red[7]);
  const float mu  = ts * (1.0f / 1024.0f);
  const float var = tq * (1.0f / 1024.0f) - mu * mu;
  const float rs  = 1.0f / sqrtf(var + 1e-5f);
  const int d = tid * 4;
  const float4 gv  = *(const float4*)(gamma + d);
  const float4 btv = *(const float4*)(beta + d);
  float4 r;
  r.x = (y0 - mu) * rs * gv.x + btv.x;
  r.y = (y1 - mu) * rs * gv.y + btv.y;
  r.z = (y2 - mu) * rs * gv.z + btv.z;
  r.w = (y3 - mu) * rs * gv.w + btv.w;
  *(float4*)(out + base + d) = r;
}

// ---------------------------------------------------------------------------
// Workspace: 3 f32 (A,C,D) + u8 spikes + 3 bf16 B-planes = 60.8 MB.
// ---------------------------------------------------------------------------
extern "C" void kernel_launch(void* const* d_in, const int* in_sizes, int n_in,
                              void* d_out, int out_size, void* d_ws, size_t ws_size,
                              hipStream_t stream) {
  const float* x       = (const float*)d_in[0];
  const float* context = (const float*)d_in[1];
  const float* Wg  = (const float*)d_in[2];
  const float* bg  = (const float*)d_in[3];
  const float* Wc  = (const float*)d_in[4];
  const float* Wq  = (const float*)d_in[5];
  const float* Wk  = (const float*)d_in[6];
  const float* Wv  = (const float*)d_in[7];
  const float* Wo  = (const float*)d_in[8];
  const float* Wm  = (const float*)d_in[9];
  const float* rWk = (const float*)d_in[10];
  const float* rWv = (const float*)d_in[11];
  const float* rWr = (const float*)d_in[12];
  const float* rWo = (const float*)d_in[13];
  const float* wd  = (const float*)d_in[14];
  const float* uf  = (const float*)d_in[15];
  const float* gamma = (const float*)d_in[16];
  const float* beta  = (const float*)d_in[17];
  float* out = (float*)d_out;   // reference output dtype = float32

  float* w  = (float*)d_ws;
  float*   bA = w;
  float*   bC = w + 1 * NELEM;
  float*   bD = w + 2 * NELEM;
  uint8_t* bS = (uint8_t*)(w + 3 * NELEM);           // u8 spikes
  ushort*  pB = (ushort*)((uint8_t*)d_ws + 3 * NELEM * 4 + NELEM); // B planes

  const dim3 ew(4096);
  const dim3 cg(16, 16);

  // Stage 1: thalamic gate
  cvt_b3t<<<cg, 256, 0, stream>>>(Wg, pB);
  gemm_k<0,0><<<256, 512, 0, stream>>>(x, pB, bA);
  cvt_b3t<<<cg, 256, 0, stream>>>(Wc, pB);
  gemm_k<1,0><<<256, 512, 0, stream>>>(context, pB, bA);
  gate_kernel<<<ew, 256, 0, stream>>>(x, bA, bg, bA);
  // Stage 2: LIF -> spikes2 (u8)
  lif_u8_kernel<<<64, 64, 0, stream>>>(bA, bS);
  // Stage 3: spike self-attention (O written in-place over Q)
  cvt_b3t<<<cg, 256, 0, stream>>>(Wq, pB);
  gemm_k<0,1><<<256, 512, 0, stream>>>(bS, pB, bA);
  cvt_b3t<<<cg, 256, 0, stream>>>(Wk, pB);
  gemm_k<0,1><<<256, 512, 0, stream>>>(bS, pB, bC);
  cvt_b3t<<<cg, 256, 0, stream>>>(Wv, pB);
  gemm_k<0,1><<<256, 512, 0, stream>>>(bS, pB, bD);
  flash_attn<<<512, 256, 0, stream>>>(bA, bC, bD, bA);
  cvt_b3t<<<cg, 256, 0, stream>>>(Wo, pB);
  gemm_k<0,0><<<256, 512, 0, stream>>>(bA, pB, bC);        // bC = attn_out@Wo
  // Stage 4: apical modulation
  cvt_b3t<<<cg, 256, 0, stream>>>(Wm, pB);
  gemm_k<0,0><<<256, 512, 0, stream>>>(context, pB, bA);
  mod_kernel<<<ew, 256, 0, stream>>>(bC, bA, bD);          // bD = modulated
  // Stage 5: RWKV
  cvt_b3t<<<cg, 256, 0, stream>>>(rWk, pB);
  gemm_k<0,0><<<256, 512, 0, stream>>>(bD, pB, bA);        // bA = k
  cvt_b3t<<<cg, 256, 0, stream>>>(rWv, pB);
  gemm_k<0,0><<<256, 512, 0, stream>>>(bD, pB, bC);        // bC = v
  rwkv_kernel<<<64, 64, 0, stream>>>(bA, bC, wd, uf, bA);  // bA = wkv
  cvt_b3t<<<cg, 256, 0, stream>>>(rWr, pB);
  gemm_k<0,0><<<256, 512, 0, stream>>>(bD, pB, bC);        // bC = r
  rmul_kernel<<<ew, 256, 0, stream>>>(bC, bA, bA);         // bA = sig(r)*wkv
  cvt_b3t<<<cg, 256, 0, stream>>>(rWo, pB);
  gemm_k<0,0><<<256, 512, 0, stream>>>(bA, pB, bC);        // bC = recurrent
  // Stage 6: output LIF (in-place) + residual + LayerNorm
  lif_ip_kernel<<<64, 64, 0, stream>>>(bC);
  ln_kernel<<<4096, 256, 0, stream>>>(bC, bS, gamma, beta, out);
}

// Round 10
// 1664.232 us; speedup vs baseline: 2.0335x; 1.1318x over previous
//
#include <hip/hip_runtime.h>
#include <hip/hip_bf16.h>
#include <math.h>

// Problem dims (fixed)
#define BDIM 4
#define TDIM 1024
#define DDIM 1024
#define DH   128
#define NELEM ((size_t)BDIM * TDIM * DDIM)   // 4,194,304

typedef __attribute__((ext_vector_type(8))) short bfrag;   // 8 bf16 (4 VGPR)
typedef __attribute__((ext_vector_type(4))) float facc;    // 4 f32 acc

__device__ __forceinline__ ushort f2bf(float x) {          // f32 -> bf16 RNE
  union { float f; uint u; } v; v.f = x;
  const uint r = v.u + 0x7FFFu + ((v.u >> 16) & 1u);
  return (ushort)(r >> 16);
}
__device__ __forceinline__ float bf2f(ushort h) {
  union { uint u; float f; } v; v.u = ((uint)h) << 16; return v.f;
}

constexpr int GM = 4096, GN = 1024, GK = 1024;
constexpr int BM = 128, BK = 32;
constexpr int BKP = 40;                    // padded LDS k-dim (80 B rows)

// ---------------------------------------------------------------------------
// cvt_b3t: up to 3 weight matrices [1024][1024] f32 -> 3-way bf16 split
// planes, blocked-transposed [kTot/32][N=1024][32].
// blockIdx.z selects matrix; dst = P + z*zstride (ushorts), k-offset z*zkoff
// (K-merge mode). Plane stride = kTot*GN ushorts.
// ---------------------------------------------------------------------------
__global__ __launch_bounds__(256)
void cvt_b3t(const float* __restrict__ W0, const float* __restrict__ W1,
             const float* __restrict__ W2, ushort* __restrict__ P,
             int zstride, int zkoff, int kTot) {
  __shared__ float Ls[64][68];
  const int z = blockIdx.z;
  const float* W = (z == 0) ? W0 : (z == 1 ? W1 : W2);
  ushort* Pz = P + (size_t)z * zstride;
  const size_t PS = (size_t)kTot * GN;     // ushorts per plane
  const int t = threadIdx.x;
  const int k0 = blockIdx.x * 64, n0 = blockIdx.y * 64;
  const int r = t >> 4, c4 = (t & 15) << 2;
#pragma unroll
  for (int i = 0; i < 4; ++i)
    *(float4*)&Ls[r + i * 16][c4] =
        *(const float4*)(W + (size_t)(k0 + r + i * 16) * GN + n0 + c4);
  __syncthreads();
  const int n = t >> 2, kc = (t & 3) << 4;
  uint p1[8], p2[8], p3[8];
#pragma unroll
  for (int jj = 0; jj < 8; ++jj) {
    const float x0 = Ls[kc + 2 * jj][n], x1 = Ls[kc + 2 * jj + 1][n];
    const ushort a1 = f2bf(x0); float ra = x0 - bf2f(a1);
    const ushort b1 = f2bf(ra); ra = ra - bf2f(b1);
    const ushort c1 = f2bf(ra);
    const ushort a2 = f2bf(x1); float rb = x1 - bf2f(a2);
    const ushort b2 = f2bf(rb); rb = rb - bf2f(b2);
    const ushort c2 = f2bf(rb);
    p1[jj] = (uint)a1 | ((uint)a2 << 16);
    p2[jj] = (uint)b1 | ((uint)b2 << 16);
    p3[jj] = (uint)c1 | ((uint)c2 << 16);
  }
  const int kk = k0 + kc + z * zkoff;
  ushort* d = Pz + (size_t)(kk >> 5) * (GN * 32) + (size_t)(n0 + n) * 32 + (kk & 31);
  *(uint4*)(d)          = *(uint4*)&p1[0];
  *(uint4*)(d + 8)      = *(uint4*)&p1[4];
  *(uint4*)(d + PS)     = *(uint4*)&p2[0];
  *(uint4*)(d + PS + 8) = *(uint4*)&p2[4];
  *(uint4*)(d + 2 * PS)     = *(uint4*)&p3[0];
  *(uint4*)(d + 2 * PS + 8) = *(uint4*)&p3[4];
}

// ---------------------------------------------------------------------------
// GEMM via 3-way-split bf16 MFMA. Tile 128x64, 256 thr / 4 waves, LDS 46 KB
// -> 3 INDEPENDENT blocks/CU (R9 lesson: same-block waves are barrier-locked;
// occupancy must come from separate blocks).
// NMAT: N-merged matrices (per-matrix B planes + output buffer).
// KTOT=2048: K-merged A (Av for k<1024, Av2 after) — gate stage.
// Passes per K-step (unchanged numerics): accM += a1*b1; accC += a2*b1 +
// a3*b1 + a1*b2 + a2*b2 + a1*b3.  AU8: A exact in bf16 -> 3 passes.
// ---------------------------------------------------------------------------
template<int EPI, int AU8, int NMAT, int KTOT>
__global__ __launch_bounds__(256)
void gemm_k(const void* __restrict__ Av, const void* __restrict__ Av2,
            const ushort* __restrict__ pB,
            float* __restrict__ C0, float* __restrict__ C1,
            float* __restrict__ C2) {
  constexpr size_t PS = (size_t)KTOT * GN;   // ushorts per plane
  __shared__ ushort As[3][BM][BKP];
  __shared__ ushort Bs[3][64][BKP];
  const int tid = threadIdx.x;
  const int n   = blockIdx.x;               // 512*NMAT blocks; XCD = n & 7
  const int xcd = n & 7;
  const int idx = n >> 3;
  const int by  = xcd * 4 + (idx & 3);      // 0..31
  const int bx  = idx >> 2;                 // 0..16*NMAT-1
  const int mat = bx >> 4;
  const int row0 = by * BM;
  const int col0 = (bx & 15) * 64;
  const ushort* pBm = pB + (size_t)mat * 3 * PS;
  float* C = (mat == 0) ? C0 : (mat == 1 ? C1 : C2);

  const int sm  = tid & 127;                // staged A-row
  const int sk0 = (tid >> 7) << 4;          // 0 or 16

  const int wave = tid >> 6;                // 0..3
  const int lane = tid & 63;
  const int wrow = (wave >> 1) * 64;        // 0,64
  const int wcol = (wave & 1) * 32;         // 0,32
  const int lrow = lane & 15;
  const int kof  = (lane >> 4) * 8;

  facc accM[4][2], accC[4][2];
#pragma unroll
  for (int i = 0; i < 4; ++i)
#pragma unroll
    for (int j = 0; j < 2; ++j) { accM[i][j] = (facc)0.f; accC[i][j] = (facc)0.f; }

  float av[16];
  uint4 a8raw;
  uint4 bregs[3];

  auto gloadA = [&](int K0) {
    const void* src = Av; int k = K0;
    if (KTOT > 1024 && K0 >= 1024) { src = Av2; k = K0 - 1024; }
    if (AU8) {
      a8raw = *(const uint4*)((const uint8_t*)src + (size_t)(row0 + sm) * 1024 + k + sk0);
    } else {
      const float* Ap = (const float*)src + (size_t)(row0 + sm) * 1024 + k + sk0;
      *(float4*)&av[0]  = *(const float4*)(Ap);
      *(float4*)&av[4]  = *(const float4*)(Ap + 4);
      *(float4*)&av[8]  = *(const float4*)(Ap + 8);
      *(float4*)&av[12] = *(const float4*)(Ap + 12);
    }
  };
  auto gloadB = [&](int K0) {
    const int kb = K0 >> 5;
#pragma unroll
    for (int j = 0; j < 3; ++j) {
      const int u = tid + 256 * j;
      const int q = u & 3, nn = (u >> 2) & 63, p = u >> 8;
      bregs[j] = *(const uint4*)(pBm + (size_t)p * PS + (size_t)kb * (GN * 32)
                                 + (size_t)(col0 + nn) * 32 + q * 8);
    }
  };
  auto swrite = [&]() {
    if (AU8) {
      const uint w4[4] = {a8raw.x, a8raw.y, a8raw.z, a8raw.w};
      uint pk[8];
#pragma unroll
      for (int i = 0; i < 8; ++i) {
        const uint b0 = (w4[i >> 1] >> ((i & 1) * 16)) & 0xFFu;
        const uint b1 = (w4[i >> 1] >> ((i & 1) * 16 + 8)) & 0xFFu;
        pk[i] = (b0 * 0x3F80u) | ((b1 * 0x3F80u) << 16);
      }
      *(uint4*)&As[0][sm][sk0]     = *(uint4*)&pk[0];
      *(uint4*)&As[0][sm][sk0 + 8] = *(uint4*)&pk[4];
    } else {
      uint q1[8], q2[8], q3[8];
#pragma unroll
      for (int i = 0; i < 8; ++i) {
        const float x0 = av[2 * i], x1 = av[2 * i + 1];
        const ushort a1 = f2bf(x0); float ra = x0 - bf2f(a1);
        const ushort b1 = f2bf(ra); ra = ra - bf2f(b1);
        const ushort c1 = f2bf(ra);
        const ushort a2 = f2bf(x1); float rb = x1 - bf2f(a2);
        const ushort b2 = f2bf(rb); rb = rb - bf2f(b2);
        const ushort c2 = f2bf(rb);
        q1[i] = (uint)a1 | ((uint)a2 << 16);
        q2[i] = (uint)b1 | ((uint)b2 << 16);
        q3[i] = (uint)c1 | ((uint)c2 << 16);
      }
      *(uint4*)&As[0][sm][sk0]     = *(uint4*)&q1[0];
      *(uint4*)&As[0][sm][sk0 + 8] = *(uint4*)&q1[4];
      *(uint4*)&As[1][sm][sk0]     = *(uint4*)&q2[0];
      *(uint4*)&As[1][sm][sk0 + 8] = *(uint4*)&q2[4];
      *(uint4*)&As[2][sm][sk0]     = *(uint4*)&q3[0];
      *(uint4*)&As[2][sm][sk0 + 8] = *(uint4*)&q3[4];
    }
#pragma unroll
    for (int j = 0; j < 3; ++j) {
      const int u = tid + 256 * j;
      const int q = u & 3, nn = (u >> 2) & 63, p = u >> 8;
      *(uint4*)&Bs[p][nn][q * 8] = bregs[j];
    }
  };

  gloadA(0); gloadB(0);
  for (int k0 = 0; k0 < KTOT; k0 += BK) {
    __syncthreads();                      // previous compute done with LDS
    swrite();
    const int kn = k0 + BK;
    if (kn < KTOT) { gloadA(kn); gloadB(kn); }   // lands during compute
    __syncthreads();
    bfrag fb0[2], fb1[2], fb2[2];
#pragma unroll
    for (int f = 0; f < 2; ++f) {
      fb0[f] = *(const bfrag*)&Bs[0][wcol + f * 16 + lrow][kof];
      fb1[f] = *(const bfrag*)&Bs[1][wcol + f * 16 + lrow][kof];
      fb2[f] = *(const bfrag*)&Bs[2][wcol + f * 16 + lrow][kof];
    }
#pragma unroll
    for (int mi = 0; mi < 4; ++mi) {
      const bfrag a1 = *(const bfrag*)&As[0][wrow + mi * 16 + lrow][kof];
      bfrag a2, a3;
      if (!AU8) {
        a2 = *(const bfrag*)&As[1][wrow + mi * 16 + lrow][kof];
        a3 = *(const bfrag*)&As[2][wrow + mi * 16 + lrow][kof];
      }
#pragma unroll
      for (int ni = 0; ni < 2; ++ni) {
        accM[mi][ni] = __builtin_amdgcn_mfma_f32_16x16x32_bf16(a1, fb0[ni], accM[mi][ni], 0, 0, 0);
        if (!AU8) {
          accC[mi][ni] = __builtin_amdgcn_mfma_f32_16x16x32_bf16(a2, fb0[ni], accC[mi][ni], 0, 0, 0);
          accC[mi][ni] = __builtin_amdgcn_mfma_f32_16x16x32_bf16(a3, fb0[ni], accC[mi][ni], 0, 0, 0);
        }
      }
#pragma unroll
      for (int ni = 0; ni < 2; ++ni) {
        accC[mi][ni] = __builtin_amdgcn_mfma_f32_16x16x32_bf16(a1, fb1[ni], accC[mi][ni], 0, 0, 0);
        if (!AU8)
          accC[mi][ni] = __builtin_amdgcn_mfma_f32_16x16x32_bf16(a2, fb1[ni], accC[mi][ni], 0, 0, 0);
      }
#pragma unroll
      for (int ni = 0; ni < 2; ++ni)
        accC[mi][ni] = __builtin_amdgcn_mfma_f32_16x16x32_bf16(a1, fb2[ni], accC[mi][ni], 0, 0, 0);
    }
  }

  // epilogue: D frag col = lane&15, row = (lane>>4)*4 + reg (m89/m91).
#pragma unroll
  for (int mi = 0; mi < 4; ++mi) {
#pragma unroll
    for (int ni = 0; ni < 2; ++ni) {
      const int rbase = row0 + wrow + mi * 16 + (lane >> 4) * 4;
      const int cc    = col0 + wcol + ni * 16 + lrow;
      float* cp = C + (size_t)rbase * GN + cc;
#pragma unroll
      for (int r = 0; r < 4; ++r) {
        float v = accM[mi][ni][r] + accC[mi][ni][r];
        if (EPI == 1) v += cp[(size_t)r * GN];
        cp[(size_t)r * GN] = v;
      }
    }
  }
}

// ---------------------------------------------------------------------------
// Elementwise kernels (float4, 1 f4/thread, grid = NELEM/4/256 = 4096)
// ---------------------------------------------------------------------------
__device__ __forceinline__ float sigf(float z) { return 1.0f / (1.0f + expf(-z)); }

__global__ __launch_bounds__(256)
void gate_kernel(const float* __restrict__ x, const float* __restrict__ L,
                 const float* __restrict__ bg, float* __restrict__ out) {
  const int i4 = blockIdx.x * 256 + threadIdx.x;
  const float4 xv = ((const float4*)x)[i4];
  const float4 lv = ((const float4*)L)[i4];
  const float4 bv = ((const float4*)bg)[i4 & 255];
  float4 r;
  r.x = xv.x * (0.5f * sigf(lv.x + bv.x) + 0.5f);
  r.y = xv.y * (0.5f * sigf(lv.y + bv.y) + 0.5f);
  r.z = xv.z * (0.5f * sigf(lv.z + bv.z) + 0.5f);
  r.w = xv.w * (0.5f * sigf(lv.w + bv.w) + 0.5f);
  ((float4*)out)[i4] = r;
}

__global__ __launch_bounds__(256)
void mod_kernel(const float* __restrict__ a, const float* __restrict__ c,
                float* __restrict__ out) {
  const int i4 = blockIdx.x * 256 + threadIdx.x;
  const float4 av = ((const float4*)a)[i4];
  const float4 cv = ((const float4*)c)[i4];
  float4 r;
  r.x = av.x * (1.0f + tanhf(cv.x));
  r.y = av.y * (1.0f + tanhf(cv.y));
  r.z = av.z * (1.0f + tanhf(cv.z));
  r.w = av.w * (1.0f + tanhf(cv.w));
  ((float4*)out)[i4] = r;
}

__global__ __launch_bounds__(256)
void rmul_kernel(const float* __restrict__ rr, const float* __restrict__ wkv,
                 float* __restrict__ out) {
  const int i4 = blockIdx.x * 256 + threadIdx.x;
  const float4 rv = ((const float4*)rr)[i4];
  const float4 wv = ((const float4*)wkv)[i4];
  float4 r;
  r.x = sigf(rv.x) * wv.x;
  r.y = sigf(rv.y) * wv.y;
  r.z = sigf(rv.z) * wv.z;
  r.w = sigf(rv.w) * wv.w;
  ((float4*)out)[i4] = r;
}

// ---------------------------------------------------------------------------
// LIF scans: latency-bound serial loops -> software-pipelined (prefetch next
// 8 timesteps into regs while computing current 8). Op order unchanged.
// ---------------------------------------------------------------------------
__global__ __launch_bounds__(64)
void lif_u8_kernel(const float* __restrict__ x, uint8_t* __restrict__ s) {
  const int c = blockIdx.x * 64 + threadIdx.x;
  const size_t off = (size_t)(c >> 10) * TDIM * DDIM + (c & 1023);
  const float* xp = x + off;
  uint8_t* sp = s + off;
  float u = 0.f;
  float cur[8];
#pragma unroll
  for (int i = 0; i < 8; ++i) cur[i] = xp[(size_t)i * DDIM];
  for (int t = 0; t < TDIM; t += 8) {
    float nxt[8];
    if (t + 8 < TDIM) {
#pragma unroll
      for (int i = 0; i < 8; ++i) nxt[i] = xp[(size_t)(t + 8 + i) * DDIM];
    }
#pragma unroll
    for (int i = 0; i < 8; ++i) {
      u = __fadd_rn(__fmul_rn(0.9f, u), cur[i]);
      const bool fire = (u >= 1.0f);
      sp[(size_t)(t + i) * DDIM] = fire ? 1 : 0;
      if (fire) u -= 1.0f;
    }
#pragma unroll
    for (int i = 0; i < 8; ++i) cur[i] = nxt[i];
  }
}

__global__ __launch_bounds__(64)
void lif_ip_kernel(float* __restrict__ x) {
  const int c = blockIdx.x * 64 + threadIdx.x;
  const size_t off = (size_t)(c >> 10) * TDIM * DDIM + (c & 1023);
  float* xp = x + off;
  float u = 0.f;
  float cur[8];
#pragma unroll
  for (int i = 0; i < 8; ++i) cur[i] = xp[(size_t)i * DDIM];
  for (int t = 0; t < TDIM; t += 8) {
    float nxt[8];
    if (t + 8 < TDIM) {
#pragma unroll
      for (int i = 0; i < 8; ++i) nxt[i] = xp[(size_t)(t + 8 + i) * DDIM];
    }
#pragma unroll
    for (int i = 0; i < 8; ++i) {
      u = __fadd_rn(__fmul_rn(0.9f, u), cur[i]);
      const float sv = (u >= 1.0f) ? 1.0f : 0.0f;
      xp[(size_t)(t + i) * DDIM] = sv;
      u -= sv;
    }
#pragma unroll
    for (int i = 0; i < 8; ++i) cur[i] = nxt[i];
  }
}

// ---------------------------------------------------------------------------
// RWKV recurrence, software-pipelined (prefetch next 4 k/v pairs).
// ---------------------------------------------------------------------------
__global__ __launch_bounds__(64)
void rwkv_kernel(const float* __restrict__ k, const float* __restrict__ v,
                 const float* __restrict__ wd, const float* __restrict__ uf,
                 float* __restrict__ out) {
  const int c = blockIdx.x * 64 + threadIdx.x;
  const int d = c & 1023;
  const size_t off = (size_t)(c >> 10) * TDIM * DDIM + d;
  const float* kp = k + off;
  const float* vp = v + off;
  float* op = out + off;
  const float w = expf(wd[d]);
  const float u = uf[d];
  float aa = 0.f, bb = 0.f, pp = -1e30f;
  float kc[4], vc[4];
#pragma unroll
  for (int i = 0; i < 4; ++i) {
    kc[i] = kp[(size_t)i * DDIM];
    vc[i] = vp[(size_t)i * DDIM];
  }
  for (int t = 0; t < TDIM; t += 4) {
    float kn[4], vn[4];
    if (t + 4 < TDIM) {
#pragma unroll
      for (int i = 0; i < 4; ++i) {
        kn[i] = kp[(size_t)(t + 4 + i) * DDIM];
        vn[i] = vp[(size_t)(t + 4 + i) * DDIM];
      }
    }
#pragma unroll
    for (int i = 0; i < 4; ++i) {
      const float kt = kc[i], vt = vc[i];
      const float ww = __fadd_rn(u, kt);
      const float p  = fmaxf(pp, ww);
      float e1 = expf(__fsub_rn(pp, p));
      float e2 = expf(__fsub_rn(ww, p));
      const float num = __fadd_rn(__fmul_rn(e1, aa), __fmul_rn(e2, vt));
      const float den = __fadd_rn(__fmul_rn(e1, bb), e2);
      op[(size_t)(t + i) * DDIM] = num / den;
      const float ww2 = __fsub_rn(pp, w);
      const float p2  = fmaxf(ww2, kt);
      e1 = expf(__fsub_rn(ww2, p2));
      e2 = expf(__fsub_rn(kt, p2));
      aa = __fadd_rn(__fmul_rn(e1, aa), __fmul_rn(e2, vt));
      bb = __fadd_rn(__fmul_rn(e1, bb), e2);
      pp = p2;
    }
#pragma unroll
    for (int i = 0; i < 4; ++i) { kc[i] = kn[i]; vc[i] = vn[i]; }
  }
}

// ---------------------------------------------------------------------------
// Flash attention, f32, non-causal (unchanged — MFMA rewrite next round).
// ---------------------------------------------------------------------------
#define KT 32
__global__ __launch_bounds__(256)
void flash_attn(const float* __restrict__ Q, const float* __restrict__ K,
                const float* __restrict__ V, float* __restrict__ O) {
  __shared__ float Qs[64][DH + 4];
  __shared__ float Ks[KT][DH + 4];
  __shared__ float Vs[KT][DH + 4];
  __shared__ float Ps[64][KT + 4];
  const int tid = threadIdx.x;
  const int n    = blockIdx.x;
  const int xcd  = n & 7;
  const int idx  = n >> 3;
  const int qt   = idx & 15;
  const int grp4 = idx >> 4;
  const int p    = grp4 * 8 + xcd;
  const int b    = p >> 3, h = p & 7;
  const size_t base = ((size_t)b * TDIM) * DDIM + (size_t)h * DH;
  const float* Qg = Q + base + (size_t)(qt * 64) * DDIM;
#pragma unroll
  for (int q2 = 0; q2 < 8; ++q2) {
    const int f = tid + q2 * 256;
    const int r = f >> 5, c4 = (f & 31) << 2;
    *(float4*)&Qs[r][c4] = *(const float4*)(Qg + (size_t)r * DDIM + c4);
  }
  const int ty = tid >> 4, tx = tid & 15;
  const int r0 = ty * 4;
  const int cx = tx * 8;
  float m[4] = {-INFINITY, -INFINITY, -INFINITY, -INFINITY};
  float l[4] = {0.f, 0.f, 0.f, 0.f};
  float o[4][8];
#pragma unroll
  for (int i = 0; i < 4; ++i)
#pragma unroll
    for (int j = 0; j < 8; ++j) o[i][j] = 0.f;
  const float ISC = 0.08838834764831845f;

  for (int kt0 = 0; kt0 < TDIM; kt0 += KT) {
    __syncthreads();
    {
      const float* Kg = K + base + (size_t)kt0 * DDIM;
      const float* Vg = V + base + (size_t)kt0 * DDIM;
#pragma unroll
      for (int i = 0; i < 4; ++i) {
        const int f = tid + i * 256;
        const int rr = f >> 5, c4 = (f & 31) << 2;
        *(float4*)&Ks[rr][c4] = *(const float4*)(Kg + (size_t)rr * DDIM + c4);
        *(float4*)&Vs[rr][c4] = *(const float4*)(Vg + (size_t)rr * DDIM + c4);
      }
    }
    __syncthreads();
    float s[4][2];
#pragma unroll
    for (int i = 0; i < 4; ++i) { s[i][0] = 0.f; s[i][1] = 0.f; }
    for (int kd = 0; kd < DH; kd += 4) {
      float4 qa[4];
#pragma unroll
      for (int i = 0; i < 4; ++i) qa[i] = *(const float4*)&Qs[r0 + i][kd];
      const float4 kb0 = *(const float4*)&Ks[tx][kd];
      const float4 kb1 = *(const float4*)&Ks[tx + 16][kd];
#pragma unroll
      for (int i = 0; i < 4; ++i) {
        s[i][0] = fmaf(qa[i].x, kb0.x, s[i][0]);
        s[i][0] = fmaf(qa[i].y, kb0.y, s[i][0]);
        s[i][0] = fmaf(qa[i].z, kb0.z, s[i][0]);
        s[i][0] = fmaf(qa[i].w, kb0.w, s[i][0]);
        s[i][1] = fmaf(qa[i].x, kb1.x, s[i][1]);
        s[i][1] = fmaf(qa[i].y, kb1.y, s[i][1]);
        s[i][1] = fmaf(qa[i].z, kb1.z, s[i][1]);
        s[i][1] = fmaf(qa[i].w, kb1.w, s[i][1]);
      }
    }
#pragma unroll
    for (int i = 0; i < 4; ++i) {
      const float sc0 = s[i][0] * ISC, sc1 = s[i][1] * ISC;
      float mx = fmaxf(sc0, sc1);
      mx = fmaxf(mx, __shfl_xor(mx, 1, 16));
      mx = fmaxf(mx, __shfl_xor(mx, 2, 16));
      mx = fmaxf(mx, __shfl_xor(mx, 4, 16));
      mx = fmaxf(mx, __shfl_xor(mx, 8, 16));
      const float mn = fmaxf(m[i], mx);
      const float rf = expf(m[i] - mn);
      const float p0 = expf(sc0 - mn), p1 = expf(sc1 - mn);
      float ps = p0 + p1;
      ps += __shfl_xor(ps, 1, 16);
      ps += __shfl_xor(ps, 2, 16);
      ps += __shfl_xor(ps, 4, 16);
      ps += __shfl_xor(ps, 8, 16);
      l[i] = l[i] * rf + ps;
      m[i] = mn;
#pragma unroll
      for (int jj = 0; jj < 8; ++jj) o[i][jj] *= rf;
      Ps[r0 + i][tx]      = p0;
      Ps[r0 + i][tx + 16] = p1;
    }
    __syncthreads();
#pragma unroll
    for (int s4 = 0; s4 < KT; s4 += 4) {
      float pav[4][4];
#pragma unroll
      for (int i = 0; i < 4; ++i) {
        const float4 pa = *(const float4*)&Ps[r0 + i][s4];
        pav[i][0] = pa.x; pav[i][1] = pa.y; pav[i][2] = pa.z; pav[i][3] = pa.w;
      }
#pragma unroll
      for (int u2 = 0; u2 < 4; ++u2) {
        const float4 v0 = *(const float4*)&Vs[s4 + u2][cx];
        const float4 v1 = *(const float4*)&Vs[s4 + u2][cx + 4];
#pragma unroll
        for (int i = 0; i < 4; ++i) {
          const float p_ = pav[i][u2];
          o[i][0] = fmaf(p_, v0.x, o[i][0]);
          o[i][1] = fmaf(p_, v0.y, o[i][1]);
          o[i][2] = fmaf(p_, v0.z, o[i][2]);
          o[i][3] = fmaf(p_, v0.w, o[i][3]);
          o[i][4] = fmaf(p_, v1.x, o[i][4]);
          o[i][5] = fmaf(p_, v1.y, o[i][5]);
          o[i][6] = fmaf(p_, v1.z, o[i][6]);
          o[i][7] = fmaf(p_, v1.w, o[i][7]);
        }
      }
    }
  }
  float* Og = O + base + (size_t)(qt * 64) * DDIM;
#pragma unroll
  for (int i = 0; i < 4; ++i) {
    const float invl = 1.0f / l[i];
    float4 v0, v1;
    v0.x = o[i][0] * invl; v0.y = o[i][1] * invl;
    v0.z = o[i][2] * invl; v0.w = o[i][3] * invl;
    v1.x = o[i][4] * invl; v1.y = o[i][5] * invl;
    v1.z = o[i][6] * invl; v1.w = o[i][7] * invl;
    *(float4*)(Og + (size_t)(r0 + i) * DDIM + cx)     = v0;
    *(float4*)(Og + (size_t)(r0 + i) * DDIM + cx + 4) = v1;
  }
}

// ---------------------------------------------------------------------------
// Final: y = lif2(f32) + spikes2(u8); LayerNorm; float32 store.
// ---------------------------------------------------------------------------
__global__ __launch_bounds__(256)
void ln_kernel(const float* __restrict__ a, const uint8_t* __restrict__ s8,
               const float* __restrict__ gamma, const float* __restrict__ beta,
               float* __restrict__ out) {
  const int row = blockIdx.x;
  const int tid = threadIdx.x;
  const size_t base = (size_t)row * DDIM;
  const float4 av = *(const float4*)(a + base + tid * 4);
  const uchar4 sv = *(const uchar4*)(s8 + base + tid * 4);
  const float y0 = av.x + (float)sv.x, y1 = av.y + (float)sv.y;
  const float y2 = av.z + (float)sv.z, y3 = av.w + (float)sv.w;
  float s = (y0 + y1) + (y2 + y3);
  float q = (y0 * y0 + y1 * y1) + (y2 * y2 + y3 * y3);
#pragma unroll
  for (int off = 1; off < 64; off <<= 1) {
    s += __shfl_xor(s, off);
    q += __shfl_xor(q, off);
  }
  __shared__ float red[8];
  const int wid = tid >> 6;
  if ((tid & 63) == 0) { red[wid * 2] = s; red[wid * 2 + 1] = q; }
  __syncthreads();
  const float ts = (red[0] + red[2]) + (red[4] + red[6]);
  const float tq = (red[1] + red[3]) + (red[5] + red[7]);
  const float mu  = ts * (1.0f / 1024.0f);
  const float var = tq * (1.0f / 1024.0f) - mu * mu;
  const float rs  = 1.0f / sqrtf(var + 1e-5f);
  const int d = tid * 4;
  const float4 gv  = *(const float4*)(gamma + d);
  const float4 btv = *(const float4*)(beta + d);
  float4 r;
  r.x = (y0 - mu) * rs * gv.x + btv.x;
  r.y = (y1 - mu) * rs * gv.y + btv.y;
  r.z = (y2 - mu) * rs * gv.z + btv.z;
  r.w = (y3 - mu) * rs * gv.w + btv.w;
  *(float4*)(out + base + d) = r;
}

// ---------------------------------------------------------------------------
// Workspace: 3 f32 (A,C,D) 50.3 MB + u8 spikes 4.2 MB + B planes 18 MB
// = 72.8 MB (<= 84 MB bound proven by R1/R3 bit-identical behavior).
// ---------------------------------------------------------------------------
extern "C" void kernel_launch(void* const* d_in, const int* in_sizes, int n_in,
                              void* d_out, int out_size, void* d_ws, size_t ws_size,
                              hipStream_t stream) {
  const float* x       = (const float*)d_in[0];
  const float* context = (const float*)d_in[1];
  const float* Wg  = (const float*)d_in[2];
  const float* bg  = (const float*)d_in[3];
  const float* Wc  = (const float*)d_in[4];
  const float* Wq  = (const float*)d_in[5];
  const float* Wk  = (const float*)d_in[6];
  const float* Wv  = (const float*)d_in[7];
  const float* Wo  = (const float*)d_in[8];
  const float* Wm  = (const float*)d_in[9];
  const float* rWk = (const float*)d_in[10];
  const float* rWv = (const float*)d_in[11];
  const float* rWr = (const float*)d_in[12];
  const float* rWo = (const float*)d_in[13];
  const float* wd  = (const float*)d_in[14];
  const float* uf  = (const float*)d_in[15];
  const float* gamma = (const float*)d_in[16];
  const float* beta  = (const float*)d_in[17];
  float* out = (float*)d_out;   // reference output dtype = float32

  float* w  = (float*)d_ws;
  float*   bA = w;
  float*   bC = w + 1 * NELEM;
  float*   bD = w + 2 * NELEM;
  uint8_t* bS = (uint8_t*)(w + 3 * NELEM);                          // u8 spikes
  ushort*  pB = (ushort*)((uint8_t*)d_ws + 3 * NELEM * 4 + NELEM);  // B planes

  const dim3 ew(4096);
  constexpr int M1 = 1024 * 1024;   // ushorts per 1024-K plane

  // Stage 1: thalamic gate — single K=2048 GEMM over [x | context]
  cvt_b3t<<<dim3(16, 16, 2), 256, 0, stream>>>(Wg, Wc, nullptr, pB, 0, 1024, 2048);
  gemm_k<0, 0, 1, 2048><<<512, 256, 0, stream>>>(x, context, pB, bA, nullptr, nullptr);
  gate_kernel<<<ew, 256, 0, stream>>>(x, bA, bg, bA);
  // Stage 2: LIF -> spikes2 (u8)
  lif_u8_kernel<<<64, 64, 0, stream>>>(bA, bS);
  // Stage 3: spike self-attention — Q,K,V in ONE N-merged launch
  cvt_b3t<<<dim3(16, 16, 3), 256, 0, stream>>>(Wq, Wk, Wv, pB, 3 * M1, 0, 1024);
  gemm_k<0, 1, 3, 1024><<<1536, 256, 0, stream>>>(bS, nullptr, pB, bA, bC, bD);
  flash_attn<<<512, 256, 0, stream>>>(bA, bC, bD, bA);
  cvt_b3t<<<dim3(16, 16, 1), 256, 0, stream>>>(Wo, nullptr, nullptr, pB, 0, 0, 1024);
  gemm_k<0, 0, 1, 1024><<<512, 256, 0, stream>>>(bA, nullptr, pB, bC, nullptr, nullptr);
  // Stage 4: apical modulation
  cvt_b3t<<<dim3(16, 16, 1), 256, 0, stream>>>(Wm, nullptr, nullptr, pB, 0, 0, 1024);
  gemm_k<0, 0, 1, 1024><<<512, 256, 0, stream>>>(context, nullptr, pB, bA, nullptr, nullptr);
  mod_kernel<<<ew, 256, 0, stream>>>(bC, bA, bD);          // bD = modulated
  // Stage 5: RWKV — k,v N-merged
  cvt_b3t<<<dim3(16, 16, 2), 256, 0, stream>>>(rWk, rWv, nullptr, pB, 3 * M1, 0, 1024);
  gemm_k<0, 0, 2, 1024><<<1024, 256, 0, stream>>>(bD, nullptr, pB, bA, bC, nullptr);
  rwkv_kernel<<<64, 64, 0, stream>>>(bA, bC, wd, uf, bA);  // bA = wkv
  cvt_b3t<<<dim3(16, 16, 1), 256, 0, stream>>>(rWr, nullptr, nullptr, pB, 0, 0, 1024);
  gemm_k<0, 0, 1, 1024><<<512, 256, 0, stream>>>(bD, nullptr, pB, bC, nullptr, nullptr);
  rmul_kernel<<<ew, 256, 0, stream>>>(bC, bA, bA);         // bA = sig(r)*wkv
  cvt_b3t<<<dim3(16, 16, 1), 256, 0, stream>>>(rWo, nullptr, nullptr, pB, 0, 0, 1024);
  gemm_k<0, 0, 1, 1024><<<512, 256, 0, stream>>>(bA, nullptr, pB, bC, nullptr, nullptr);
  // Stage 6: output LIF (in-place) + residual + LayerNorm
  lif_ip_kernel<<<64, 64, 0, stream>>>(bC);
  ln_kernel<<<4096, 256, 0, stream>>>(bC, bS, gamma, beta, out);
}

// Round 11
// 1591.129 us; speedup vs baseline: 2.1269x; 1.0459x over previous
//
#include <hip/hip_runtime.h>
#include <hip/hip_bf16.h>
#include <math.h>

// Problem dims (fixed)
#define BDIM 4
#define TDIM 1024
#define DDIM 1024
#define DH   128
#define NELEM ((size_t)BDIM * TDIM * DDIM)   // 4,194,304

typedef __attribute__((ext_vector_type(8))) short bfrag;   // 8 bf16 (4 VGPR)
typedef __attribute__((ext_vector_type(4))) float facc;    // 4 f32 acc

__device__ __forceinline__ ushort f2bf(float x) {          // f32 -> bf16 RNE
  union { float f; uint u; } v; v.f = x;
  const uint r = v.u + 0x7FFFu + ((v.u >> 16) & 1u);
  return (ushort)(r >> 16);
}
__device__ __forceinline__ float bf2f(ushort h) {
  union { uint u; float f; } v; v.u = ((uint)h) << 16; return v.f;
}
__device__ __forceinline__ void split3(float x, ushort& s1, ushort& s2, ushort& s3) {
  s1 = f2bf(x); float r = x - bf2f(s1);
  s2 = f2bf(r); r = r - bf2f(s2);
  s3 = f2bf(r);
}

constexpr int GM = 4096, GN = 1024, GK = 1024;
constexpr int BM = 128, BK = 32;
constexpr int BKP = 40;                    // padded LDS k-dim (80 B rows)

// ---------------------------------------------------------------------------
// cvt_b3t: up to 3 weight matrices [1024][1024] f32 -> 3-way bf16 split
// planes, blocked-transposed [kTot/32][N=1024][32].
// ---------------------------------------------------------------------------
__global__ __launch_bounds__(256)
void cvt_b3t(const float* __restrict__ W0, const float* __restrict__ W1,
             const float* __restrict__ W2, ushort* __restrict__ P,
             int zstride, int zkoff, int kTot) {
  __shared__ float Ls[64][68];
  const int z = blockIdx.z;
  const float* W = (z == 0) ? W0 : (z == 1 ? W1 : W2);
  ushort* Pz = P + (size_t)z * zstride;
  const size_t PS = (size_t)kTot * GN;     // ushorts per plane
  const int t = threadIdx.x;
  const int k0 = blockIdx.x * 64, n0 = blockIdx.y * 64;
  const int r = t >> 4, c4 = (t & 15) << 2;
#pragma unroll
  for (int i = 0; i < 4; ++i)
    *(float4*)&Ls[r + i * 16][c4] =
        *(const float4*)(W + (size_t)(k0 + r + i * 16) * GN + n0 + c4);
  __syncthreads();
  const int n = t >> 2, kc = (t & 3) << 4;
  uint p1[8], p2[8], p3[8];
#pragma unroll
  for (int jj = 0; jj < 8; ++jj) {
    const float x0 = Ls[kc + 2 * jj][n], x1 = Ls[kc + 2 * jj + 1][n];
    ushort a1, b1, c1, a2, b2, c2;
    split3(x0, a1, b1, c1);
    split3(x1, a2, b2, c2);
    p1[jj] = (uint)a1 | ((uint)a2 << 16);
    p2[jj] = (uint)b1 | ((uint)b2 << 16);
    p3[jj] = (uint)c1 | ((uint)c2 << 16);
  }
  const int kk = k0 + kc + z * zkoff;
  ushort* d = Pz + (size_t)(kk >> 5) * (GN * 32) + (size_t)(n0 + n) * 32 + (kk & 31);
  *(uint4*)(d)          = *(uint4*)&p1[0];
  *(uint4*)(d + 8)      = *(uint4*)&p1[4];
  *(uint4*)(d + PS)     = *(uint4*)&p2[0];
  *(uint4*)(d + PS + 8) = *(uint4*)&p2[4];
  *(uint4*)(d + 2 * PS)     = *(uint4*)&p3[0];
  *(uint4*)(d + 2 * PS + 8) = *(uint4*)&p3[4];
}

// ---------------------------------------------------------------------------
// GEMM via 3-way-split bf16 MFMA (proven R8-R10). Tile 128x64, 4 waves,
// 46 KB LDS -> 3 blocks/CU. NMAT: N-merged. KTOT=2048: K-merged A.
// ---------------------------------------------------------------------------
template<int EPI, int AU8, int NMAT, int KTOT>
__global__ __launch_bounds__(256)
void gemm_k(const void* __restrict__ Av, const void* __restrict__ Av2,
            const ushort* __restrict__ pB,
            float* __restrict__ C0, float* __restrict__ C1,
            float* __restrict__ C2) {
  constexpr size_t PS = (size_t)KTOT * GN;   // ushorts per plane
  __shared__ ushort As[3][BM][BKP];
  __shared__ ushort Bs[3][64][BKP];
  const int tid = threadIdx.x;
  const int n   = blockIdx.x;
  const int xcd = n & 7;
  const int idx = n >> 3;
  const int by  = xcd * 4 + (idx & 3);
  const int bx  = idx >> 2;
  const int mat = bx >> 4;
  const int row0 = by * BM;
  const int col0 = (bx & 15) * 64;
  const ushort* pBm = pB + (size_t)mat * 3 * PS;
  float* C = (mat == 0) ? C0 : (mat == 1 ? C1 : C2);

  const int sm  = tid & 127;
  const int sk0 = (tid >> 7) << 4;

  const int wave = tid >> 6;
  const int lane = tid & 63;
  const int wrow = (wave >> 1) * 64;
  const int wcol = (wave & 1) * 32;
  const int lrow = lane & 15;
  const int kof  = (lane >> 4) * 8;

  facc accM[4][2], accC[4][2];
#pragma unroll
  for (int i = 0; i < 4; ++i)
#pragma unroll
    for (int j = 0; j < 2; ++j) { accM[i][j] = (facc)0.f; accC[i][j] = (facc)0.f; }

  float av[16];
  uint4 a8raw;
  uint4 bregs[3];

  auto gloadA = [&](int K0) {
    const void* src = Av; int k = K0;
    if (KTOT > 1024 && K0 >= 1024) { src = Av2; k = K0 - 1024; }
    if (AU8) {
      a8raw = *(const uint4*)((const uint8_t*)src + (size_t)(row0 + sm) * 1024 + k + sk0);
    } else {
      const float* Ap = (const float*)src + (size_t)(row0 + sm) * 1024 + k + sk0;
      *(float4*)&av[0]  = *(const float4*)(Ap);
      *(float4*)&av[4]  = *(const float4*)(Ap + 4);
      *(float4*)&av[8]  = *(const float4*)(Ap + 8);
      *(float4*)&av[12] = *(const float4*)(Ap + 12);
    }
  };
  auto gloadB = [&](int K0) {
    const int kb = K0 >> 5;
#pragma unroll
    for (int j = 0; j < 3; ++j) {
      const int u = tid + 256 * j;
      const int q = u & 3, nn = (u >> 2) & 63, p = u >> 8;
      bregs[j] = *(const uint4*)(pBm + (size_t)p * PS + (size_t)kb * (GN * 32)
                                 + (size_t)(col0 + nn) * 32 + q * 8);
    }
  };
  auto swrite = [&]() {
    if (AU8) {
      const uint w4[4] = {a8raw.x, a8raw.y, a8raw.z, a8raw.w};
      uint pk[8];
#pragma unroll
      for (int i = 0; i < 8; ++i) {
        const uint b0 = (w4[i >> 1] >> ((i & 1) * 16)) & 0xFFu;
        const uint b1 = (w4[i >> 1] >> ((i & 1) * 16 + 8)) & 0xFFu;
        pk[i] = (b0 * 0x3F80u) | ((b1 * 0x3F80u) << 16);
      }
      *(uint4*)&As[0][sm][sk0]     = *(uint4*)&pk[0];
      *(uint4*)&As[0][sm][sk0 + 8] = *(uint4*)&pk[4];
    } else {
      uint q1[8], q2[8], q3[8];
#pragma unroll
      for (int i = 0; i < 8; ++i) {
        ushort a1, b1, c1, a2, b2, c2;
        split3(av[2 * i], a1, b1, c1);
        split3(av[2 * i + 1], a2, b2, c2);
        q1[i] = (uint)a1 | ((uint)a2 << 16);
        q2[i] = (uint)b1 | ((uint)b2 << 16);
        q3[i] = (uint)c1 | ((uint)c2 << 16);
      }
      *(uint4*)&As[0][sm][sk0]     = *(uint4*)&q1[0];
      *(uint4*)&As[0][sm][sk0 + 8] = *(uint4*)&q1[4];
      *(uint4*)&As[1][sm][sk0]     = *(uint4*)&q2[0];
      *(uint4*)&As[1][sm][sk0 + 8] = *(uint4*)&q2[4];
      *(uint4*)&As[2][sm][sk0]     = *(uint4*)&q3[0];
      *(uint4*)&As[2][sm][sk0 + 8] = *(uint4*)&q3[4];
    }
#pragma unroll
    for (int j = 0; j < 3; ++j) {
      const int u = tid + 256 * j;
      const int q = u & 3, nn = (u >> 2) & 63, p = u >> 8;
      *(uint4*)&Bs[p][nn][q * 8] = bregs[j];
    }
  };

  gloadA(0); gloadB(0);
  for (int k0 = 0; k0 < KTOT; k0 += BK) {
    __syncthreads();
    swrite();
    const int kn = k0 + BK;
    if (kn < KTOT) { gloadA(kn); gloadB(kn); }
    __syncthreads();
    bfrag fb0[2], fb1[2], fb2[2];
#pragma unroll
    for (int f = 0; f < 2; ++f) {
      fb0[f] = *(const bfrag*)&Bs[0][wcol + f * 16 + lrow][kof];
      fb1[f] = *(const bfrag*)&Bs[1][wcol + f * 16 + lrow][kof];
      fb2[f] = *(const bfrag*)&Bs[2][wcol + f * 16 + lrow][kof];
    }
#pragma unroll
    for (int mi = 0; mi < 4; ++mi) {
      const bfrag a1 = *(const bfrag*)&As[0][wrow + mi * 16 + lrow][kof];
      bfrag a2, a3;
      if (!AU8) {
        a2 = *(const bfrag*)&As[1][wrow + mi * 16 + lrow][kof];
        a3 = *(const bfrag*)&As[2][wrow + mi * 16 + lrow][kof];
      }
#pragma unroll
      for (int ni = 0; ni < 2; ++ni) {
        accM[mi][ni] = __builtin_amdgcn_mfma_f32_16x16x32_bf16(a1, fb0[ni], accM[mi][ni], 0, 0, 0);
        if (!AU8) {
          accC[mi][ni] = __builtin_amdgcn_mfma_f32_16x16x32_bf16(a2, fb0[ni], accC[mi][ni], 0, 0, 0);
          accC[mi][ni] = __builtin_amdgcn_mfma_f32_16x16x32_bf16(a3, fb0[ni], accC[mi][ni], 0, 0, 0);
        }
      }
#pragma unroll
      for (int ni = 0; ni < 2; ++ni) {
        accC[mi][ni] = __builtin_amdgcn_mfma_f32_16x16x32_bf16(a1, fb1[ni], accC[mi][ni], 0, 0, 0);
        if (!AU8)
          accC[mi][ni] = __builtin_amdgcn_mfma_f32_16x16x32_bf16(a2, fb1[ni], accC[mi][ni], 0, 0, 0);
      }
#pragma unroll
      for (int ni = 0; ni < 2; ++ni)
        accC[mi][ni] = __builtin_amdgcn_mfma_f32_16x16x32_bf16(a1, fb2[ni], accC[mi][ni], 0, 0, 0);
    }
  }

#pragma unroll
  for (int mi = 0; mi < 4; ++mi) {
#pragma unroll
    for (int ni = 0; ni < 2; ++ni) {
      const int rbase = row0 + wrow + mi * 16 + (lane >> 4) * 4;
      const int cc    = col0 + wcol + ni * 16 + lrow;
      float* cp = C + (size_t)rbase * GN + cc;
#pragma unroll
      for (int r = 0; r < 4; ++r) {
        float v = accM[mi][ni][r] + accC[mi][ni][r];
        if (EPI == 1) v += cp[(size_t)r * GN];
        cp[(size_t)r * GN] = v;
      }
    }
  }
}

// ---------------------------------------------------------------------------
// Elementwise kernels
// ---------------------------------------------------------------------------
__device__ __forceinline__ float sigf(float z) { return 1.0f / (1.0f + expf(-z)); }

__global__ __launch_bounds__(256)
void gate_kernel(const float* __restrict__ x, const float* __restrict__ L,
                 const float* __restrict__ bg, float* __restrict__ out) {
  const int i4 = blockIdx.x * 256 + threadIdx.x;
  const float4 xv = ((const float4*)x)[i4];
  const float4 lv = ((const float4*)L)[i4];
  const float4 bv = ((const float4*)bg)[i4 & 255];
  float4 r;
  r.x = xv.x * (0.5f * sigf(lv.x + bv.x) + 0.5f);
  r.y = xv.y * (0.5f * sigf(lv.y + bv.y) + 0.5f);
  r.z = xv.z * (0.5f * sigf(lv.z + bv.z) + 0.5f);
  r.w = xv.w * (0.5f * sigf(lv.w + bv.w) + 0.5f);
  ((float4*)out)[i4] = r;
}

__global__ __launch_bounds__(256)
void mod_kernel(const float* __restrict__ a, const float* __restrict__ c,
                float* __restrict__ out) {
  const int i4 = blockIdx.x * 256 + threadIdx.x;
  const float4 av = ((const float4*)a)[i4];
  const float4 cv = ((const float4*)c)[i4];
  float4 r;
  r.x = av.x * (1.0f + tanhf(cv.x));
  r.y = av.y * (1.0f + tanhf(cv.y));
  r.z = av.z * (1.0f + tanhf(cv.z));
  r.w = av.w * (1.0f + tanhf(cv.w));
  ((float4*)out)[i4] = r;
}

__global__ __launch_bounds__(256)
void rmul_kernel(const float* __restrict__ rr, const float* __restrict__ wkv,
                 float* __restrict__ out) {
  const int i4 = blockIdx.x * 256 + threadIdx.x;
  const float4 rv = ((const float4*)rr)[i4];
  const float4 wv = ((const float4*)wkv)[i4];
  float4 r;
  r.x = sigf(rv.x) * wv.x;
  r.y = sigf(rv.y) * wv.y;
  r.z = sigf(rv.z) * wv.z;
  r.w = sigf(rv.w) * wv.w;
  ((float4*)out)[i4] = r;
}

// ---------------------------------------------------------------------------
// LIF scans (software-pipelined, proven R10)
// ---------------------------------------------------------------------------
__global__ __launch_bounds__(64)
void lif_u8_kernel(const float* __restrict__ x, uint8_t* __restrict__ s) {
  const int c = blockIdx.x * 64 + threadIdx.x;
  const size_t off = (size_t)(c >> 10) * TDIM * DDIM + (c & 1023);
  const float* xp = x + off;
  uint8_t* sp = s + off;
  float u = 0.f;
  float cur[8];
#pragma unroll
  for (int i = 0; i < 8; ++i) cur[i] = xp[(size_t)i * DDIM];
  for (int t = 0; t < TDIM; t += 8) {
    float nxt[8];
    if (t + 8 < TDIM) {
#pragma unroll
      for (int i = 0; i < 8; ++i) nxt[i] = xp[(size_t)(t + 8 + i) * DDIM];
    }
#pragma unroll
    for (int i = 0; i < 8; ++i) {
      u = __fadd_rn(__fmul_rn(0.9f, u), cur[i]);
      const bool fire = (u >= 1.0f);
      sp[(size_t)(t + i) * DDIM] = fire ? 1 : 0;
      if (fire) u -= 1.0f;
    }
#pragma unroll
    for (int i = 0; i < 8; ++i) cur[i] = nxt[i];
  }
}

__global__ __launch_bounds__(64)
void lif_ip_kernel(float* __restrict__ x) {
  const int c = blockIdx.x * 64 + threadIdx.x;
  const size_t off = (size_t)(c >> 10) * TDIM * DDIM + (c & 1023);
  float* xp = x + off;
  float u = 0.f;
  float cur[8];
#pragma unroll
  for (int i = 0; i < 8; ++i) cur[i] = xp[(size_t)i * DDIM];
  for (int t = 0; t < TDIM; t += 8) {
    float nxt[8];
    if (t + 8 < TDIM) {
#pragma unroll
      for (int i = 0; i < 8; ++i) nxt[i] = xp[(size_t)(t + 8 + i) * DDIM];
    }
#pragma unroll
    for (int i = 0; i < 8; ++i) {
      u = __fadd_rn(__fmul_rn(0.9f, u), cur[i]);
      const float sv = (u >= 1.0f) ? 1.0f : 0.0f;
      xp[(size_t)(t + i) * DDIM] = sv;
      u -= sv;
    }
#pragma unroll
    for (int i = 0; i < 8; ++i) cur[i] = nxt[i];
  }
}

__global__ __launch_bounds__(64)
void rwkv_kernel(const float* __restrict__ k, const float* __restrict__ v,
                 const float* __restrict__ wd, const float* __restrict__ uf,
                 float* __restrict__ out) {
  const int c = blockIdx.x * 64 + threadIdx.x;
  const int d = c & 1023;
  const size_t off = (size_t)(c >> 10) * TDIM * DDIM + d;
  const float* kp = k + off;
  const float* vp = v + off;
  float* op = out + off;
  const float w = expf(wd[d]);
  const float u = uf[d];
  float aa = 0.f, bb = 0.f, pp = -1e30f;
  float kc[4], vc[4];
#pragma unroll
  for (int i = 0; i < 4; ++i) {
    kc[i] = kp[(size_t)i * DDIM];
    vc[i] = vp[(size_t)i * DDIM];
  }
  for (int t = 0; t < TDIM; t += 4) {
    float kn[4], vn[4];
    if (t + 4 < TDIM) {
#pragma unroll
      for (int i = 0; i < 4; ++i) {
        kn[i] = kp[(size_t)(t + 4 + i) * DDIM];
        vn[i] = vp[(size_t)(t + 4 + i) * DDIM];
      }
    }
#pragma unroll
    for (int i = 0; i < 4; ++i) {
      const float kt = kc[i], vt = vc[i];
      const float ww = __fadd_rn(u, kt);
      const float p  = fmaxf(pp, ww);
      float e1 = expf(__fsub_rn(pp, p));
      float e2 = expf(__fsub_rn(ww, p));
      const float num = __fadd_rn(__fmul_rn(e1, aa), __fmul_rn(e2, vt));
      const float den = __fadd_rn(__fmul_rn(e1, bb), e2);
      op[(size_t)(t + i) * DDIM] = num / den;
      const float ww2 = __fsub_rn(pp, w);
      const float p2  = fmaxf(ww2, kt);
      e1 = expf(__fsub_rn(ww2, p2));
      e2 = expf(__fsub_rn(kt, p2));
      aa = __fadd_rn(__fmul_rn(e1, aa), __fmul_rn(e2, vt));
      bb = __fadd_rn(__fmul_rn(e1, bb), e2);
      pp = p2;
    }
#pragma unroll
    for (int i = 0; i < 4; ++i) { kc[i] = kn[i]; vc[i] = vn[i]; }
  }
}

// ---------------------------------------------------------------------------
// MFMA flash attention. Grid 512 (16 qt x 32 bh, XCD-swizzled), 256 thr /
// 4 waves. Each wave owns 16 q-rows; KT=32 key tiles.
// Q: register-resident 3-plane bf16 frags (loaded once from global).
// K staged [key][kd] (== proven gemm Bs pattern); V staged TRANSPOSED
// [d][key] so PV B-frags are contiguous b128; P written per-wave (private,
// no barrier) to [q][key] split planes, read back as A-frags.
// 6-pass accM/accC split everywhere (noise ~1e-7, proven class R8).
// O MAY ALIAS Q: Q consumed into regs in prologue; blocks disjoint rows.
// ---------------------------------------------------------------------------
__global__ __launch_bounds__(256)
void flash_attn(const float* __restrict__ Q, const float* __restrict__ K,
                const float* __restrict__ V, float* __restrict__ O) {
  __shared__ ushort Ks[3][32][136];    // [plane][key][kd]   26.1 KB
  __shared__ ushort Vt[3][128][40];    // [plane][d][key]    30.7 KB
  __shared__ ushort Pl[4][3][16][40];  // [wave][plane][q][key] 15.4 KB
  const int tid = threadIdx.x;
  const int n    = blockIdx.x;
  const int xcd  = n & 7;
  const int idx  = n >> 3;
  const int qt   = idx & 15;
  const int grp4 = idx >> 4;
  const int p    = grp4 * 8 + xcd;
  const int b    = p >> 3, h = p & 7;
  const size_t base = ((size_t)b * TDIM) * DDIM + (size_t)h * DH;

  const int wave = tid >> 6;
  const int lane = tid & 63;
  const int lr   = lane & 15;          // frag row/col index
  const int g    = lane >> 4;          // k-group
  const int sr   = tid >> 3;           // staging: key row 0..31
  const int sc   = (tid & 7) * 16;     // staging: d base

  // ---- prologue: Q -> register frags (3 planes x 4 ksteps) ----
  bfrag q1[4], q2[4], q3[4];
  {
    const float* Qrow = Q + base + (size_t)(qt * 64 + wave * 16 + lr) * DDIM;
#pragma unroll
    for (int s = 0; s < 4; ++s) {
      const float4 f0 = *(const float4*)(Qrow + s * 32 + g * 8);
      const float4 f1 = *(const float4*)(Qrow + s * 32 + g * 8 + 4);
      const float qf[8] = {f0.x, f0.y, f0.z, f0.w, f1.x, f1.y, f1.z, f1.w};
      union { bfrag v; ushort u[8]; } u1, u2, u3;
#pragma unroll
      for (int j = 0; j < 8; ++j) split3(qf[j], u1.u[j], u2.u[j], u3.u[j]);
      q1[s] = u1.v; q2[s] = u2.v; q3[s] = u3.v;
    }
  }

  facc oM[8], oC[8];
#pragma unroll
  for (int i = 0; i < 8; ++i) { oM[i] = (facc)0.f; oC[i] = (facc)0.f; }
  float m[4] = {-INFINITY, -INFINITY, -INFINITY, -INFINITY};
  float l[4] = {0.f, 0.f, 0.f, 0.f};
  const float ISC = 0.08838834764831845f;   // 1/sqrt(128)

  for (int kt0 = 0; kt0 < TDIM; kt0 += 32) {
    __syncthreads();                  // prev tile's reads of Ks/Vt done
    {                                 // ---- stage K [key][kd], V^T [d][key]
      const float* Kg = K + base + (size_t)(kt0 + sr) * DDIM + sc;
      const float* Vg = V + base + (size_t)(kt0 + sr) * DDIM + sc;
      float kv[16], vv[16];
      *(float4*)&kv[0]  = *(const float4*)(Kg);
      *(float4*)&kv[4]  = *(const float4*)(Kg + 4);
      *(float4*)&kv[8]  = *(const float4*)(Kg + 8);
      *(float4*)&kv[12] = *(const float4*)(Kg + 12);
      *(float4*)&vv[0]  = *(const float4*)(Vg);
      *(float4*)&vv[4]  = *(const float4*)(Vg + 4);
      *(float4*)&vv[8]  = *(const float4*)(Vg + 8);
      *(float4*)&vv[12] = *(const float4*)(Vg + 12);
      uint w1[8], w2[8], w3[8];
#pragma unroll
      for (int i = 0; i < 8; ++i) {
        ushort a1, b1, c1, a2, b2, c2;
        split3(kv[2 * i], a1, b1, c1);
        split3(kv[2 * i + 1], a2, b2, c2);
        w1[i] = (uint)a1 | ((uint)a2 << 16);
        w2[i] = (uint)b1 | ((uint)b2 << 16);
        w3[i] = (uint)c1 | ((uint)c2 << 16);
      }
      *(uint4*)&Ks[0][sr][sc]     = *(uint4*)&w1[0];
      *(uint4*)&Ks[0][sr][sc + 8] = *(uint4*)&w1[4];
      *(uint4*)&Ks[1][sr][sc]     = *(uint4*)&w2[0];
      *(uint4*)&Ks[1][sr][sc + 8] = *(uint4*)&w2[4];
      *(uint4*)&Ks[2][sr][sc]     = *(uint4*)&w3[0];
      *(uint4*)&Ks[2][sr][sc + 8] = *(uint4*)&w3[4];
#pragma unroll
      for (int i = 0; i < 16; ++i) {
        ushort a1, b1, c1;
        split3(vv[i], a1, b1, c1);
        Vt[0][sc + i][sr] = a1;
        Vt[1][sc + i][sr] = b1;
        Vt[2][sc + i][sr] = c1;
      }
    }
    __syncthreads();

    // ---- QK^T: S frags (2 nfrags of 16 keys), 6-pass split ----
    facc sM0 = (facc)0.f, sC0 = (facc)0.f, sM1 = (facc)0.f, sC1 = (facc)0.f;
#pragma unroll
    for (int s = 0; s < 4; ++s) {
      const int ko = s * 32 + g * 8;
      const bfrag kb10 = *(const bfrag*)&Ks[0][lr][ko];
      const bfrag kb11 = *(const bfrag*)&Ks[0][lr + 16][ko];
      const bfrag kb20 = *(const bfrag*)&Ks[1][lr][ko];
      const bfrag kb21 = *(const bfrag*)&Ks[1][lr + 16][ko];
      const bfrag kb30 = *(const bfrag*)&Ks[2][lr][ko];
      const bfrag kb31 = *(const bfrag*)&Ks[2][lr + 16][ko];
      sM0 = __builtin_amdgcn_mfma_f32_16x16x32_bf16(q1[s], kb10, sM0, 0, 0, 0);
      sC0 = __builtin_amdgcn_mfma_f32_16x16x32_bf16(q2[s], kb10, sC0, 0, 0, 0);
      sC0 = __builtin_amdgcn_mfma_f32_16x16x32_bf16(q3[s], kb10, sC0, 0, 0, 0);
      sC0 = __builtin_amdgcn_mfma_f32_16x16x32_bf16(q1[s], kb20, sC0, 0, 0, 0);
      sC0 = __builtin_amdgcn_mfma_f32_16x16x32_bf16(q2[s], kb20, sC0, 0, 0, 0);
      sC0 = __builtin_amdgcn_mfma_f32_16x16x32_bf16(q1[s], kb30, sC0, 0, 0, 0);
      sM1 = __builtin_amdgcn_mfma_f32_16x16x32_bf16(q1[s], kb11, sM1, 0, 0, 0);
      sC1 = __builtin_amdgcn_mfma_f32_16x16x32_bf16(q2[s], kb11, sC1, 0, 0, 0);
      sC1 = __builtin_amdgcn_mfma_f32_16x16x32_bf16(q3[s], kb11, sC1, 0, 0, 0);
      sC1 = __builtin_amdgcn_mfma_f32_16x16x32_bf16(q1[s], kb21, sC1, 0, 0, 0);
      sC1 = __builtin_amdgcn_mfma_f32_16x16x32_bf16(q2[s], kb21, sC1, 0, 0, 0);
      sC1 = __builtin_amdgcn_mfma_f32_16x16x32_bf16(q1[s], kb31, sC1, 0, 0, 0);
    }

    // ---- online softmax (rows q=g*4+r; 16-lane reduce over keys) ----
#pragma unroll
    for (int r = 0; r < 4; ++r) {
      const float sc0 = (sM0[r] + sC0[r]) * ISC;     // key = lr
      const float sc1 = (sM1[r] + sC1[r]) * ISC;     // key = lr+16
      float mx = fmaxf(sc0, sc1);
      mx = fmaxf(mx, __shfl_xor(mx, 1, 16));
      mx = fmaxf(mx, __shfl_xor(mx, 2, 16));
      mx = fmaxf(mx, __shfl_xor(mx, 4, 16));
      mx = fmaxf(mx, __shfl_xor(mx, 8, 16));
      const float mn = fmaxf(m[r], mx);
      const float rf = expf(m[r] - mn);
      const float p0 = expf(sc0 - mn), p1 = expf(sc1 - mn);
      float ps = p0 + p1;
      ps += __shfl_xor(ps, 1, 16);
      ps += __shfl_xor(ps, 2, 16);
      ps += __shfl_xor(ps, 4, 16);
      ps += __shfl_xor(ps, 8, 16);
      l[r] = l[r] * rf + ps;
      m[r] = mn;
#pragma unroll
      for (int nf = 0; nf < 8; ++nf) { oM[nf][r] *= rf; oC[nf][r] *= rf; }
      // split P and write to per-wave LDS [q=g*4+r][key]
      ushort a1, b1, c1;
      split3(p0, a1, b1, c1);
      Pl[wave][0][g * 4 + r][lr] = a1;
      Pl[wave][1][g * 4 + r][lr] = b1;
      Pl[wave][2][g * 4 + r][lr] = c1;
      split3(p1, a1, b1, c1);
      Pl[wave][0][g * 4 + r][lr + 16] = a1;
      Pl[wave][1][g * 4 + r][lr + 16] = b1;
      Pl[wave][2][g * 4 + r][lr + 16] = c1;
    }

    // ---- PV: O += P @ V (wave-private P, no barrier needed) ----
    const bfrag pa1 = *(const bfrag*)&Pl[wave][0][lr][g * 8];
    const bfrag pa2 = *(const bfrag*)&Pl[wave][1][lr][g * 8];
    const bfrag pa3 = *(const bfrag*)&Pl[wave][2][lr][g * 8];
#pragma unroll
    for (int nf = 0; nf < 8; ++nf) {
      const bfrag vb1 = *(const bfrag*)&Vt[0][nf * 16 + lr][g * 8];
      const bfrag vb2 = *(const bfrag*)&Vt[1][nf * 16 + lr][g * 8];
      const bfrag vb3 = *(const bfrag*)&Vt[2][nf * 16 + lr][g * 8];
      oM[nf] = __builtin_amdgcn_mfma_f32_16x16x32_bf16(pa1, vb1, oM[nf], 0, 0, 0);
      oC[nf] = __builtin_amdgcn_mfma_f32_16x16x32_bf16(pa2, vb1, oC[nf], 0, 0, 0);
      oC[nf] = __builtin_amdgcn_mfma_f32_16x16x32_bf16(pa3, vb1, oC[nf], 0, 0, 0);
      oC[nf] = __builtin_amdgcn_mfma_f32_16x16x32_bf16(pa1, vb2, oC[nf], 0, 0, 0);
      oC[nf] = __builtin_amdgcn_mfma_f32_16x16x32_bf16(pa2, vb2, oC[nf], 0, 0, 0);
      oC[nf] = __builtin_amdgcn_mfma_f32_16x16x32_bf16(pa1, vb3, oC[nf], 0, 0, 0);
    }
  }

  // ---- epilogue: O/l -> global (rows q=g*4+r, cols d=lr+16*nf) ----
  float* Og = O + base + (size_t)(qt * 64 + wave * 16) * DDIM;
#pragma unroll
  for (int r = 0; r < 4; ++r) {
    const float invl = 1.0f / l[r];
    float* orow = Og + (size_t)(g * 4 + r) * DDIM;
#pragma unroll
    for (int nf = 0; nf < 8; ++nf)
      orow[nf * 16 + lr] = (oM[nf][r] + oC[nf][r]) * invl;
  }
}

// ---------------------------------------------------------------------------
// Final: y = lif2(f32) + spikes2(u8); LayerNorm; float32 store.
// ---------------------------------------------------------------------------
__global__ __launch_bounds__(256)
void ln_kernel(const float* __restrict__ a, const uint8_t* __restrict__ s8,
               const float* __restrict__ gamma, const float* __restrict__ beta,
               float* __restrict__ out) {
  const int row = blockIdx.x;
  const int tid = threadIdx.x;
  const size_t base = (size_t)row * DDIM;
  const float4 av = *(const float4*)(a + base + tid * 4);
  const uchar4 sv = *(const uchar4*)(s8 + base + tid * 4);
  const float y0 = av.x + (float)sv.x, y1 = av.y + (float)sv.y;
  const float y2 = av.z + (float)sv.z, y3 = av.w + (float)sv.w;
  float s = (y0 + y1) + (y2 + y3);
  float q = (y0 * y0 + y1 * y1) + (y2 * y2 + y3 * y3);
#pragma unroll
  for (int off = 1; off < 64; off <<= 1) {
    s += __shfl_xor(s, off);
    q += __shfl_xor(q, off);
  }
  __shared__ float red[8];
  const int wid = tid >> 6;
  if ((tid & 63) == 0) { red[wid * 2] = s; red[wid * 2 + 1] = q; }
  __syncthreads();
  const float ts = (red[0] + red[2]) + (red[4] + red[6]);
  const float tq = (red[1] + red[3]) + (red[5] + red[7]);
  const float mu  = ts * (1.0f / 1024.0f);
  const float var = tq * (1.0f / 1024.0f) - mu * mu;
  const float rs  = 1.0f / sqrtf(var + 1e-5f);
  const int d = tid * 4;
  const float4 gv  = *(const float4*)(gamma + d);
  const float4 btv = *(const float4*)(beta + d);
  float4 r;
  r.x = (y0 - mu) * rs * gv.x + btv.x;
  r.y = (y1 - mu) * rs * gv.y + btv.y;
  r.z = (y2 - mu) * rs * gv.z + btv.z;
  r.w = (y3 - mu) * rs * gv.w + btv.w;
  *(float4*)(out + base + d) = r;
}

// ---------------------------------------------------------------------------
// Workspace: 3 f32 (A,C,D) 50.3 MB + u8 spikes 4.2 MB + B planes 18 MB.
// ---------------------------------------------------------------------------
extern "C" void kernel_launch(void* const* d_in, const int* in_sizes, int n_in,
                              void* d_out, int out_size, void* d_ws, size_t ws_size,
                              hipStream_t stream) {
  const float* x       = (const float*)d_in[0];
  const float* context = (const float*)d_in[1];
  const float* Wg  = (const float*)d_in[2];
  const float* bg  = (const float*)d_in[3];
  const float* Wc  = (const float*)d_in[4];
  const float* Wq  = (const float*)d_in[5];
  const float* Wk  = (const float*)d_in[6];
  const float* Wv  = (const float*)d_in[7];
  const float* Wo  = (const float*)d_in[8];
  const float* Wm  = (const float*)d_in[9];
  const float* rWk = (const float*)d_in[10];
  const float* rWv = (const float*)d_in[11];
  const float* rWr = (const float*)d_in[12];
  const float* rWo = (const float*)d_in[13];
  const float* wd  = (const float*)d_in[14];
  const float* uf  = (const float*)d_in[15];
  const float* gamma = (const float*)d_in[16];
  const float* beta  = (const float*)d_in[17];
  float* out = (float*)d_out;   // reference output dtype = float32

  float* w  = (float*)d_ws;
  float*   bA = w;
  float*   bC = w + 1 * NELEM;
  float*   bD = w + 2 * NELEM;
  uint8_t* bS = (uint8_t*)(w + 3 * NELEM);                          // u8 spikes
  ushort*  pB = (ushort*)((uint8_t*)d_ws + 3 * NELEM * 4 + NELEM);  // B planes

  const dim3 ew(4096);
  constexpr int M1 = 1024 * 1024;   // ushorts per 1024-K plane

  // Stage 1: thalamic gate — single K=2048 GEMM over [x | context]
  cvt_b3t<<<dim3(16, 16, 2), 256, 0, stream>>>(Wg, Wc, nullptr, pB, 0, 1024, 2048);
  gemm_k<0, 0, 1, 2048><<<512, 256, 0, stream>>>(x, context, pB, bA, nullptr, nullptr);
  gate_kernel<<<ew, 256, 0, stream>>>(x, bA, bg, bA);
  // Stage 2: LIF -> spikes2 (u8)
  lif_u8_kernel<<<64, 64, 0, stream>>>(bA, bS);
  // Stage 3: spike self-attention — Q,K,V in ONE N-merged launch
  cvt_b3t<<<dim3(16, 16, 3), 256, 0, stream>>>(Wq, Wk, Wv, pB, 3 * M1, 0, 1024);
  gemm_k<0, 1, 3, 1024><<<1536, 256, 0, stream>>>(bS, nullptr, pB, bA, bC, bD);
  flash_attn<<<512, 256, 0, stream>>>(bA, bC, bD, bA);
  cvt_b3t<<<dim3(16, 16, 1), 256, 0, stream>>>(Wo, nullptr, nullptr, pB, 0, 0, 1024);
  gemm_k<0, 0, 1, 1024><<<512, 256, 0, stream>>>(bA, nullptr, pB, bC, nullptr, nullptr);
  // Stage 4: apical modulation
  cvt_b3t<<<dim3(16, 16, 1), 256, 0, stream>>>(Wm, nullptr, nullptr, pB, 0, 0, 1024);
  gemm_k<0, 0, 1, 1024><<<512, 256, 0, stream>>>(context, nullptr, pB, bA, nullptr, nullptr);
  mod_kernel<<<ew, 256, 0, stream>>>(bC, bA, bD);          // bD = modulated
  // Stage 5: RWKV — k,v N-merged
  cvt_b3t<<<dim3(16, 16, 2), 256, 0, stream>>>(rWk, rWv, nullptr, pB, 3 * M1, 0, 1024);
  gemm_k<0, 0, 2, 1024><<<1024, 256, 0, stream>>>(bD, nullptr, pB, bA, bC, nullptr);
  rwkv_kernel<<<64, 64, 0, stream>>>(bA, bC, wd, uf, bA);  // bA = wkv
  cvt_b3t<<<dim3(16, 16, 1), 256, 0, stream>>>(rWr, nullptr, nullptr, pB, 0, 0, 1024);
  gemm_k<0, 0, 1, 1024><<<512, 256, 0, stream>>>(bD, nullptr, pB, bC, nullptr, nullptr);
  rmul_kernel<<<ew, 256, 0, stream>>>(bC, bA, bA);         // bA = sig(r)*wkv
  cvt_b3t<<<dim3(16, 16, 1), 256, 0, stream>>>(rWo, nullptr, nullptr, pB, 0, 0, 1024);
  gemm_k<0, 0, 1, 1024><<<512, 256, 0, stream>>>(bA, nullptr, pB, bC, nullptr, nullptr);
  // Stage 6: output LIF (in-place) + residual + LayerNorm
  lif_ip_kernel<<<64, 64, 0, stream>>>(bC);
  ln_kernel<<<4096, 256, 0, stream>>>(bC, bS, gamma, beta, out);
}

// Round 12
// 1562.674 us; speedup vs baseline: 2.1656x; 1.0182x over previous
//
#include <hip/hip_runtime.h>
#include <hip/hip_bf16.h>
#include <math.h>

// Problem dims (fixed)
#define BDIM 4
#define TDIM 1024
#define DDIM 1024
#define DH   128
#define NELEM ((size_t)BDIM * TDIM * DDIM)   // 4,194,304

typedef __attribute__((ext_vector_type(8))) short bfrag;   // 8 bf16 (4 VGPR)
typedef __attribute__((ext_vector_type(4))) float facc;    // 4 f32 acc

__device__ __forceinline__ ushort f2bf(float x) {          // f32 -> bf16 RNE
  union { float f; uint u; } v; v.f = x;
  const uint r = v.u + 0x7FFFu + ((v.u >> 16) & 1u);
  return (ushort)(r >> 16);
}
__device__ __forceinline__ float bf2f(ushort h) {
  union { uint u; float f; } v; v.u = ((uint)h) << 16; return v.f;
}
__device__ __forceinline__ void split3(float x, ushort& s1, ushort& s2, ushort& s3) {
  s1 = f2bf(x); float r = x - bf2f(s1);
  s2 = f2bf(r); r = r - bf2f(s2);
  s3 = f2bf(r);
}

constexpr int GM = 4096, GN = 1024, GK = 1024;
constexpr int BM = 128, BK = 32;
constexpr int BKP = 40;                    // padded LDS k-dim (80 B rows)

// ---------------------------------------------------------------------------
// cvt_b3t: up to 3 weight matrices [1024][1024] f32 -> 3-way bf16 split
// planes, blocked-transposed [kTot/32][N=1024][32].
// ---------------------------------------------------------------------------
__global__ __launch_bounds__(256)
void cvt_b3t(const float* __restrict__ W0, const float* __restrict__ W1,
             const float* __restrict__ W2, ushort* __restrict__ P,
             int zstride, int zkoff, int kTot) {
  __shared__ float Ls[64][68];
  const int z = blockIdx.z;
  const float* W = (z == 0) ? W0 : (z == 1 ? W1 : W2);
  ushort* Pz = P + (size_t)z * zstride;
  const size_t PS = (size_t)kTot * GN;     // ushorts per plane
  const int t = threadIdx.x;
  const int k0 = blockIdx.x * 64, n0 = blockIdx.y * 64;
  const int r = t >> 4, c4 = (t & 15) << 2;
#pragma unroll
  for (int i = 0; i < 4; ++i)
    *(float4*)&Ls[r + i * 16][c4] =
        *(const float4*)(W + (size_t)(k0 + r + i * 16) * GN + n0 + c4);
  __syncthreads();
  const int n = t >> 2, kc = (t & 3) << 4;
  uint p1[8], p2[8], p3[8];
#pragma unroll
  for (int jj = 0; jj < 8; ++jj) {
    const float x0 = Ls[kc + 2 * jj][n], x1 = Ls[kc + 2 * jj + 1][n];
    ushort a1, b1, c1, a2, b2, c2;
    split3(x0, a1, b1, c1);
    split3(x1, a2, b2, c2);
    p1[jj] = (uint)a1 | ((uint)a2 << 16);
    p2[jj] = (uint)b1 | ((uint)b2 << 16);
    p3[jj] = (uint)c1 | ((uint)c2 << 16);
  }
  const int kk = k0 + kc + z * zkoff;
  ushort* d = Pz + (size_t)(kk >> 5) * (GN * 32) + (size_t)(n0 + n) * 32 + (kk & 31);
  *(uint4*)(d)          = *(uint4*)&p1[0];
  *(uint4*)(d + 8)      = *(uint4*)&p1[4];
  *(uint4*)(d + PS)     = *(uint4*)&p2[0];
  *(uint4*)(d + PS + 8) = *(uint4*)&p2[4];
  *(uint4*)(d + 2 * PS)     = *(uint4*)&p3[0];
  *(uint4*)(d + 2 * PS + 8) = *(uint4*)&p3[4];
}

// ---------------------------------------------------------------------------
// GEMM via 3-way-split bf16 MFMA (proven R8-R10). Tile 128x64, 4 waves,
// 46 KB LDS -> 3 blocks/CU. NMAT: N-merged. KTOT=2048: K-merged A.
// ---------------------------------------------------------------------------
template<int EPI, int AU8, int NMAT, int KTOT>
__global__ __launch_bounds__(256)
void gemm_k(const void* __restrict__ Av, const void* __restrict__ Av2,
            const ushort* __restrict__ pB,
            float* __restrict__ C0, float* __restrict__ C1,
            float* __restrict__ C2) {
  constexpr size_t PS = (size_t)KTOT * GN;   // ushorts per plane
  __shared__ ushort As[3][BM][BKP];
  __shared__ ushort Bs[3][64][BKP];
  const int tid = threadIdx.x;
  const int n   = blockIdx.x;
  const int xcd = n & 7;
  const int idx = n >> 3;
  const int by  = xcd * 4 + (idx & 3);
  const int bx  = idx >> 2;
  const int mat = bx >> 4;
  const int row0 = by * BM;
  const int col0 = (bx & 15) * 64;
  const ushort* pBm = pB + (size_t)mat * 3 * PS;
  float* C = (mat == 0) ? C0 : (mat == 1 ? C1 : C2);

  const int sm  = tid & 127;
  const int sk0 = (tid >> 7) << 4;

  const int wave = tid >> 6;
  const int lane = tid & 63;
  const int wrow = (wave >> 1) * 64;
  const int wcol = (wave & 1) * 32;
  const int lrow = lane & 15;
  const int kof  = (lane >> 4) * 8;

  facc accM[4][2], accC[4][2];
#pragma unroll
  for (int i = 0; i < 4; ++i)
#pragma unroll
    for (int j = 0; j < 2; ++j) { accM[i][j] = (facc)0.f; accC[i][j] = (facc)0.f; }

  float av[16];
  uint4 a8raw;
  uint4 bregs[3];

  auto gloadA = [&](int K0) {
    const void* src = Av; int k = K0;
    if (KTOT > 1024 && K0 >= 1024) { src = Av2; k = K0 - 1024; }
    if (AU8) {
      a8raw = *(const uint4*)((const uint8_t*)src + (size_t)(row0 + sm) * 1024 + k + sk0);
    } else {
      const float* Ap = (const float*)src + (size_t)(row0 + sm) * 1024 + k + sk0;
      *(float4*)&av[0]  = *(const float4*)(Ap);
      *(float4*)&av[4]  = *(const float4*)(Ap + 4);
      *(float4*)&av[8]  = *(const float4*)(Ap + 8);
      *(float4*)&av[12] = *(const float4*)(Ap + 12);
    }
  };
  auto gloadB = [&](int K0) {
    const int kb = K0 >> 5;
#pragma unroll
    for (int j = 0; j < 3; ++j) {
      const int u = tid + 256 * j;
      const int q = u & 3, nn = (u >> 2) & 63, p = u >> 8;
      bregs[j] = *(const uint4*)(pBm + (size_t)p * PS + (size_t)kb * (GN * 32)
                                 + (size_t)(col0 + nn) * 32 + q * 8);
    }
  };
  auto swrite = [&]() {
    if (AU8) {
      const uint w4[4] = {a8raw.x, a8raw.y, a8raw.z, a8raw.w};
      uint pk[8];
#pragma unroll
      for (int i = 0; i < 8; ++i) {
        const uint b0 = (w4[i >> 1] >> ((i & 1) * 16)) & 0xFFu;
        const uint b1 = (w4[i >> 1] >> ((i & 1) * 16 + 8)) & 0xFFu;
        pk[i] = (b0 * 0x3F80u) | ((b1 * 0x3F80u) << 16);
      }
      *(uint4*)&As[0][sm][sk0]     = *(uint4*)&pk[0];
      *(uint4*)&As[0][sm][sk0 + 8] = *(uint4*)&pk[4];
    } else {
      uint q1[8], q2[8], q3[8];
#pragma unroll
      for (int i = 0; i < 8; ++i) {
        ushort a1, b1, c1, a2, b2, c2;
        split3(av[2 * i], a1, b1, c1);
        split3(av[2 * i + 1], a2, b2, c2);
        q1[i] = (uint)a1 | ((uint)a2 << 16);
        q2[i] = (uint)b1 | ((uint)b2 << 16);
        q3[i] = (uint)c1 | ((uint)c2 << 16);
      }
      *(uint4*)&As[0][sm][sk0]     = *(uint4*)&q1[0];
      *(uint4*)&As[0][sm][sk0 + 8] = *(uint4*)&q1[4];
      *(uint4*)&As[1][sm][sk0]     = *(uint4*)&q2[0];
      *(uint4*)&As[1][sm][sk0 + 8] = *(uint4*)&q2[4];
      *(uint4*)&As[2][sm][sk0]     = *(uint4*)&q3[0];
      *(uint4*)&As[2][sm][sk0 + 8] = *(uint4*)&q3[4];
    }
#pragma unroll
    for (int j = 0; j < 3; ++j) {
      const int u = tid + 256 * j;
      const int q = u & 3, nn = (u >> 2) & 63, p = u >> 8;
      *(uint4*)&Bs[p][nn][q * 8] = bregs[j];
    }
  };

  gloadA(0); gloadB(0);
  for (int k0 = 0; k0 < KTOT; k0 += BK) {
    __syncthreads();
    swrite();
    const int kn = k0 + BK;
    if (kn < KTOT) { gloadA(kn); gloadB(kn); }
    __syncthreads();
    bfrag fb0[2], fb1[2], fb2[2];
#pragma unroll
    for (int f = 0; f < 2; ++f) {
      fb0[f] = *(const bfrag*)&Bs[0][wcol + f * 16 + lrow][kof];
      fb1[f] = *(const bfrag*)&Bs[1][wcol + f * 16 + lrow][kof];
      fb2[f] = *(const bfrag*)&Bs[2][wcol + f * 16 + lrow][kof];
    }
#pragma unroll
    for (int mi = 0; mi < 4; ++mi) {
      const bfrag a1 = *(const bfrag*)&As[0][wrow + mi * 16 + lrow][kof];
      bfrag a2, a3;
      if (!AU8) {
        a2 = *(const bfrag*)&As[1][wrow + mi * 16 + lrow][kof];
        a3 = *(const bfrag*)&As[2][wrow + mi * 16 + lrow][kof];
      }
#pragma unroll
      for (int ni = 0; ni < 2; ++ni) {
        accM[mi][ni] = __builtin_amdgcn_mfma_f32_16x16x32_bf16(a1, fb0[ni], accM[mi][ni], 0, 0, 0);
        if (!AU8) {
          accC[mi][ni] = __builtin_amdgcn_mfma_f32_16x16x32_bf16(a2, fb0[ni], accC[mi][ni], 0, 0, 0);
          accC[mi][ni] = __builtin_amdgcn_mfma_f32_16x16x32_bf16(a3, fb0[ni], accC[mi][ni], 0, 0, 0);
        }
      }
#pragma unroll
      for (int ni = 0; ni < 2; ++ni) {
        accC[mi][ni] = __builtin_amdgcn_mfma_f32_16x16x32_bf16(a1, fb1[ni], accC[mi][ni], 0, 0, 0);
        if (!AU8)
          accC[mi][ni] = __builtin_amdgcn_mfma_f32_16x16x32_bf16(a2, fb1[ni], accC[mi][ni], 0, 0, 0);
      }
#pragma unroll
      for (int ni = 0; ni < 2; ++ni)
        accC[mi][ni] = __builtin_amdgcn_mfma_f32_16x16x32_bf16(a1, fb2[ni], accC[mi][ni], 0, 0, 0);
    }
  }

#pragma unroll
  for (int mi = 0; mi < 4; ++mi) {
#pragma unroll
    for (int ni = 0; ni < 2; ++ni) {
      const int rbase = row0 + wrow + mi * 16 + (lane >> 4) * 4;
      const int cc    = col0 + wcol + ni * 16 + lrow;
      float* cp = C + (size_t)rbase * GN + cc;
#pragma unroll
      for (int r = 0; r < 4; ++r) {
        float v = accM[mi][ni][r] + accC[mi][ni][r];
        if (EPI == 1) v += cp[(size_t)r * GN];
        cp[(size_t)r * GN] = v;
      }
    }
  }
}

// ---------------------------------------------------------------------------
// Elementwise kernels
// ---------------------------------------------------------------------------
__device__ __forceinline__ float sigf(float z) { return 1.0f / (1.0f + expf(-z)); }

__global__ __launch_bounds__(256)
void gate_kernel(const float* __restrict__ x, const float* __restrict__ L,
                 const float* __restrict__ bg, float* __restrict__ out) {
  const int i4 = blockIdx.x * 256 + threadIdx.x;
  const float4 xv = ((const float4*)x)[i4];
  const float4 lv = ((const float4*)L)[i4];
  const float4 bv = ((const float4*)bg)[i4 & 255];
  float4 r;
  r.x = xv.x * (0.5f * sigf(lv.x + bv.x) + 0.5f);
  r.y = xv.y * (0.5f * sigf(lv.y + bv.y) + 0.5f);
  r.z = xv.z * (0.5f * sigf(lv.z + bv.z) + 0.5f);
  r.w = xv.w * (0.5f * sigf(lv.w + bv.w) + 0.5f);
  ((float4*)out)[i4] = r;
}

__global__ __launch_bounds__(256)
void mod_kernel(const float* __restrict__ a, const float* __restrict__ c,
                float* __restrict__ out) {
  const int i4 = blockIdx.x * 256 + threadIdx.x;
  const float4 av = ((const float4*)a)[i4];
  const float4 cv = ((const float4*)c)[i4];
  float4 r;
  r.x = av.x * (1.0f + tanhf(cv.x));
  r.y = av.y * (1.0f + tanhf(cv.y));
  r.z = av.z * (1.0f + tanhf(cv.z));
  r.w = av.w * (1.0f + tanhf(cv.w));
  ((float4*)out)[i4] = r;
}

__global__ __launch_bounds__(256)
void rmul_kernel(const float* __restrict__ rr, const float* __restrict__ wkv,
                 float* __restrict__ out) {
  const int i4 = blockIdx.x * 256 + threadIdx.x;
  const float4 rv = ((const float4*)rr)[i4];
  const float4 wv = ((const float4*)wkv)[i4];
  float4 r;
  r.x = sigf(rv.x) * wv.x;
  r.y = sigf(rv.y) * wv.y;
  r.z = sigf(rv.z) * wv.z;
  r.w = sigf(rv.w) * wv.w;
  ((float4*)out)[i4] = r;
}

// ---------------------------------------------------------------------------
// LIF scans (software-pipelined, proven R10)
// ---------------------------------------------------------------------------
__global__ __launch_bounds__(64)
void lif_u8_kernel(const float* __restrict__ x, uint8_t* __restrict__ s) {
  const int c = blockIdx.x * 64 + threadIdx.x;
  const size_t off = (size_t)(c >> 10) * TDIM * DDIM + (c & 1023);
  const float* xp = x + off;
  uint8_t* sp = s + off;
  float u = 0.f;
  float cur[8];
#pragma unroll
  for (int i = 0; i < 8; ++i) cur[i] = xp[(size_t)i * DDIM];
  for (int t = 0; t < TDIM; t += 8) {
    float nxt[8];
    if (t + 8 < TDIM) {
#pragma unroll
      for (int i = 0; i < 8; ++i) nxt[i] = xp[(size_t)(t + 8 + i) * DDIM];
    }
#pragma unroll
    for (int i = 0; i < 8; ++i) {
      u = __fadd_rn(__fmul_rn(0.9f, u), cur[i]);
      const bool fire = (u >= 1.0f);
      sp[(size_t)(t + i) * DDIM] = fire ? 1 : 0;
      if (fire) u -= 1.0f;
    }
#pragma unroll
    for (int i = 0; i < 8; ++i) cur[i] = nxt[i];
  }
}

__global__ __launch_bounds__(64)
void lif_ip_kernel(float* __restrict__ x) {
  const int c = blockIdx.x * 64 + threadIdx.x;
  const size_t off = (size_t)(c >> 10) * TDIM * DDIM + (c & 1023);
  float* xp = x + off;
  float u = 0.f;
  float cur[8];
#pragma unroll
  for (int i = 0; i < 8; ++i) cur[i] = xp[(size_t)i * DDIM];
  for (int t = 0; t < TDIM; t += 8) {
    float nxt[8];
    if (t + 8 < TDIM) {
#pragma unroll
      for (int i = 0; i < 8; ++i) nxt[i] = xp[(size_t)(t + 8 + i) * DDIM];
    }
#pragma unroll
    for (int i = 0; i < 8; ++i) {
      u = __fadd_rn(__fmul_rn(0.9f, u), cur[i]);
      const float sv = (u >= 1.0f) ? 1.0f : 0.0f;
      xp[(size_t)(t + i) * DDIM] = sv;
      u -= sv;
    }
#pragma unroll
    for (int i = 0; i < 8; ++i) cur[i] = nxt[i];
  }
}

__global__ __launch_bounds__(64)
void rwkv_kernel(const float* __restrict__ k, const float* __restrict__ v,
                 const float* __restrict__ wd, const float* __restrict__ uf,
                 float* __restrict__ out) {
  const int c = blockIdx.x * 64 + threadIdx.x;
  const int d = c & 1023;
  const size_t off = (size_t)(c >> 10) * TDIM * DDIM + d;
  const float* kp = k + off;
  const float* vp = v + off;
  float* op = out + off;
  const float w = expf(wd[d]);
  const float u = uf[d];
  float aa = 0.f, bb = 0.f, pp = -1e30f;
  float kc[4], vc[4];
#pragma unroll
  for (int i = 0; i < 4; ++i) {
    kc[i] = kp[(size_t)i * DDIM];
    vc[i] = vp[(size_t)i * DDIM];
  }
  for (int t = 0; t < TDIM; t += 4) {
    float kn[4], vn[4];
    if (t + 4 < TDIM) {
#pragma unroll
      for (int i = 0; i < 4; ++i) {
        kn[i] = kp[(size_t)(t + 4 + i) * DDIM];
        vn[i] = vp[(size_t)(t + 4 + i) * DDIM];
      }
    }
#pragma unroll
    for (int i = 0; i < 4; ++i) {
      const float kt = kc[i], vt = vc[i];
      const float ww = __fadd_rn(u, kt);
      const float p  = fmaxf(pp, ww);
      float e1 = expf(__fsub_rn(pp, p));
      float e2 = expf(__fsub_rn(ww, p));
      const float num = __fadd_rn(__fmul_rn(e1, aa), __fmul_rn(e2, vt));
      const float den = __fadd_rn(__fmul_rn(e1, bb), e2);
      op[(size_t)(t + i) * DDIM] = num / den;
      const float ww2 = __fsub_rn(pp, w);
      const float p2  = fmaxf(ww2, kt);
      e1 = expf(__fsub_rn(ww2, p2));
      e2 = expf(__fsub_rn(kt, p2));
      aa = __fadd_rn(__fmul_rn(e1, aa), __fmul_rn(e2, vt));
      bb = __fadd_rn(__fmul_rn(e1, bb), e2);
      pp = p2;
    }
#pragma unroll
    for (int i = 0; i < 4; ++i) { kc[i] = kn[i]; vc[i] = vn[i]; }
  }
}

// ---------------------------------------------------------------------------
// MFMA flash attention (R11 structure). Changes this round:
//  (a) Vt key-block rotation swizzle: key ks of d-row stored at slot
//      (ks + 8*((d>>4)&3)) & 31 -> V-transpose scalar writes go 16-way ->
//      4-way bank conflict; b128 reads stay contiguous at rotated base.
//  (b) Global K/V prefetch one tile ahead (GEMM-proven): loads for t+1
//      issued after staging writes of t, land under compute.
// ---------------------------------------------------------------------------
__global__ __launch_bounds__(256)
void flash_attn(const float* __restrict__ Q, const float* __restrict__ K,
                const float* __restrict__ V, float* __restrict__ O) {
  __shared__ ushort Ks[3][32][136];    // [plane][key][kd]   26.1 KB
  __shared__ ushort Vt[3][128][40];    // [plane][d][key-slot] 30.7 KB
  __shared__ ushort Pl[4][3][16][40];  // [wave][plane][q][key] 15.4 KB
  const int tid = threadIdx.x;
  const int n    = blockIdx.x;
  const int xcd  = n & 7;
  const int idx  = n >> 3;
  const int qt   = idx & 15;
  const int grp4 = idx >> 4;
  const int p    = grp4 * 8 + xcd;
  const int b    = p >> 3, h = p & 7;
  const size_t base = ((size_t)b * TDIM) * DDIM + (size_t)h * DH;

  const int wave = tid >> 6;
  const int lane = tid & 63;
  const int lr   = lane & 15;          // frag row/col index
  const int g    = lane >> 4;          // k-group
  const int sr   = tid >> 3;           // staging: key row 0..31
  const int sc   = (tid & 7) * 16;     // staging: d base
  const int vslot = (sr + 8 * (tid & 3)) & 31;   // rotated key slot (j&3 = tid&3)

  // ---- prologue: Q -> register frags (3 planes x 4 ksteps) ----
  bfrag q1[4], q2[4], q3[4];
  {
    const float* Qrow = Q + base + (size_t)(qt * 64 + wave * 16 + lr) * DDIM;
#pragma unroll
    for (int s = 0; s < 4; ++s) {
      const float4 f0 = *(const float4*)(Qrow + s * 32 + g * 8);
      const float4 f1 = *(const float4*)(Qrow + s * 32 + g * 8 + 4);
      const float qf[8] = {f0.x, f0.y, f0.z, f0.w, f1.x, f1.y, f1.z, f1.w};
      union { bfrag v; ushort u[8]; } u1, u2, u3;
#pragma unroll
      for (int j = 0; j < 8; ++j) split3(qf[j], u1.u[j], u2.u[j], u3.u[j]);
      q1[s] = u1.v; q2[s] = u2.v; q3[s] = u3.v;
    }
  }

  facc oM[8], oC[8];
#pragma unroll
  for (int i = 0; i < 8; ++i) { oM[i] = (facc)0.f; oC[i] = (facc)0.f; }
  float m[4] = {-INFINITY, -INFINITY, -INFINITY, -INFINITY};
  float l[4] = {0.f, 0.f, 0.f, 0.f};
  const float ISC = 0.08838834764831845f;   // 1/sqrt(128)

  // ---- K/V tile prefetch registers (tile 0) ----
  float kv[16], vv[16];
  auto gload = [&](int kt0) {
    const float* Kg = K + base + (size_t)(kt0 + sr) * DDIM + sc;
    const float* Vg = V + base + (size_t)(kt0 + sr) * DDIM + sc;
    *(float4*)&kv[0]  = *(const float4*)(Kg);
    *(float4*)&kv[4]  = *(const float4*)(Kg + 4);
    *(float4*)&kv[8]  = *(const float4*)(Kg + 8);
    *(float4*)&kv[12] = *(const float4*)(Kg + 12);
    *(float4*)&vv[0]  = *(const float4*)(Vg);
    *(float4*)&vv[4]  = *(const float4*)(Vg + 4);
    *(float4*)&vv[8]  = *(const float4*)(Vg + 8);
    *(float4*)&vv[12] = *(const float4*)(Vg + 12);
  };
  gload(0);

  for (int kt0 = 0; kt0 < TDIM; kt0 += 32) {
    __syncthreads();                  // prev tile's reads of Ks/Vt done
    {                                 // ---- stage from prefetched regs ----
      uint w1[8], w2[8], w3[8];
#pragma unroll
      for (int i = 0; i < 8; ++i) {
        ushort a1, b1, c1, a2, b2, c2;
        split3(kv[2 * i], a1, b1, c1);
        split3(kv[2 * i + 1], a2, b2, c2);
        w1[i] = (uint)a1 | ((uint)a2 << 16);
        w2[i] = (uint)b1 | ((uint)b2 << 16);
        w3[i] = (uint)c1 | ((uint)c2 << 16);
      }
      *(uint4*)&Ks[0][sr][sc]     = *(uint4*)&w1[0];
      *(uint4*)&Ks[0][sr][sc + 8] = *(uint4*)&w1[4];
      *(uint4*)&Ks[1][sr][sc]     = *(uint4*)&w2[0];
      *(uint4*)&Ks[1][sr][sc + 8] = *(uint4*)&w2[4];
      *(uint4*)&Ks[2][sr][sc]     = *(uint4*)&w3[0];
      *(uint4*)&Ks[2][sr][sc + 8] = *(uint4*)&w3[4];
#pragma unroll
      for (int i = 0; i < 16; ++i) {
        ushort a1, b1, c1;
        split3(vv[i], a1, b1, c1);
        Vt[0][sc + i][vslot] = a1;
        Vt[1][sc + i][vslot] = b1;
        Vt[2][sc + i][vslot] = c1;
      }
    }
    if (kt0 + 32 < TDIM) gload(kt0 + 32);   // lands under compute below
    __syncthreads();

    // ---- QK^T: S frags (2 nfrags of 16 keys), 6-pass split ----
    facc sM0 = (facc)0.f, sC0 = (facc)0.f, sM1 = (facc)0.f, sC1 = (facc)0.f;
#pragma unroll
    for (int s = 0; s < 4; ++s) {
      const int ko = s * 32 + g * 8;
      const bfrag kb10 = *(const bfrag*)&Ks[0][lr][ko];
      const bfrag kb11 = *(const bfrag*)&Ks[0][lr + 16][ko];
      const bfrag kb20 = *(const bfrag*)&Ks[1][lr][ko];
      const bfrag kb21 = *(const bfrag*)&Ks[1][lr + 16][ko];
      const bfrag kb30 = *(const bfrag*)&Ks[2][lr][ko];
      const bfrag kb31 = *(const bfrag*)&Ks[2][lr + 16][ko];
      sM0 = __builtin_amdgcn_mfma_f32_16x16x32_bf16(q1[s], kb10, sM0, 0, 0, 0);
      sC0 = __builtin_amdgcn_mfma_f32_16x16x32_bf16(q2[s], kb10, sC0, 0, 0, 0);
      sC0 = __builtin_amdgcn_mfma_f32_16x16x32_bf16(q3[s], kb10, sC0, 0, 0, 0);
      sC0 = __builtin_amdgcn_mfma_f32_16x16x32_bf16(q1[s], kb20, sC0, 0, 0, 0);
      sC0 = __builtin_amdgcn_mfma_f32_16x16x32_bf16(q2[s], kb20, sC0, 0, 0, 0);
      sC0 = __builtin_amdgcn_mfma_f32_16x16x32_bf16(q1[s], kb30, sC0, 0, 0, 0);
      sM1 = __builtin_amdgcn_mfma_f32_16x16x32_bf16(q1[s], kb11, sM1, 0, 0, 0);
      sC1 = __builtin_amdgcn_mfma_f32_16x16x32_bf16(q2[s], kb11, sC1, 0, 0, 0);
      sC1 = __builtin_amdgcn_mfma_f32_16x16x32_bf16(q3[s], kb11, sC1, 0, 0, 0);
      sC1 = __builtin_amdgcn_mfma_f32_16x16x32_bf16(q1[s], kb21, sC1, 0, 0, 0);
      sC1 = __builtin_amdgcn_mfma_f32_16x16x32_bf16(q2[s], kb21, sC1, 0, 0, 0);
      sC1 = __builtin_amdgcn_mfma_f32_16x16x32_bf16(q1[s], kb31, sC1, 0, 0, 0);
    }

    // ---- online softmax (rows q=g*4+r; 16-lane reduce over keys) ----
#pragma unroll
    for (int r = 0; r < 4; ++r) {
      const float sc0 = (sM0[r] + sC0[r]) * ISC;     // key = lr
      const float sc1 = (sM1[r] + sC1[r]) * ISC;     // key = lr+16
      float mx = fmaxf(sc0, sc1);
      mx = fmaxf(mx, __shfl_xor(mx, 1, 16));
      mx = fmaxf(mx, __shfl_xor(mx, 2, 16));
      mx = fmaxf(mx, __shfl_xor(mx, 4, 16));
      mx = fmaxf(mx, __shfl_xor(mx, 8, 16));
      const float mn = fmaxf(m[r], mx);
      const float rf = expf(m[r] - mn);
      const float p0 = expf(sc0 - mn), p1 = expf(sc1 - mn);
      float ps = p0 + p1;
      ps += __shfl_xor(ps, 1, 16);
      ps += __shfl_xor(ps, 2, 16);
      ps += __shfl_xor(ps, 4, 16);
      ps += __shfl_xor(ps, 8, 16);
      l[r] = l[r] * rf + ps;
      m[r] = mn;
#pragma unroll
      for (int nf = 0; nf < 8; ++nf) { oM[nf][r] *= rf; oC[nf][r] *= rf; }
      ushort a1, b1, c1;
      split3(p0, a1, b1, c1);
      Pl[wave][0][g * 4 + r][lr] = a1;
      Pl[wave][1][g * 4 + r][lr] = b1;
      Pl[wave][2][g * 4 + r][lr] = c1;
      split3(p1, a1, b1, c1);
      Pl[wave][0][g * 4 + r][lr + 16] = a1;
      Pl[wave][1][g * 4 + r][lr + 16] = b1;
      Pl[wave][2][g * 4 + r][lr + 16] = c1;
    }

    // ---- PV: O += P @ V (wave-private P; Vt reads at rotated slot) ----
    const bfrag pa1 = *(const bfrag*)&Pl[wave][0][lr][g * 8];
    const bfrag pa2 = *(const bfrag*)&Pl[wave][1][lr][g * 8];
    const bfrag pa3 = *(const bfrag*)&Pl[wave][2][lr][g * 8];
#pragma unroll
    for (int nf = 0; nf < 8; ++nf) {
      const int vs = 8 * ((g + nf) & 3);             // rotated key-slot base
      const bfrag vb1 = *(const bfrag*)&Vt[0][nf * 16 + lr][vs];
      const bfrag vb2 = *(const bfrag*)&Vt[1][nf * 16 + lr][vs];
      const bfrag vb3 = *(const bfrag*)&Vt[2][nf * 16 + lr][vs];
      oM[nf] = __builtin_amdgcn_mfma_f32_16x16x32_bf16(pa1, vb1, oM[nf], 0, 0, 0);
      oC[nf] = __builtin_amdgcn_mfma_f32_16x16x32_bf16(pa2, vb1, oC[nf], 0, 0, 0);
      oC[nf] = __builtin_amdgcn_mfma_f32_16x16x32_bf16(pa3, vb1, oC[nf], 0, 0, 0);
      oC[nf] = __builtin_amdgcn_mfma_f32_16x16x32_bf16(pa1, vb2, oC[nf], 0, 0, 0);
      oC[nf] = __builtin_amdgcn_mfma_f32_16x16x32_bf16(pa2, vb2, oC[nf], 0, 0, 0);
      oC[nf] = __builtin_amdgcn_mfma_f32_16x16x32_bf16(pa1, vb3, oC[nf], 0, 0, 0);
    }
  }

  // ---- epilogue: O/l -> global (rows q=g*4+r, cols d=lr+16*nf) ----
  float* Og = O + base + (size_t)(qt * 64 + wave * 16) * DDIM;
#pragma unroll
  for (int r = 0; r < 4; ++r) {
    const float invl = 1.0f / l[r];
    float* orow = Og + (size_t)(g * 4 + r) * DDIM;
#pragma unroll
    for (int nf = 0; nf < 8; ++nf)
      orow[nf * 16 + lr] = (oM[nf][r] + oC[nf][r]) * invl;
  }
}

// ---------------------------------------------------------------------------
// Final: y = lif2(f32) + spikes2(u8); LayerNorm; float32 store.
// ---------------------------------------------------------------------------
__global__ __launch_bounds__(256)
void ln_kernel(const float* __restrict__ a, const uint8_t* __restrict__ s8,
               const float* __restrict__ gamma, const float* __restrict__ beta,
               float* __restrict__ out) {
  const int row = blockIdx.x;
  const int tid = threadIdx.x;
  const size_t base = (size_t)row * DDIM;
  const float4 av = *(const float4*)(a + base + tid * 4);
  const uchar4 sv = *(const uchar4*)(s8 + base + tid * 4);
  const float y0 = av.x + (float)sv.x, y1 = av.y + (float)sv.y;
  const float y2 = av.z + (float)sv.z, y3 = av.w + (float)sv.w;
  float s = (y0 + y1) + (y2 + y3);
  float q = (y0 * y0 + y1 * y1) + (y2 * y2 + y3 * y3);
#pragma unroll
  for (int off = 1; off < 64; off <<= 1) {
    s += __shfl_xor(s, off);
    q += __shfl_xor(q, off);
  }
  __shared__ float red[8];
  const int wid = tid >> 6;
  if ((tid & 63) == 0) { red[wid * 2] = s; red[wid * 2 + 1] = q; }
  __syncthreads();
  const float ts = (red[0] + red[2]) + (red[4] + red[6]);
  const float tq = (red[1] + red[3]) + (red[5] + red[7]);
  const float mu  = ts * (1.0f / 1024.0f);
  const float var = tq * (1.0f / 1024.0f) - mu * mu;
  const float rs  = 1.0f / sqrtf(var + 1e-5f);
  const int d = tid * 4;
  const float4 gv  = *(const float4*)(gamma + d);
  const float4 btv = *(const float4*)(beta + d);
  float4 r;
  r.x = (y0 - mu) * rs * gv.x + btv.x;
  r.y = (y1 - mu) * rs * gv.y + btv.y;
  r.z = (y2 - mu) * rs * gv.z + btv.z;
  r.w = (y3 - mu) * rs * gv.w + btv.w;
  *(float4*)(out + base + d) = r;
}

// ---------------------------------------------------------------------------
// Workspace: 3 f32 (A,C,D) 50.3 MB + u8 spikes 4.2 MB + B planes 18 MB.
// ---------------------------------------------------------------------------
extern "C" void kernel_launch(void* const* d_in, const int* in_sizes, int n_in,
                              void* d_out, int out_size, void* d_ws, size_t ws_size,
                              hipStream_t stream) {
  const float* x       = (const float*)d_in[0];
  const float* context = (const float*)d_in[1];
  const float* Wg  = (const float*)d_in[2];
  const float* bg  = (const float*)d_in[3];
  const float* Wc  = (const float*)d_in[4];
  const float* Wq  = (const float*)d_in[5];
  const float* Wk  = (const float*)d_in[6];
  const float* Wv  = (const float*)d_in[7];
  const float* Wo  = (const float*)d_in[8];
  const float* Wm  = (const float*)d_in[9];
  const float* rWk = (const float*)d_in[10];
  const float* rWv = (const float*)d_in[11];
  const float* rWr = (const float*)d_in[12];
  const float* rWo = (const float*)d_in[13];
  const float* wd  = (const float*)d_in[14];
  const float* uf  = (const float*)d_in[15];
  const float* gamma = (const float*)d_in[16];
  const float* beta  = (const float*)d_in[17];
  float* out = (float*)d_out;   // reference output dtype = float32

  float* w  = (float*)d_ws;
  float*   bA = w;
  float*   bC = w + 1 * NELEM;
  float*   bD = w + 2 * NELEM;
  uint8_t* bS = (uint8_t*)(w + 3 * NELEM);                          // u8 spikes
  ushort*  pB = (ushort*)((uint8_t*)d_ws + 3 * NELEM * 4 + NELEM);  // B planes

  const dim3 ew(4096);
  constexpr int M1 = 1024 * 1024;   // ushorts per 1024-K plane

  // Stage 1: thalamic gate — single K=2048 GEMM over [x | context]
  cvt_b3t<<<dim3(16, 16, 2), 256, 0, stream>>>(Wg, Wc, nullptr, pB, 0, 1024, 2048);
  gemm_k<0, 0, 1, 2048><<<512, 256, 0, stream>>>(x, context, pB, bA, nullptr, nullptr);
  gate_kernel<<<ew, 256, 0, stream>>>(x, bA, bg, bA);
  // Stage 2: LIF -> spikes2 (u8)
  lif_u8_kernel<<<64, 64, 0, stream>>>(bA, bS);
  // Stage 3: spike self-attention — Q,K,V in ONE N-merged launch
  cvt_b3t<<<dim3(16, 16, 3), 256, 0, stream>>>(Wq, Wk, Wv, pB, 3 * M1, 0, 1024);
  gemm_k<0, 1, 3, 1024><<<1536, 256, 0, stream>>>(bS, nullptr, pB, bA, bC, bD);
  flash_attn<<<512, 256, 0, stream>>>(bA, bC, bD, bA);
  cvt_b3t<<<dim3(16, 16, 1), 256, 0, stream>>>(Wo, nullptr, nullptr, pB, 0, 0, 1024);
  gemm_k<0, 0, 1, 1024><<<512, 256, 0, stream>>>(bA, nullptr, pB, bC, nullptr, nullptr);
  // Stage 4: apical modulation
  cvt_b3t<<<dim3(16, 16, 1), 256, 0, stream>>>(Wm, nullptr, nullptr, pB, 0, 0, 1024);
  gemm_k<0, 0, 1, 1024><<<512, 256, 0, stream>>>(context, nullptr, pB, bA, nullptr, nullptr);
  mod_kernel<<<ew, 256, 0, stream>>>(bC, bA, bD);          // bD = modulated
  // Stage 5: RWKV — k,v N-merged
  cvt_b3t<<<dim3(16, 16, 2), 256, 0, stream>>>(rWk, rWv, nullptr, pB, 3 * M1, 0, 1024);
  gemm_k<0, 0, 2, 1024><<<1024, 256, 0, stream>>>(bD, nullptr, pB, bA, bC, nullptr);
  rwkv_kernel<<<64, 64, 0, stream>>>(bA, bC, wd, uf, bA);  // bA = wkv
  cvt_b3t<<<dim3(16, 16, 1), 256, 0, stream>>>(rWr, nullptr, nullptr, pB, 0, 0, 1024);
  gemm_k<0, 0, 1, 1024><<<512, 256, 0, stream>>>(bD, nullptr, pB, bC, nullptr, nullptr);
  rmul_kernel<<<ew, 256, 0, stream>>>(bC, bA, bA);         // bA = sig(r)*wkv
  cvt_b3t<<<dim3(16, 16, 1), 256, 0, stream>>>(rWo, nullptr, nullptr, pB, 0, 0, 1024);
  gemm_k<0, 0, 1, 1024><<<512, 256, 0, stream>>>(bA, nullptr, pB, bC, nullptr, nullptr);
  // Stage 6: output LIF (in-place) + residual + LayerNorm
  lif_ip_kernel<<<64, 64, 0, stream>>>(bC);
  ln_kernel<<<4096, 256, 0, stream>>>(bC, bS, gamma, beta, out);
}

// Round 13
// 1199.550 us; speedup vs baseline: 2.8212x; 1.3027x over previous
//
#include <hip/hip_runtime.h>
#include <hip/hip_bf16.h>
#include <math.h>

// Problem dims (fixed)
#define BDIM 4
#define TDIM 1024
#define DDIM 1024
#define DH   128
#define NELEM ((size_t)BDIM * TDIM * DDIM)   // 4,194,304

typedef __attribute__((ext_vector_type(8))) _Float16 hfrag;  // 8 f16 (4 VGPR)
typedef __attribute__((ext_vector_type(4))) float facc;      // 4 f32 acc

// f16 2-plane split: x = h1 + h2/2048 (22 mantissa bits; h2 scaled by 2^11
// so it stays in f16 normal range). Kept passes a1b1, a1b2, a2b1; dropped
// a2b2 ~2^-22 rel (~4e-7/dot, same decade as the bit-exact-proven 6-pass).
__device__ __forceinline__ void split2(float x, ushort& h1, ushort& h2) {
  const _Float16 a = (_Float16)x;
  const _Float16 b = (_Float16)((x - (float)a) * 2048.0f);
  union { _Float16 h; ushort u; } ua, ub;
  ua.h = a; ub.h = b;
  h1 = ua.u; h2 = ub.u;
}
#define INV2048 4.8828125e-4f    // 1/2048, exact

constexpr int GM = 4096, GN = 1024, GK = 1024;
constexpr int BM = 128, BK = 32;
constexpr int BKP = 40;                    // padded LDS k-dim (80 B rows)

// ---------------------------------------------------------------------------
// cvt_h2t: up to 3 weight matrices [1024][1024] f32 -> 2-plane f16 split,
// blocked-transposed [kTot/32][N=1024][32].
// ---------------------------------------------------------------------------
__global__ __launch_bounds__(256)
void cvt_h2t(const float* __restrict__ W0, const float* __restrict__ W1,
             const float* __restrict__ W2, ushort* __restrict__ P,
             int zstride, int zkoff, int kTot) {
  __shared__ float Ls[64][68];
  const int z = blockIdx.z;
  const float* W = (z == 0) ? W0 : (z == 1 ? W1 : W2);
  ushort* Pz = P + (size_t)z * zstride;
  const size_t PS = (size_t)kTot * GN;     // ushorts per plane
  const int t = threadIdx.x;
  const int k0 = blockIdx.x * 64, n0 = blockIdx.y * 64;
  const int r = t >> 4, c4 = (t & 15) << 2;
#pragma unroll
  for (int i = 0; i < 4; ++i)
    *(float4*)&Ls[r + i * 16][c4] =
        *(const float4*)(W + (size_t)(k0 + r + i * 16) * GN + n0 + c4);
  __syncthreads();
  const int n = t >> 2, kc = (t & 3) << 4;
  uint p1[8], p2[8];
#pragma unroll
  for (int jj = 0; jj < 8; ++jj) {
    const float x0 = Ls[kc + 2 * jj][n], x1 = Ls[kc + 2 * jj + 1][n];
    ushort a1, a2, b1, b2;
    split2(x0, a1, a2);
    split2(x1, b1, b2);
    p1[jj] = (uint)a1 | ((uint)b1 << 16);
    p2[jj] = (uint)a2 | ((uint)b2 << 16);
  }
  const int kk = k0 + kc + z * zkoff;
  ushort* d = Pz + (size_t)(kk >> 5) * (GN * 32) + (size_t)(n0 + n) * 32 + (kk & 31);
  *(uint4*)(d)          = *(uint4*)&p1[0];
  *(uint4*)(d + 8)      = *(uint4*)&p1[4];
  *(uint4*)(d + PS)     = *(uint4*)&p2[0];
  *(uint4*)(d + PS + 8) = *(uint4*)&p2[4];
}

// ---------------------------------------------------------------------------
// GEMM via 2-plane f16 MFMA (3 passes; AU8 spikes exact -> 2 passes).
// Tile 128x64, 4 waves, LDS 31 KB. NMAT: N-merged. KTOT=2048: K-merged A.
// accM += a1*b1; accS += a1*b2 + a2*b1; result = accM + accS/2048.
// ---------------------------------------------------------------------------
template<int EPI, int AU8, int NMAT, int KTOT>
__global__ __launch_bounds__(256)
void gemm_k(const void* __restrict__ Av, const void* __restrict__ Av2,
            const ushort* __restrict__ pB,
            float* __restrict__ C0, float* __restrict__ C1,
            float* __restrict__ C2) {
  constexpr size_t PS = (size_t)KTOT * GN;   // ushorts per plane
  __shared__ ushort As[2][BM][BKP];
  __shared__ ushort Bs[2][64][BKP];
  const int tid = threadIdx.x;
  const int n   = blockIdx.x;
  const int xcd = n & 7;
  const int idx = n >> 3;
  const int by  = xcd * 4 + (idx & 3);
  const int bx  = idx >> 2;
  const int mat = bx >> 4;
  const int row0 = by * BM;
  const int col0 = (bx & 15) * 64;
  const ushort* pBm = pB + (size_t)mat * 2 * PS;
  float* C = (mat == 0) ? C0 : (mat == 1 ? C1 : C2);

  const int sm  = tid & 127;
  const int sk0 = (tid >> 7) << 4;

  const int wave = tid >> 6;
  const int lane = tid & 63;
  const int wrow = (wave >> 1) * 64;
  const int wcol = (wave & 1) * 32;
  const int lrow = lane & 15;
  const int kof  = (lane >> 4) * 8;

  facc accM[4][2], accS[4][2];
#pragma unroll
  for (int i = 0; i < 4; ++i)
#pragma unroll
    for (int j = 0; j < 2; ++j) { accM[i][j] = (facc)0.f; accS[i][j] = (facc)0.f; }

  float av[16];
  uint4 a8raw;
  uint4 bregs[2];

  auto gloadA = [&](int K0) {
    const void* src = Av; int k = K0;
    if (KTOT > 1024 && K0 >= 1024) { src = Av2; k = K0 - 1024; }
    if (AU8) {
      a8raw = *(const uint4*)((const uint8_t*)src + (size_t)(row0 + sm) * 1024 + k + sk0);
    } else {
      const float* Ap = (const float*)src + (size_t)(row0 + sm) * 1024 + k + sk0;
      *(float4*)&av[0]  = *(const float4*)(Ap);
      *(float4*)&av[4]  = *(const float4*)(Ap + 4);
      *(float4*)&av[8]  = *(const float4*)(Ap + 8);
      *(float4*)&av[12] = *(const float4*)(Ap + 12);
    }
  };
  auto gloadB = [&](int K0) {
    const int kb = K0 >> 5;
#pragma unroll
    for (int j = 0; j < 2; ++j) {
      const int u = tid + 256 * j;
      const int q = u & 3, nn = (u >> 2) & 63, p = u >> 8;
      bregs[j] = *(const uint4*)(pBm + (size_t)p * PS + (size_t)kb * (GN * 32)
                                 + (size_t)(col0 + nn) * 32 + q * 8);
    }
  };
  auto swrite = [&]() {
    if (AU8) {
      const uint w4[4] = {a8raw.x, a8raw.y, a8raw.z, a8raw.w};
      uint pk[8];
#pragma unroll
      for (int i = 0; i < 8; ++i) {
        const uint b0 = (w4[i >> 1] >> ((i & 1) * 16)) & 0xFFu;
        const uint b1 = (w4[i >> 1] >> ((i & 1) * 16 + 8)) & 0xFFu;
        pk[i] = (b0 * 0x3C00u) | ((b1 * 0x3C00u) << 16);   // f16 1.0 = 0x3C00
      }
      *(uint4*)&As[0][sm][sk0]     = *(uint4*)&pk[0];
      *(uint4*)&As[0][sm][sk0 + 8] = *(uint4*)&pk[4];
    } else {
      uint q1[8], q2[8];
#pragma unroll
      for (int i = 0; i < 8; ++i) {
        ushort a1, a2, b1, b2;
        split2(av[2 * i], a1, a2);
        split2(av[2 * i + 1], b1, b2);
        q1[i] = (uint)a1 | ((uint)b1 << 16);
        q2[i] = (uint)a2 | ((uint)b2 << 16);
      }
      *(uint4*)&As[0][sm][sk0]     = *(uint4*)&q1[0];
      *(uint4*)&As[0][sm][sk0 + 8] = *(uint4*)&q1[4];
      *(uint4*)&As[1][sm][sk0]     = *(uint4*)&q2[0];
      *(uint4*)&As[1][sm][sk0 + 8] = *(uint4*)&q2[4];
    }
#pragma unroll
    for (int j = 0; j < 2; ++j) {
      const int u = tid + 256 * j;
      const int q = u & 3, nn = (u >> 2) & 63, p = u >> 8;
      *(uint4*)&Bs[p][nn][q * 8] = bregs[j];
    }
  };

  gloadA(0); gloadB(0);
  for (int k0 = 0; k0 < KTOT; k0 += BK) {
    __syncthreads();
    swrite();
    const int kn = k0 + BK;
    if (kn < KTOT) { gloadA(kn); gloadB(kn); }
    __syncthreads();
    hfrag fb1[2], fb2[2];
#pragma unroll
    for (int f = 0; f < 2; ++f) {
      fb1[f] = *(const hfrag*)&Bs[0][wcol + f * 16 + lrow][kof];
      fb2[f] = *(const hfrag*)&Bs[1][wcol + f * 16 + lrow][kof];
    }
#pragma unroll
    for (int mi = 0; mi < 4; ++mi) {
      const hfrag a1 = *(const hfrag*)&As[0][wrow + mi * 16 + lrow][kof];
      hfrag a2;
      if (!AU8) a2 = *(const hfrag*)&As[1][wrow + mi * 16 + lrow][kof];
#pragma unroll
      for (int ni = 0; ni < 2; ++ni)
        accM[mi][ni] = __builtin_amdgcn_mfma_f32_16x16x32_f16(a1, fb1[ni], accM[mi][ni], 0, 0, 0);
#pragma unroll
      for (int ni = 0; ni < 2; ++ni) {
        accS[mi][ni] = __builtin_amdgcn_mfma_f32_16x16x32_f16(a1, fb2[ni], accS[mi][ni], 0, 0, 0);
        if (!AU8)
          accS[mi][ni] = __builtin_amdgcn_mfma_f32_16x16x32_f16(a2, fb1[ni], accS[mi][ni], 0, 0, 0);
      }
    }
  }

  // epilogue: D frag col = lane&15, row = (lane>>4)*4 + reg (m89/m91).
#pragma unroll
  for (int mi = 0; mi < 4; ++mi) {
#pragma unroll
    for (int ni = 0; ni < 2; ++ni) {
      const int rbase = row0 + wrow + mi * 16 + (lane >> 4) * 4;
      const int cc    = col0 + wcol + ni * 16 + lrow;
      float* cp = C + (size_t)rbase * GN + cc;
#pragma unroll
      for (int r = 0; r < 4; ++r) {
        float v = accM[mi][ni][r] + accS[mi][ni][r] * INV2048;
        if (EPI == 1) v += cp[(size_t)r * GN];
        cp[(size_t)r * GN] = v;
      }
    }
  }
}

// ---------------------------------------------------------------------------
// Elementwise kernels
// ---------------------------------------------------------------------------
__device__ __forceinline__ float sigf(float z) { return 1.0f / (1.0f + expf(-z)); }

__global__ __launch_bounds__(256)
void gate_kernel(const float* __restrict__ x, const float* __restrict__ L,
                 const float* __restrict__ bg, float* __restrict__ out) {
  const int i4 = blockIdx.x * 256 + threadIdx.x;
  const float4 xv = ((const float4*)x)[i4];
  const float4 lv = ((const float4*)L)[i4];
  const float4 bv = ((const float4*)bg)[i4 & 255];
  float4 r;
  r.x = xv.x * (0.5f * sigf(lv.x + bv.x) + 0.5f);
  r.y = xv.y * (0.5f * sigf(lv.y + bv.y) + 0.5f);
  r.z = xv.z * (0.5f * sigf(lv.z + bv.z) + 0.5f);
  r.w = xv.w * (0.5f * sigf(lv.w + bv.w) + 0.5f);
  ((float4*)out)[i4] = r;
}

__global__ __launch_bounds__(256)
void mod_kernel(const float* __restrict__ a, const float* __restrict__ c,
                float* __restrict__ out) {
  const int i4 = blockIdx.x * 256 + threadIdx.x;
  const float4 av = ((const float4*)a)[i4];
  const float4 cv = ((const float4*)c)[i4];
  float4 r;
  r.x = av.x * (1.0f + tanhf(cv.x));
  r.y = av.y * (1.0f + tanhf(cv.y));
  r.z = av.z * (1.0f + tanhf(cv.z));
  r.w = av.w * (1.0f + tanhf(cv.w));
  ((float4*)out)[i4] = r;
}

__global__ __launch_bounds__(256)
void rmul_kernel(const float* __restrict__ rr, const float* __restrict__ wkv,
                 float* __restrict__ out) {
  const int i4 = blockIdx.x * 256 + threadIdx.x;
  const float4 rv = ((const float4*)rr)[i4];
  const float4 wv = ((const float4*)wkv)[i4];
  float4 r;
  r.x = sigf(rv.x) * wv.x;
  r.y = sigf(rv.y) * wv.y;
  r.z = sigf(rv.z) * wv.z;
  r.w = sigf(rv.w) * wv.w;
  ((float4*)out)[i4] = r;
}

// ---------------------------------------------------------------------------
// LIF scans (software-pipelined, proven R10)
// ---------------------------------------------------------------------------
__global__ __launch_bounds__(64)
void lif_u8_kernel(const float* __restrict__ x, uint8_t* __restrict__ s) {
  const int c = blockIdx.x * 64 + threadIdx.x;
  const size_t off = (size_t)(c >> 10) * TDIM * DDIM + (c & 1023);
  const float* xp = x + off;
  uint8_t* sp = s + off;
  float u = 0.f;
  float cur[8];
#pragma unroll
  for (int i = 0; i < 8; ++i) cur[i] = xp[(size_t)i * DDIM];
  for (int t = 0; t < TDIM; t += 8) {
    float nxt[8];
    if (t + 8 < TDIM) {
#pragma unroll
      for (int i = 0; i < 8; ++i) nxt[i] = xp[(size_t)(t + 8 + i) * DDIM];
    }
#pragma unroll
    for (int i = 0; i < 8; ++i) {
      u = __fadd_rn(__fmul_rn(0.9f, u), cur[i]);
      const bool fire = (u >= 1.0f);
      sp[(size_t)(t + i) * DDIM] = fire ? 1 : 0;
      if (fire) u -= 1.0f;
    }
#pragma unroll
    for (int i = 0; i < 8; ++i) cur[i] = nxt[i];
  }
}

__global__ __launch_bounds__(64)
void lif_ip_kernel(float* __restrict__ x) {
  const int c = blockIdx.x * 64 + threadIdx.x;
  const size_t off = (size_t)(c >> 10) * TDIM * DDIM + (c & 1023);
  float* xp = x + off;
  float u = 0.f;
  float cur[8];
#pragma unroll
  for (int i = 0; i < 8; ++i) cur[i] = xp[(size_t)i * DDIM];
  for (int t = 0; t < TDIM; t += 8) {
    float nxt[8];
    if (t + 8 < TDIM) {
#pragma unroll
      for (int i = 0; i < 8; ++i) nxt[i] = xp[(size_t)(t + 8 + i) * DDIM];
    }
#pragma unroll
    for (int i = 0; i < 8; ++i) {
      u = __fadd_rn(__fmul_rn(0.9f, u), cur[i]);
      const float sv = (u >= 1.0f) ? 1.0f : 0.0f;
      xp[(size_t)(t + i) * DDIM] = sv;
      u -= sv;
    }
#pragma unroll
    for (int i = 0; i < 8; ++i) cur[i] = nxt[i];
  }
}

__global__ __launch_bounds__(64)
void rwkv_kernel(const float* __restrict__ k, const float* __restrict__ v,
                 const float* __restrict__ wd, const float* __restrict__ uf,
                 float* __restrict__ out) {
  const int c = blockIdx.x * 64 + threadIdx.x;
  const int d = c & 1023;
  const size_t off = (size_t)(c >> 10) * TDIM * DDIM + d;
  const float* kp = k + off;
  const float* vp = v + off;
  float* op = out + off;
  const float w = expf(wd[d]);
  const float u = uf[d];
  float aa = 0.f, bb = 0.f, pp = -1e30f;
  float kc[4], vc[4];
#pragma unroll
  for (int i = 0; i < 4; ++i) {
    kc[i] = kp[(size_t)i * DDIM];
    vc[i] = vp[(size_t)i * DDIM];
  }
  for (int t = 0; t < TDIM; t += 4) {
    float kn[4], vn[4];
    if (t + 4 < TDIM) {
#pragma unroll
      for (int i = 0; i < 4; ++i) {
        kn[i] = kp[(size_t)(t + 4 + i) * DDIM];
        vn[i] = vp[(size_t)(t + 4 + i) * DDIM];
      }
    }
#pragma unroll
    for (int i = 0; i < 4; ++i) {
      const float kt = kc[i], vt = vc[i];
      const float ww = __fadd_rn(u, kt);
      const float p  = fmaxf(pp, ww);
      float e1 = expf(__fsub_rn(pp, p));
      float e2 = expf(__fsub_rn(ww, p));
      const float num = __fadd_rn(__fmul_rn(e1, aa), __fmul_rn(e2, vt));
      const float den = __fadd_rn(__fmul_rn(e1, bb), e2);
      op[(size_t)(t + i) * DDIM] = num / den;
      const float ww2 = __fsub_rn(pp, w);
      const float p2  = fmaxf(ww2, kt);
      e1 = expf(__fsub_rn(ww2, p2));
      e2 = expf(__fsub_rn(kt, p2));
      aa = __fadd_rn(__fmul_rn(e1, aa), __fmul_rn(e2, vt));
      bb = __fadd_rn(__fmul_rn(e1, bb), e2);
      pp = p2;
    }
#pragma unroll
    for (int i = 0; i < 4; ++i) { kc[i] = kn[i]; vc[i] = vn[i]; }
  }
}

// ---------------------------------------------------------------------------
// MFMA flash attention — f16 2-plane split (3 passes). LDS 48 KB ->
// 3 blocks/CU. Vt key-rotation swizzle + K/V global prefetch kept from R12.
// ---------------------------------------------------------------------------
__global__ __launch_bounds__(256)
void flash_attn(const float* __restrict__ Q, const float* __restrict__ K,
                const float* __restrict__ V, float* __restrict__ O) {
  __shared__ ushort Ks[2][32][136];    // [plane][key][kd]     17.4 KB
  __shared__ ushort Vt[2][128][40];    // [plane][d][key-slot] 20.5 KB
  __shared__ ushort Pl[4][2][16][40];  // [wave][plane][q][key] 10.2 KB
  const int tid = threadIdx.x;
  const int n    = blockIdx.x;
  const int xcd  = n & 7;
  const int idx  = n >> 3;
  const int qt   = idx & 15;
  const int grp4 = idx >> 4;
  const int p    = grp4 * 8 + xcd;
  const int b    = p >> 3, h = p & 7;
  const size_t base = ((size_t)b * TDIM) * DDIM + (size_t)h * DH;

  const int wave = tid >> 6;
  const int lane = tid & 63;
  const int lr   = lane & 15;          // frag row/col index
  const int g    = lane >> 4;          // k-group
  const int sr   = tid >> 3;           // staging: key row 0..31
  const int sc   = (tid & 7) * 16;     // staging: d base
  const int vslot = (sr + 8 * (tid & 3)) & 31;   // rotated key slot

  // ---- prologue: Q -> register frags (2 planes x 4 ksteps) ----
  hfrag q1[4], q2[4];
  {
    const float* Qrow = Q + base + (size_t)(qt * 64 + wave * 16 + lr) * DDIM;
#pragma unroll
    for (int s = 0; s < 4; ++s) {
      const float4 f0 = *(const float4*)(Qrow + s * 32 + g * 8);
      const float4 f1 = *(const float4*)(Qrow + s * 32 + g * 8 + 4);
      const float qf[8] = {f0.x, f0.y, f0.z, f0.w, f1.x, f1.y, f1.z, f1.w};
      union { hfrag v; ushort u[8]; } u1, u2;
#pragma unroll
      for (int j = 0; j < 8; ++j) split2(qf[j], u1.u[j], u2.u[j]);
      q1[s] = u1.v; q2[s] = u2.v;
    }
  }

  facc oM[8], oS[8];
#pragma unroll
  for (int i = 0; i < 8; ++i) { oM[i] = (facc)0.f; oS[i] = (facc)0.f; }
  float m[4] = {-INFINITY, -INFINITY, -INFINITY, -INFINITY};
  float l[4] = {0.f, 0.f, 0.f, 0.f};
  const float ISC = 0.08838834764831845f;   // 1/sqrt(128)

  // ---- K/V tile prefetch registers (tile 0) ----
  float kv[16], vv[16];
  auto gload = [&](int kt0) {
    const float* Kg = K + base + (size_t)(kt0 + sr) * DDIM + sc;
    const float* Vg = V + base + (size_t)(kt0 + sr) * DDIM + sc;
    *(float4*)&kv[0]  = *(const float4*)(Kg);
    *(float4*)&kv[4]  = *(const float4*)(Kg + 4);
    *(float4*)&kv[8]  = *(const float4*)(Kg + 8);
    *(float4*)&kv[12] = *(const float4*)(Kg + 12);
    *(float4*)&vv[0]  = *(const float4*)(Vg);
    *(float4*)&vv[4]  = *(const float4*)(Vg + 4);
    *(float4*)&vv[8]  = *(const float4*)(Vg + 8);
    *(float4*)&vv[12] = *(const float4*)(Vg + 12);
  };
  gload(0);

  for (int kt0 = 0; kt0 < TDIM; kt0 += 32) {
    __syncthreads();                  // prev tile's reads of Ks/Vt done
    {                                 // ---- stage from prefetched regs ----
      uint w1[8], w2[8];
#pragma unroll
      for (int i = 0; i < 8; ++i) {
        ushort a1, a2, b1, b2;
        split2(kv[2 * i], a1, a2);
        split2(kv[2 * i + 1], b1, b2);
        w1[i] = (uint)a1 | ((uint)b1 << 16);
        w2[i] = (uint)a2 | ((uint)b2 << 16);
      }
      *(uint4*)&Ks[0][sr][sc]     = *(uint4*)&w1[0];
      *(uint4*)&Ks[0][sr][sc + 8] = *(uint4*)&w1[4];
      *(uint4*)&Ks[1][sr][sc]     = *(uint4*)&w2[0];
      *(uint4*)&Ks[1][sr][sc + 8] = *(uint4*)&w2[4];
#pragma unroll
      for (int i = 0; i < 16; ++i) {
        ushort a1, a2;
        split2(vv[i], a1, a2);
        Vt[0][sc + i][vslot] = a1;
        Vt[1][sc + i][vslot] = a2;
      }
    }
    if (kt0 + 32 < TDIM) gload(kt0 + 32);   // lands under compute below
    __syncthreads();

    // ---- QK^T: S frags (2 nfrags of 16 keys), 3-pass split ----
    facc sM0 = (facc)0.f, sS0 = (facc)0.f, sM1 = (facc)0.f, sS1 = (facc)0.f;
#pragma unroll
    for (int s = 0; s < 4; ++s) {
      const int ko = s * 32 + g * 8;
      const hfrag kb10 = *(const hfrag*)&Ks[0][lr][ko];
      const hfrag kb11 = *(const hfrag*)&Ks[0][lr + 16][ko];
      const hfrag kb20 = *(const hfrag*)&Ks[1][lr][ko];
      const hfrag kb21 = *(const hfrag*)&Ks[1][lr + 16][ko];
      sM0 = __builtin_amdgcn_mfma_f32_16x16x32_f16(q1[s], kb10, sM0, 0, 0, 0);
      sS0 = __builtin_amdgcn_mfma_f32_16x16x32_f16(q1[s], kb20, sS0, 0, 0, 0);
      sS0 = __builtin_amdgcn_mfma_f32_16x16x32_f16(q2[s], kb10, sS0, 0, 0, 0);
      sM1 = __builtin_amdgcn_mfma_f32_16x16x32_f16(q1[s], kb11, sM1, 0, 0, 0);
      sS1 = __builtin_amdgcn_mfma_f32_16x16x32_f16(q1[s], kb21, sS1, 0, 0, 0);
      sS1 = __builtin_amdgcn_mfma_f32_16x16x32_f16(q2[s], kb11, sS1, 0, 0, 0);
    }

    // ---- online softmax (rows q=g*4+r; 16-lane reduce over keys) ----
#pragma unroll
    for (int r = 0; r < 4; ++r) {
      const float sc0 = (sM0[r] + sS0[r] * INV2048) * ISC;   // key = lr
      const float sc1 = (sM1[r] + sS1[r] * INV2048) * ISC;   // key = lr+16
      float mx = fmaxf(sc0, sc1);
      mx = fmaxf(mx, __shfl_xor(mx, 1, 16));
      mx = fmaxf(mx, __shfl_xor(mx, 2, 16));
      mx = fmaxf(mx, __shfl_xor(mx, 4, 16));
      mx = fmaxf(mx, __shfl_xor(mx, 8, 16));
      const float mn = fmaxf(m[r], mx);
      const float rf = expf(m[r] - mn);
      const float p0 = expf(sc0 - mn), p1 = expf(sc1 - mn);
      float ps = p0 + p1;
      ps += __shfl_xor(ps, 1, 16);
      ps += __shfl_xor(ps, 2, 16);
      ps += __shfl_xor(ps, 4, 16);
      ps += __shfl_xor(ps, 8, 16);
      l[r] = l[r] * rf + ps;
      m[r] = mn;
#pragma unroll
      for (int nf = 0; nf < 8; ++nf) { oM[nf][r] *= rf; oS[nf][r] *= rf; }
      ushort a1, a2;
      split2(p0, a1, a2);
      Pl[wave][0][g * 4 + r][lr] = a1;
      Pl[wave][1][g * 4 + r][lr] = a2;
      split2(p1, a1, a2);
      Pl[wave][0][g * 4 + r][lr + 16] = a1;
      Pl[wave][1][g * 4 + r][lr + 16] = a2;
    }

    // ---- PV: O += P @ V (wave-private P; Vt reads at rotated slot) ----
    const hfrag pa1 = *(const hfrag*)&Pl[wave][0][lr][g * 8];
    const hfrag pa2 = *(const hfrag*)&Pl[wave][1][lr][g * 8];
#pragma unroll
    for (int nf = 0; nf < 8; ++nf) {
      const int vs = 8 * ((g + nf) & 3);             // rotated key-slot base
      const hfrag vb1 = *(const hfrag*)&Vt[0][nf * 16 + lr][vs];
      const hfrag vb2 = *(const hfrag*)&Vt[1][nf * 16 + lr][vs];
      oM[nf] = __builtin_amdgcn_mfma_f32_16x16x32_f16(pa1, vb1, oM[nf], 0, 0, 0);
      oS[nf] = __builtin_amdgcn_mfma_f32_16x16x32_f16(pa1, vb2, oS[nf], 0, 0, 0);
      oS[nf] = __builtin_amdgcn_mfma_f32_16x16x32_f16(pa2, vb1, oS[nf], 0, 0, 0);
    }
  }

  // ---- epilogue: O/l -> global (rows q=g*4+r, cols d=lr+16*nf) ----
  float* Og = O + base + (size_t)(qt * 64 + wave * 16) * DDIM;
#pragma unroll
  for (int r = 0; r < 4; ++r) {
    const float invl = 1.0f / l[r];
    float* orow = Og + (size_t)(g * 4 + r) * DDIM;
#pragma unroll
    for (int nf = 0; nf < 8; ++nf)
      orow[nf * 16 + lr] = (oM[nf][r] + oS[nf][r] * INV2048) * invl;
  }
}

// ---------------------------------------------------------------------------
// Final: y = lif2(f32) + spikes2(u8); LayerNorm; float32 store.
// ---------------------------------------------------------------------------
__global__ __launch_bounds__(256)
void ln_kernel(const float* __restrict__ a, const uint8_t* __restrict__ s8,
               const float* __restrict__ gamma, const float* __restrict__ beta,
               float* __restrict__ out) {
  const int row = blockIdx.x;
  const int tid = threadIdx.x;
  const size_t base = (size_t)row * DDIM;
  const float4 av = *(const float4*)(a + base + tid * 4);
  const uchar4 sv = *(const uchar4*)(s8 + base + tid * 4);
  const float y0 = av.x + (float)sv.x, y1 = av.y + (float)sv.y;
  const float y2 = av.z + (float)sv.z, y3 = av.w + (float)sv.w;
  float s = (y0 + y1) + (y2 + y3);
  float q = (y0 * y0 + y1 * y1) + (y2 * y2 + y3 * y3);
#pragma unroll
  for (int off = 1; off < 64; off <<= 1) {
    s += __shfl_xor(s, off);
    q += __shfl_xor(q, off);
  }
  __shared__ float red[8];
  const int wid = tid >> 6;
  if ((tid & 63) == 0) { red[wid * 2] = s; red[wid * 2 + 1] = q; }
  __syncthreads();
  const float ts = (red[0] + red[2]) + (red[4] + red[6]);
  const float tq = (red[1] + red[3]) + (red[5] + red[7]);
  const float mu  = ts * (1.0f / 1024.0f);
  const float var = tq * (1.0f / 1024.0f) - mu * mu;
  const float rs  = 1.0f / sqrtf(var + 1e-5f);
  const int d = tid * 4;
  const float4 gv  = *(const float4*)(gamma + d);
  const float4 btv = *(const float4*)(beta + d);
  float4 r;
  r.x = (y0 - mu) * rs * gv.x + btv.x;
  r.y = (y1 - mu) * rs * gv.y + btv.y;
  r.z = (y2 - mu) * rs * gv.z + btv.z;
  r.w = (y3 - mu) * rs * gv.w + btv.w;
  *(float4*)(out + base + d) = r;
}

// ---------------------------------------------------------------------------
// Workspace: 3 f32 (A,C,D) 50.3 MB + u8 spikes 4.2 MB + B planes 12 MB.
// ---------------------------------------------------------------------------
extern "C" void kernel_launch(void* const* d_in, const int* in_sizes, int n_in,
                              void* d_out, int out_size, void* d_ws, size_t ws_size,
                              hipStream_t stream) {
  const float* x       = (const float*)d_in[0];
  const float* context = (const float*)d_in[1];
  const float* Wg  = (const float*)d_in[2];
  const float* bg  = (const float*)d_in[3];
  const float* Wc  = (const float*)d_in[4];
  const float* Wq  = (const float*)d_in[5];
  const float* Wk  = (const float*)d_in[6];
  const float* Wv  = (const float*)d_in[7];
  const float* Wo  = (const float*)d_in[8];
  const float* Wm  = (const float*)d_in[9];
  const float* rWk = (const float*)d_in[10];
  const float* rWv = (const float*)d_in[11];
  const float* rWr = (const float*)d_in[12];
  const float* rWo = (const float*)d_in[13];
  const float* wd  = (const float*)d_in[14];
  const float* uf  = (const float*)d_in[15];
  const float* gamma = (const float*)d_in[16];
  const float* beta  = (const float*)d_in[17];
  float* out = (float*)d_out;   // reference output dtype = float32

  float* w  = (float*)d_ws;
  float*   bA = w;
  float*   bC = w + 1 * NELEM;
  float*   bD = w + 2 * NELEM;
  uint8_t* bS = (uint8_t*)(w + 3 * NELEM);                          // u8 spikes
  ushort*  pB = (ushort*)((uint8_t*)d_ws + 3 * NELEM * 4 + NELEM);  // B planes

  const dim3 ew(4096);
  constexpr int M1 = 1024 * 1024;   // ushorts per 1024-K plane

  // Stage 1: thalamic gate — single K=2048 GEMM over [x | context]
  cvt_h2t<<<dim3(16, 16, 2), 256, 0, stream>>>(Wg, Wc, nullptr, pB, 0, 1024, 2048);
  gemm_k<0, 0, 1, 2048><<<512, 256, 0, stream>>>(x, context, pB, bA, nullptr, nullptr);
  gate_kernel<<<ew, 256, 0, stream>>>(x, bA, bg, bA);
  // Stage 2: LIF -> spikes2 (u8)
  lif_u8_kernel<<<64, 64, 0, stream>>>(bA, bS);
  // Stage 3: spike self-attention — Q,K,V in ONE N-merged launch
  cvt_h2t<<<dim3(16, 16, 3), 256, 0, stream>>>(Wq, Wk, Wv, pB, 2 * M1, 0, 1024);
  gemm_k<0, 1, 3, 1024><<<1536, 256, 0, stream>>>(bS, nullptr, pB, bA, bC, bD);
  flash_attn<<<512, 256, 0, stream>>>(bA, bC, bD, bA);
  cvt_h2t<<<dim3(16, 16, 1), 256, 0, stream>>>(Wo, nullptr, nullptr, pB, 0, 0, 1024);
  gemm_k<0, 0, 1, 1024><<<512, 256, 0, stream>>>(bA, nullptr, pB, bC, nullptr, nullptr);
  // Stage 4: apical modulation
  cvt_h2t<<<dim3(16, 16, 1), 256, 0, stream>>>(Wm, nullptr, nullptr, pB, 0, 0, 1024);
  gemm_k<0, 0, 1, 1024><<<512, 256, 0, stream>>>(context, nullptr, pB, bA, nullptr, nullptr);
  mod_kernel<<<ew, 256, 0, stream>>>(bC, bA, bD);          // bD = modulated
  // Stage 5: RWKV — k,v N-merged
  cvt_h2t<<<dim3(16, 16, 2), 256, 0, stream>>>(rWk, rWv, nullptr, pB, 2 * M1, 0, 1024);
  gemm_k<0, 0, 2, 1024><<<1024, 256, 0, stream>>>(bD, nullptr, pB, bA, bC, nullptr);
  rwkv_kernel<<<64, 64, 0, stream>>>(bA, bC, wd, uf, bA);  // bA = wkv
  cvt_h2t<<<dim3(16, 16, 1), 256, 0, stream>>>(rWr, nullptr, nullptr, pB, 0, 0, 1024);
  gemm_k<0, 0, 1, 1024><<<512, 256, 0, stream>>>(bD, nullptr, pB, bC, nullptr, nullptr);
  rmul_kernel<<<ew, 256, 0, stream>>>(bC, bA, bA);         // bA = sig(r)*wkv
  cvt_h2t<<<dim3(16, 16, 1), 256, 0, stream>>>(rWo, nullptr, nullptr, pB, 0, 0, 1024);
  gemm_k<0, 0, 1, 1024><<<512, 256, 0, stream>>>(bA, nullptr, pB, bC, nullptr, nullptr);
  // Stage 6: output LIF (in-place) + residual + LayerNorm
  lif_ip_kernel<<<64, 64, 0, stream>>>(bC);
  ln_kernel<<<4096, 256, 0, stream>>>(bC, bS, gamma, beta, out);
}

// Round 14
// 1029.157 us; speedup vs baseline: 3.2883x; 1.1656x over previous
//
#include <hip/hip_runtime.h>
#include <hip/hip_bf16.h>
#include <math.h>

// Problem dims (fixed)
#define BDIM 4
#define TDIM 1024
#define DDIM 1024
#define DH   128
#define NELEM ((size_t)BDIM * TDIM * DDIM)   // 4,194,304

typedef __attribute__((ext_vector_type(8))) _Float16 hfrag;  // 8 f16 (4 VGPR)
typedef __attribute__((ext_vector_type(4))) float facc;      // 4 f32 acc

// f16 2-plane split: x = h1 + h2/2048 (22 mantissa bits). Passes a1b1,
// a1b2, a2b1 kept; a2b2 (~2^-22 rel) dropped. Proven R13 (absmax 0.0).
__device__ __forceinline__ void split2(float x, ushort& h1, ushort& h2) {
  const _Float16 a = (_Float16)x;
  const _Float16 b = (_Float16)((x - (float)a) * 2048.0f);
  union { _Float16 h; ushort u; } ua, ub;
  ua.h = a; ub.h = b;
  h1 = ua.u; h2 = ub.u;
}
#define INV2048 4.8828125e-4f    // 1/2048, exact

// Fast exp for rwkv state math: v_exp_f32(x*log2e). ~2 ulp; exact at x=0
// (exp2(0)=1) which preserves the stabilizer's exact-1 path. Error class
// ~3e-7 rel == the proven-safe GEMM-split noise (R13 absmax 0.0).
__device__ __forceinline__ float fexp(float x) {
  return __builtin_amdgcn_exp2f(x * 1.4426950408889634f);
}

constexpr int GM = 4096, GN = 1024, GK = 1024;
constexpr int BM = 128, BK = 32;
constexpr int BKP = 40;                    // padded LDS k-dim (80 B rows)

// ---------------------------------------------------------------------------
// cvt_h2t: up to 3 weight matrices [1024][1024] f32 -> 2-plane f16 split,
// blocked-transposed [kTot/32][N=1024][32].
// ---------------------------------------------------------------------------
__global__ __launch_bounds__(256)
void cvt_h2t(const float* __restrict__ W0, const float* __restrict__ W1,
             const float* __restrict__ W2, ushort* __restrict__ P,
             int zstride, int zkoff, int kTot) {
  __shared__ float Ls[64][68];
  const int z = blockIdx.z;
  const float* W = (z == 0) ? W0 : (z == 1 ? W1 : W2);
  ushort* Pz = P + (size_t)z * zstride;
  const size_t PS = (size_t)kTot * GN;     // ushorts per plane
  const int t = threadIdx.x;
  const int k0 = blockIdx.x * 64, n0 = blockIdx.y * 64;
  const int r = t >> 4, c4 = (t & 15) << 2;
#pragma unroll
  for (int i = 0; i < 4; ++i)
    *(float4*)&Ls[r + i * 16][c4] =
        *(const float4*)(W + (size_t)(k0 + r + i * 16) * GN + n0 + c4);
  __syncthreads();
  const int n = t >> 2, kc = (t & 3) << 4;
  uint p1[8], p2[8];
#pragma unroll
  for (int jj = 0; jj < 8; ++jj) {
    const float x0 = Ls[kc + 2 * jj][n], x1 = Ls[kc + 2 * jj + 1][n];
    ushort a1, a2, b1, b2;
    split2(x0, a1, a2);
    split2(x1, b1, b2);
    p1[jj] = (uint)a1 | ((uint)b1 << 16);
    p2[jj] = (uint)a2 | ((uint)b2 << 16);
  }
  const int kk = k0 + kc + z * zkoff;
  ushort* d = Pz + (size_t)(kk >> 5) * (GN * 32) + (size_t)(n0 + n) * 32 + (kk & 31);
  *(uint4*)(d)          = *(uint4*)&p1[0];
  *(uint4*)(d + 8)      = *(uint4*)&p1[4];
  *(uint4*)(d + PS)     = *(uint4*)&p2[0];
  *(uint4*)(d + PS + 8) = *(uint4*)&p2[4];
}

// ---------------------------------------------------------------------------
// GEMM via 2-plane f16 MFMA (3 passes; AU8 spikes exact -> 2 passes).
// Tile 128x64, 4 waves, LDS 31 KB. NMAT: N-merged. KTOT=2048: K-merged A.
// ---------------------------------------------------------------------------
template<int EPI, int AU8, int NMAT, int KTOT>
__global__ __launch_bounds__(256)
void gemm_k(const void* __restrict__ Av, const void* __restrict__ Av2,
            const ushort* __restrict__ pB,
            float* __restrict__ C0, float* __restrict__ C1,
            float* __restrict__ C2) {
  constexpr size_t PS = (size_t)KTOT * GN;   // ushorts per plane
  __shared__ ushort As[2][BM][BKP];
  __shared__ ushort Bs[2][64][BKP];
  const int tid = threadIdx.x;
  const int n   = blockIdx.x;
  const int xcd = n & 7;
  const int idx = n >> 3;
  const int by  = xcd * 4 + (idx & 3);
  const int bx  = idx >> 2;
  const int mat = bx >> 4;
  const int row0 = by * BM;
  const int col0 = (bx & 15) * 64;
  const ushort* pBm = pB + (size_t)mat * 2 * PS;
  float* C = (mat == 0) ? C0 : (mat == 1 ? C1 : C2);

  const int sm  = tid & 127;
  const int sk0 = (tid >> 7) << 4;

  const int wave = tid >> 6;
  const int lane = tid & 63;
  const int wrow = (wave >> 1) * 64;
  const int wcol = (wave & 1) * 32;
  const int lrow = lane & 15;
  const int kof  = (lane >> 4) * 8;

  facc accM[4][2], accS[4][2];
#pragma unroll
  for (int i = 0; i < 4; ++i)
#pragma unroll
    for (int j = 0; j < 2; ++j) { accM[i][j] = (facc)0.f; accS[i][j] = (facc)0.f; }

  float av[16];
  uint4 a8raw;
  uint4 bregs[2];

  auto gloadA = [&](int K0) {
    const void* src = Av; int k = K0;
    if (KTOT > 1024 && K0 >= 1024) { src = Av2; k = K0 - 1024; }
    if (AU8) {
      a8raw = *(const uint4*)((const uint8_t*)src + (size_t)(row0 + sm) * 1024 + k + sk0);
    } else {
      const float* Ap = (const float*)src + (size_t)(row0 + sm) * 1024 + k + sk0;
      *(float4*)&av[0]  = *(const float4*)(Ap);
      *(float4*)&av[4]  = *(const float4*)(Ap + 4);
      *(float4*)&av[8]  = *(const float4*)(Ap + 8);
      *(float4*)&av[12] = *(const float4*)(Ap + 12);
    }
  };
  auto gloadB = [&](int K0) {
    const int kb = K0 >> 5;
#pragma unroll
    for (int j = 0; j < 2; ++j) {
      const int u = tid + 256 * j;
      const int q = u & 3, nn = (u >> 2) & 63, p = u >> 8;
      bregs[j] = *(const uint4*)(pBm + (size_t)p * PS + (size_t)kb * (GN * 32)
                                 + (size_t)(col0 + nn) * 32 + q * 8);
    }
  };
  auto swrite = [&]() {
    if (AU8) {
      const uint w4[4] = {a8raw.x, a8raw.y, a8raw.z, a8raw.w};
      uint pk[8];
#pragma unroll
      for (int i = 0; i < 8; ++i) {
        const uint b0 = (w4[i >> 1] >> ((i & 1) * 16)) & 0xFFu;
        const uint b1 = (w4[i >> 1] >> ((i & 1) * 16 + 8)) & 0xFFu;
        pk[i] = (b0 * 0x3C00u) | ((b1 * 0x3C00u) << 16);   // f16 1.0 = 0x3C00
      }
      *(uint4*)&As[0][sm][sk0]     = *(uint4*)&pk[0];
      *(uint4*)&As[0][sm][sk0 + 8] = *(uint4*)&pk[4];
    } else {
      uint q1[8], q2[8];
#pragma unroll
      for (int i = 0; i < 8; ++i) {
        ushort a1, a2, b1, b2;
        split2(av[2 * i], a1, a2);
        split2(av[2 * i + 1], b1, b2);
        q1[i] = (uint)a1 | ((uint)b1 << 16);
        q2[i] = (uint)a2 | ((uint)b2 << 16);
      }
      *(uint4*)&As[0][sm][sk0]     = *(uint4*)&q1[0];
      *(uint4*)&As[0][sm][sk0 + 8] = *(uint4*)&q1[4];
      *(uint4*)&As[1][sm][sk0]     = *(uint4*)&q2[0];
      *(uint4*)&As[1][sm][sk0 + 8] = *(uint4*)&q2[4];
    }
#pragma unroll
    for (int j = 0; j < 2; ++j) {
      const int u = tid + 256 * j;
      const int q = u & 3, nn = (u >> 2) & 63, p = u >> 8;
      *(uint4*)&Bs[p][nn][q * 8] = bregs[j];
    }
  };

  gloadA(0); gloadB(0);
  for (int k0 = 0; k0 < KTOT; k0 += BK) {
    __syncthreads();
    swrite();
    const int kn = k0 + BK;
    if (kn < KTOT) { gloadA(kn); gloadB(kn); }
    __syncthreads();
    hfrag fb1[2], fb2[2];
#pragma unroll
    for (int f = 0; f < 2; ++f) {
      fb1[f] = *(const hfrag*)&Bs[0][wcol + f * 16 + lrow][kof];
      fb2[f] = *(const hfrag*)&Bs[1][wcol + f * 16 + lrow][kof];
    }
#pragma unroll
    for (int mi = 0; mi < 4; ++mi) {
      const hfrag a1 = *(const hfrag*)&As[0][wrow + mi * 16 + lrow][kof];
      hfrag a2;
      if (!AU8) a2 = *(const hfrag*)&As[1][wrow + mi * 16 + lrow][kof];
#pragma unroll
      for (int ni = 0; ni < 2; ++ni)
        accM[mi][ni] = __builtin_amdgcn_mfma_f32_16x16x32_f16(a1, fb1[ni], accM[mi][ni], 0, 0, 0);
#pragma unroll
      for (int ni = 0; ni < 2; ++ni) {
        accS[mi][ni] = __builtin_amdgcn_mfma_f32_16x16x32_f16(a1, fb2[ni], accS[mi][ni], 0, 0, 0);
        if (!AU8)
          accS[mi][ni] = __builtin_amdgcn_mfma_f32_16x16x32_f16(a2, fb1[ni], accS[mi][ni], 0, 0, 0);
      }
    }
  }

  // epilogue: D frag col = lane&15, row = (lane>>4)*4 + reg (m89/m91).
#pragma unroll
  for (int mi = 0; mi < 4; ++mi) {
#pragma unroll
    for (int ni = 0; ni < 2; ++ni) {
      const int rbase = row0 + wrow + mi * 16 + (lane >> 4) * 4;
      const int cc    = col0 + wcol + ni * 16 + lrow;
      float* cp = C + (size_t)rbase * GN + cc;
#pragma unroll
      for (int r = 0; r < 4; ++r) {
        float v = accM[mi][ni][r] + accS[mi][ni][r] * INV2048;
        if (EPI == 1) v += cp[(size_t)r * GN];
        cp[(size_t)r * GN] = v;
      }
    }
  }
}

// ---------------------------------------------------------------------------
// Elementwise kernels
// ---------------------------------------------------------------------------
__device__ __forceinline__ float sigf(float z) { return 1.0f / (1.0f + expf(-z)); }

__global__ __launch_bounds__(256)
void gate_kernel(const float* __restrict__ x, const float* __restrict__ L,
                 const float* __restrict__ bg, float* __restrict__ out) {
  const int i4 = blockIdx.x * 256 + threadIdx.x;
  const float4 xv = ((const float4*)x)[i4];
  const float4 lv = ((const float4*)L)[i4];
  const float4 bv = ((const float4*)bg)[i4 & 255];
  float4 r;
  r.x = xv.x * (0.5f * sigf(lv.x + bv.x) + 0.5f);
  r.y = xv.y * (0.5f * sigf(lv.y + bv.y) + 0.5f);
  r.z = xv.z * (0.5f * sigf(lv.z + bv.z) + 0.5f);
  r.w = xv.w * (0.5f * sigf(lv.w + bv.w) + 0.5f);
  ((float4*)out)[i4] = r;
}

__global__ __launch_bounds__(256)
void mod_kernel(const float* __restrict__ a, const float* __restrict__ c,
                float* __restrict__ out) {
  const int i4 = blockIdx.x * 256 + threadIdx.x;
  const float4 av = ((const float4*)a)[i4];
  const float4 cv = ((const float4*)c)[i4];
  float4 r;
  r.x = av.x * (1.0f + tanhf(cv.x));
  r.y = av.y * (1.0f + tanhf(cv.y));
  r.z = av.z * (1.0f + tanhf(cv.z));
  r.w = av.w * (1.0f + tanhf(cv.w));
  ((float4*)out)[i4] = r;
}

__global__ __launch_bounds__(256)
void rmul_kernel(const float* __restrict__ rr, const float* __restrict__ wkv,
                 float* __restrict__ out) {
  const int i4 = blockIdx.x * 256 + threadIdx.x;
  const float4 rv = ((const float4*)rr)[i4];
  const float4 wv = ((const float4*)wkv)[i4];
  float4 r;
  r.x = sigf(rv.x) * wv.x;
  r.y = sigf(rv.y) * wv.y;
  r.z = sigf(rv.z) * wv.z;
  r.w = sigf(rv.w) * wv.w;
  ((float4*)out)[i4] = r;
}

// ---------------------------------------------------------------------------
// LIF scans: bit-exact op order; 16-deep load pipeline (latency-bound fix).
// ---------------------------------------------------------------------------
__global__ __launch_bounds__(64)
void lif_u8_kernel(const float* __restrict__ x, uint8_t* __restrict__ s) {
  const int c = blockIdx.x * 64 + threadIdx.x;
  const size_t off = (size_t)(c >> 10) * TDIM * DDIM + (c & 1023);
  const float* xp = x + off;
  uint8_t* sp = s + off;
  float u = 0.f;
  float cur[16];
#pragma unroll
  for (int i = 0; i < 16; ++i) cur[i] = xp[(size_t)i * DDIM];
  for (int t = 0; t < TDIM; t += 16) {
    float nxt[16];
    if (t + 16 < TDIM) {
#pragma unroll
      for (int i = 0; i < 16; ++i) nxt[i] = xp[(size_t)(t + 16 + i) * DDIM];
    }
#pragma unroll
    for (int i = 0; i < 16; ++i) {
      u = __fadd_rn(__fmul_rn(0.9f, u), cur[i]);
      const bool fire = (u >= 1.0f);
      sp[(size_t)(t + i) * DDIM] = fire ? 1 : 0;
      if (fire) u -= 1.0f;
    }
#pragma unroll
    for (int i = 0; i < 16; ++i) cur[i] = nxt[i];
  }
}

__global__ __launch_bounds__(64)
void lif_ip_kernel(float* __restrict__ x) {
  const int c = blockIdx.x * 64 + threadIdx.x;
  const size_t off = (size_t)(c >> 10) * TDIM * DDIM + (c & 1023);
  float* xp = x + off;
  float u = 0.f;
  float cur[16];
#pragma unroll
  for (int i = 0; i < 16; ++i) cur[i] = xp[(size_t)i * DDIM];
  for (int t = 0; t < TDIM; t += 16) {
    float nxt[16];
    if (t + 16 < TDIM) {
#pragma unroll
      for (int i = 0; i < 16; ++i) nxt[i] = xp[(size_t)(t + 16 + i) * DDIM];
    }
#pragma unroll
    for (int i = 0; i < 16; ++i) {
      u = __fadd_rn(__fmul_rn(0.9f, u), cur[i]);
      const float sv = (u >= 1.0f) ? 1.0f : 0.0f;
      xp[(size_t)(t + i) * DDIM] = sv;
      u -= sv;
    }
#pragma unroll
    for (int i = 0; i < 16; ++i) cur[i] = nxt[i];
  }
}

// ---------------------------------------------------------------------------
// RWKV recurrence: fast exp (v_exp_f32) + rcp on the output divide (off the
// state chain); 8-deep load pipeline. wkv error class ~3e-7 (== proven-safe
// split noise); state contraction e^-w ~0.37 prevents compounding.
// ---------------------------------------------------------------------------
__global__ __launch_bounds__(64)
void rwkv_kernel(const float* __restrict__ k, const float* __restrict__ v,
                 const float* __restrict__ wd, const float* __restrict__ uf,
                 float* __restrict__ out) {
  const int c = blockIdx.x * 64 + threadIdx.x;
  const int d = c & 1023;
  const size_t off = (size_t)(c >> 10) * TDIM * DDIM + d;
  const float* kp = k + off;
  const float* vp = v + off;
  float* op = out + off;
  const float w = expf(wd[d]);
  const float u = uf[d];
  float aa = 0.f, bb = 0.f, pp = -1e30f;
  float kc[8], vc[8];
#pragma unroll
  for (int i = 0; i < 8; ++i) {
    kc[i] = kp[(size_t)i * DDIM];
    vc[i] = vp[(size_t)i * DDIM];
  }
  for (int t = 0; t < TDIM; t += 8) {
    float kn[8], vn[8];
    if (t + 8 < TDIM) {
#pragma unroll
      for (int i = 0; i < 8; ++i) {
        kn[i] = kp[(size_t)(t + 8 + i) * DDIM];
        vn[i] = vp[(size_t)(t + 8 + i) * DDIM];
      }
    }
#pragma unroll
    for (int i = 0; i < 8; ++i) {
      const float kt = kc[i], vt = vc[i];
      const float ww = __fadd_rn(u, kt);
      const float p  = fmaxf(pp, ww);
      float e1 = fexp(__fsub_rn(pp, p));
      float e2 = fexp(__fsub_rn(ww, p));
      const float num = __fadd_rn(__fmul_rn(e1, aa), __fmul_rn(e2, vt));
      const float den = __fadd_rn(__fmul_rn(e1, bb), e2);
      op[(size_t)(t + i) * DDIM] = num * __builtin_amdgcn_rcpf(den);
      const float ww2 = __fsub_rn(pp, w);
      const float p2  = fmaxf(ww2, kt);
      e1 = fexp(__fsub_rn(ww2, p2));
      e2 = fexp(__fsub_rn(kt, p2));
      aa = __fadd_rn(__fmul_rn(e1, aa), __fmul_rn(e2, vt));
      bb = __fadd_rn(__fmul_rn(e1, bb), e2);
      pp = p2;
    }
#pragma unroll
    for (int i = 0; i < 8; ++i) { kc[i] = kn[i]; vc[i] = vn[i]; }
  }
}

// ---------------------------------------------------------------------------
// MFMA flash attention — f16 2-plane split (3 passes), Vt key-rotation
// swizzle + K/V global prefetch (proven R12/R13).
// ---------------------------------------------------------------------------
__global__ __launch_bounds__(256)
void flash_attn(const float* __restrict__ Q, const float* __restrict__ K,
                const float* __restrict__ V, float* __restrict__ O) {
  __shared__ ushort Ks[2][32][136];    // [plane][key][kd]     17.4 KB
  __shared__ ushort Vt[2][128][40];    // [plane][d][key-slot] 20.5 KB
  __shared__ ushort Pl[4][2][16][40];  // [wave][plane][q][key] 10.2 KB
  const int tid = threadIdx.x;
  const int n    = blockIdx.x;
  const int xcd  = n & 7;
  const int idx  = n >> 3;
  const int qt   = idx & 15;
  const int grp4 = idx >> 4;
  const int p    = grp4 * 8 + xcd;
  const int b    = p >> 3, h = p & 7;
  const size_t base = ((size_t)b * TDIM) * DDIM + (size_t)h * DH;

  const int wave = tid >> 6;
  const int lane = tid & 63;
  const int lr   = lane & 15;          // frag row/col index
  const int g    = lane >> 4;          // k-group
  const int sr   = tid >> 3;           // staging: key row 0..31
  const int sc   = (tid & 7) * 16;     // staging: d base
  const int vslot = (sr + 8 * (tid & 3)) & 31;   // rotated key slot

  // ---- prologue: Q -> register frags (2 planes x 4 ksteps) ----
  hfrag q1[4], q2[4];
  {
    const float* Qrow = Q + base + (size_t)(qt * 64 + wave * 16 + lr) * DDIM;
#pragma unroll
    for (int s = 0; s < 4; ++s) {
      const float4 f0 = *(const float4*)(Qrow + s * 32 + g * 8);
      const float4 f1 = *(const float4*)(Qrow + s * 32 + g * 8 + 4);
      const float qf[8] = {f0.x, f0.y, f0.z, f0.w, f1.x, f1.y, f1.z, f1.w};
      union { hfrag v; ushort u[8]; } u1, u2;
#pragma unroll
      for (int j = 0; j < 8; ++j) split2(qf[j], u1.u[j], u2.u[j]);
      q1[s] = u1.v; q2[s] = u2.v;
    }
  }

  facc oM[8], oS[8];
#pragma unroll
  for (int i = 0; i < 8; ++i) { oM[i] = (facc)0.f; oS[i] = (facc)0.f; }
  float m[4] = {-INFINITY, -INFINITY, -INFINITY, -INFINITY};
  float l[4] = {0.f, 0.f, 0.f, 0.f};
  const float ISC = 0.08838834764831845f;   // 1/sqrt(128)

  // ---- K/V tile prefetch registers (tile 0) ----
  float kv[16], vv[16];
  auto gload = [&](int kt0) {
    const float* Kg = K + base + (size_t)(kt0 + sr) * DDIM + sc;
    const float* Vg = V + base + (size_t)(kt0 + sr) * DDIM + sc;
    *(float4*)&kv[0]  = *(const float4*)(Kg);
    *(float4*)&kv[4]  = *(const float4*)(Kg + 4);
    *(float4*)&kv[8]  = *(const float4*)(Kg + 8);
    *(float4*)&kv[12] = *(const float4*)(Kg + 12);
    *(float4*)&vv[0]  = *(const float4*)(Vg);
    *(float4*)&vv[4]  = *(const float4*)(Vg + 4);
    *(float4*)&vv[8]  = *(const float4*)(Vg + 8);
    *(float4*)&vv[12] = *(const float4*)(Vg + 12);
  };
  gload(0);

  for (int kt0 = 0; kt0 < TDIM; kt0 += 32) {
    __syncthreads();                  // prev tile's reads of Ks/Vt done
    {                                 // ---- stage from prefetched regs ----
      uint w1[8], w2[8];
#pragma unroll
      for (int i = 0; i < 8; ++i) {
        ushort a1, a2, b1, b2;
        split2(kv[2 * i], a1, a2);
        split2(kv[2 * i + 1], b1, b2);
        w1[i] = (uint)a1 | ((uint)b1 << 16);
        w2[i] = (uint)a2 | ((uint)b2 << 16);
      }
      *(uint4*)&Ks[0][sr][sc]     = *(uint4*)&w1[0];
      *(uint4*)&Ks[0][sr][sc + 8] = *(uint4*)&w1[4];
      *(uint4*)&Ks[1][sr][sc]     = *(uint4*)&w2[0];
      *(uint4*)&Ks[1][sr][sc + 8] = *(uint4*)&w2[4];
#pragma unroll
      for (int i = 0; i < 16; ++i) {
        ushort a1, a2;
        split2(vv[i], a1, a2);
        Vt[0][sc + i][vslot] = a1;
        Vt[1][sc + i][vslot] = a2;
      }
    }
    if (kt0 + 32 < TDIM) gload(kt0 + 32);   // lands under compute below
    __syncthreads();

    // ---- QK^T: S frags (2 nfrags of 16 keys), 3-pass split ----
    facc sM0 = (facc)0.f, sS0 = (facc)0.f, sM1 = (facc)0.f, sS1 = (facc)0.f;
#pragma unroll
    for (int s = 0; s < 4; ++s) {
      const int ko = s * 32 + g * 8;
      const hfrag kb10 = *(const hfrag*)&Ks[0][lr][ko];
      const hfrag kb11 = *(const hfrag*)&Ks[0][lr + 16][ko];
      const hfrag kb20 = *(const hfrag*)&Ks[1][lr][ko];
      const hfrag kb21 = *(const hfrag*)&Ks[1][lr + 16][ko];
      sM0 = __builtin_amdgcn_mfma_f32_16x16x32_f16(q1[s], kb10, sM0, 0, 0, 0);
      sS0 = __builtin_amdgcn_mfma_f32_16x16x32_f16(q1[s], kb20, sS0, 0, 0, 0);
      sS0 = __builtin_amdgcn_mfma_f32_16x16x32_f16(q2[s], kb10, sS0, 0, 0, 0);
      sM1 = __builtin_amdgcn_mfma_f32_16x16x32_f16(q1[s], kb11, sM1, 0, 0, 0);
      sS1 = __builtin_amdgcn_mfma_f32_16x16x32_f16(q1[s], kb21, sS1, 0, 0, 0);
      sS1 = __builtin_amdgcn_mfma_f32_16x16x32_f16(q2[s], kb11, sS1, 0, 0, 0);
    }

    // ---- online softmax (rows q=g*4+r; 16-lane reduce over keys) ----
#pragma unroll
    for (int r = 0; r < 4; ++r) {
      const float sc0 = (sM0[r] + sS0[r] * INV2048) * ISC;   // key = lr
      const float sc1 = (sM1[r] + sS1[r] * INV2048) * ISC;   // key = lr+16
      float mx = fmaxf(sc0, sc1);
      mx = fmaxf(mx, __shfl_xor(mx, 1, 16));
      mx = fmaxf(mx, __shfl_xor(mx, 2, 16));
      mx = fmaxf(mx, __shfl_xor(mx, 4, 16));
      mx = fmaxf(mx, __shfl_xor(mx, 8, 16));
      const float mn = fmaxf(m[r], mx);
      const float rf = expf(m[r] - mn);
      const float p0 = expf(sc0 - mn), p1 = expf(sc1 - mn);
      float ps = p0 + p1;
      ps += __shfl_xor(ps, 1, 16);
      ps += __shfl_xor(ps, 2, 16);
      ps += __shfl_xor(ps, 4, 16);
      ps += __shfl_xor(ps, 8, 16);
      l[r] = l[r] * rf + ps;
      m[r] = mn;
#pragma unroll
      for (int nf = 0; nf < 8; ++nf) { oM[nf][r] *= rf; oS[nf][r] *= rf; }
      ushort a1, a2;
      split2(p0, a1, a2);
      Pl[wave][0][g * 4 + r][lr] = a1;
      Pl[wave][1][g * 4 + r][lr] = a2;
      split2(p1, a1, a2);
      Pl[wave][0][g * 4 + r][lr + 16] = a1;
      Pl[wave][1][g * 4 + r][lr + 16] = a2;
    }

    // ---- PV: O += P @ V (wave-private P; Vt reads at rotated slot) ----
    const hfrag pa1 = *(const hfrag*)&Pl[wave][0][lr][g * 8];
    const hfrag pa2 = *(const hfrag*)&Pl[wave][1][lr][g * 8];
#pragma unroll
    for (int nf = 0; nf < 8; ++nf) {
      const int vs = 8 * ((g + nf) & 3);             // rotated key-slot base
      const hfrag vb1 = *(const hfrag*)&Vt[0][nf * 16 + lr][vs];
      const hfrag vb2 = *(const hfrag*)&Vt[1][nf * 16 + lr][vs];
      oM[nf] = __builtin_amdgcn_mfma_f32_16x16x32_f16(pa1, vb1, oM[nf], 0, 0, 0);
      oS[nf] = __builtin_amdgcn_mfma_f32_16x16x32_f16(pa1, vb2, oS[nf], 0, 0, 0);
      oS[nf] = __builtin_amdgcn_mfma_f32_16x16x32_f16(pa2, vb1, oS[nf], 0, 0, 0);
    }
  }

  // ---- epilogue: O/l -> global (rows q=g*4+r, cols d=lr+16*nf) ----
  float* Og = O + base + (size_t)(qt * 64 + wave * 16) * DDIM;
#pragma unroll
  for (int r = 0; r < 4; ++r) {
    const float invl = 1.0f / l[r];
    float* orow = Og + (size_t)(g * 4 + r) * DDIM;
#pragma unroll
    for (int nf = 0; nf < 8; ++nf)
      orow[nf * 16 + lr] = (oM[nf][r] + oS[nf][r] * INV2048) * invl;
  }
}

// ---------------------------------------------------------------------------
// Final: y = lif2(f32) + spikes2(u8); LayerNorm; float32 store.
// ---------------------------------------------------------------------------
__global__ __launch_bounds__(256)
void ln_kernel(const float* __restrict__ a, const uint8_t* __restrict__ s8,
               const float* __restrict__ gamma, const float* __restrict__ beta,
               float* __restrict__ out) {
  const int row = blockIdx.x;
  const int tid = threadIdx.x;
  const size_t base = (size_t)row * DDIM;
  const float4 av = *(const float4*)(a + base + tid * 4);
  const uchar4 sv = *(const uchar4*)(s8 + base + tid * 4);
  const float y0 = av.x + (float)sv.x, y1 = av.y + (float)sv.y;
  const float y2 = av.z + (float)sv.z, y3 = av.w + (float)sv.w;
  float s = (y0 + y1) + (y2 + y3);
  float q = (y0 * y0 + y1 * y1) + (y2 * y2 + y3 * y3);
#pragma unroll
  for (int off = 1; off < 64; off <<= 1) {
    s += __shfl_xor(s, off);
    q += __shfl_xor(q, off);
  }
  __shared__ float red[8];
  const int wid = tid >> 6;
  if ((tid & 63) == 0) { red[wid * 2] = s; red[wid * 2 + 1] = q; }
  __syncthreads();
  const float ts = (red[0] + red[2]) + (red[4] + red[6]);
  const float tq = (red[1] + red[3]) + (red[5] + red[7]);
  const float mu  = ts * (1.0f / 1024.0f);
  const float var = tq * (1.0f / 1024.0f) - mu * mu;
  const float rs  = 1.0f / sqrtf(var + 1e-5f);
  const int d = tid * 4;
  const float4 gv  = *(const float4*)(gamma + d);
  const float4 btv = *(const float4*)(beta + d);
  float4 r;
  r.x = (y0 - mu) * rs * gv.x + btv.x;
  r.y = (y1 - mu) * rs * gv.y + btv.y;
  r.z = (y2 - mu) * rs * gv.z + btv.z;
  r.w = (y3 - mu) * rs * gv.w + btv.w;
  *(float4*)(out + base + d) = r;
}

// ---------------------------------------------------------------------------
// Workspace: 3 f32 (A,C,D) 50.3 MB + u8 spikes 4.2 MB + B planes 12 MB.
// ---------------------------------------------------------------------------
extern "C" void kernel_launch(void* const* d_in, const int* in_sizes, int n_in,
                              void* d_out, int out_size, void* d_ws, size_t ws_size,
                              hipStream_t stream) {
  const float* x       = (const float*)d_in[0];
  const float* context = (const float*)d_in[1];
  const float* Wg  = (const float*)d_in[2];
  const float* bg  = (const float*)d_in[3];
  const float* Wc  = (const float*)d_in[4];
  const float* Wq  = (const float*)d_in[5];
  const float* Wk  = (const float*)d_in[6];
  const float* Wv  = (const float*)d_in[7];
  const float* Wo  = (const float*)d_in[8];
  const float* Wm  = (const float*)d_in[9];
  const float* rWk = (const float*)d_in[10];
  const float* rWv = (const float*)d_in[11];
  const float* rWr = (const float*)d_in[12];
  const float* rWo = (const float*)d_in[13];
  const float* wd  = (const float*)d_in[14];
  const float* uf  = (const float*)d_in[15];
  const float* gamma = (const float*)d_in[16];
  const float* beta  = (const float*)d_in[17];
  float* out = (float*)d_out;   // reference output dtype = float32

  float* w  = (float*)d_ws;
  float*   bA = w;
  float*   bC = w + 1 * NELEM;
  float*   bD = w + 2 * NELEM;
  uint8_t* bS = (uint8_t*)(w + 3 * NELEM);                          // u8 spikes
  ushort*  pB = (ushort*)((uint8_t*)d_ws + 3 * NELEM * 4 + NELEM);  // B planes

  const dim3 ew(4096);
  constexpr int M1 = 1024 * 1024;   // ushorts per 1024-K plane

  // Stage 1: thalamic gate — single K=2048 GEMM over [x | context]
  cvt_h2t<<<dim3(16, 16, 2), 256, 0, stream>>>(Wg, Wc, nullptr, pB, 0, 1024, 2048);
  gemm_k<0, 0, 1, 2048><<<512, 256, 0, stream>>>(x, context, pB, bA, nullptr, nullptr);
  gate_kernel<<<ew, 256, 0, stream>>>(x, bA, bg, bA);
  // Stage 2: LIF -> spikes2 (u8)
  lif_u8_kernel<<<64, 64, 0, stream>>>(bA, bS);
  // Stage 3: spike self-attention — Q,K,V in ONE N-merged launch
  cvt_h2t<<<dim3(16, 16, 3), 256, 0, stream>>>(Wq, Wk, Wv, pB, 2 * M1, 0, 1024);
  gemm_k<0, 1, 3, 1024><<<1536, 256, 0, stream>>>(bS, nullptr, pB, bA, bC, bD);
  flash_attn<<<512, 256, 0, stream>>>(bA, bC, bD, bA);
  cvt_h2t<<<dim3(16, 16, 1), 256, 0, stream>>>(Wo, nullptr, nullptr, pB, 0, 0, 1024);
  gemm_k<0, 0, 1, 1024><<<512, 256, 0, stream>>>(bA, nullptr, pB, bC, nullptr, nullptr);
  // Stage 4: apical modulation
  cvt_h2t<<<dim3(16, 16, 1), 256, 0, stream>>>(Wm, nullptr, nullptr, pB, 0, 0, 1024);
  gemm_k<0, 0, 1, 1024><<<512, 256, 0, stream>>>(context, nullptr, pB, bA, nullptr, nullptr);
  mod_kernel<<<ew, 256, 0, stream>>>(bC, bA, bD);          // bD = modulated
  // Stage 5: RWKV — k,v N-merged
  cvt_h2t<<<dim3(16, 16, 2), 256, 0, stream>>>(rWk, rWv, nullptr, pB, 2 * M1, 0, 1024);
  gemm_k<0, 0, 2, 1024><<<1024, 256, 0, stream>>>(bD, nullptr, pB, bA, bC, nullptr);
  rwkv_kernel<<<64, 64, 0, stream>>>(bA, bC, wd, uf, bA);  // bA = wkv
  cvt_h2t<<<dim3(16, 16, 1), 256, 0, stream>>>(rWr, nullptr, nullptr, pB, 0, 0, 1024);
  gemm_k<0, 0, 1, 1024><<<512, 256, 0, stream>>>(bD, nullptr, pB, bC, nullptr, nullptr);
  rmul_kernel<<<ew, 256, 0, stream>>>(bC, bA, bA);         // bA = sig(r)*wkv
  cvt_h2t<<<dim3(16, 16, 1), 256, 0, stream>>>(rWo, nullptr, nullptr, pB, 0, 0, 1024);
  gemm_k<0, 0, 1, 1024><<<512, 256, 0, stream>>>(bA, nullptr, pB, bC, nullptr, nullptr);
  // Stage 6: output LIF (in-place) + residual + LayerNorm
  lif_ip_kernel<<<64, 64, 0, stream>>>(bC);
  ln_kernel<<<4096, 256, 0, stream>>>(bC, bS, gamma, beta, out);
}

// Round 15
// 972.101 us; speedup vs baseline: 3.4813x; 1.0587x over previous
//
#include <hip/hip_runtime.h>
#include <hip/hip_bf16.h>
#include <math.h>

// Problem dims (fixed)
#define BDIM 4
#define TDIM 1024
#define DDIM 1024
#define DH   128
#define NELEM ((size_t)BDIM * TDIM * DDIM)   // 4,194,304

typedef __attribute__((ext_vector_type(8))) _Float16 hfrag;  // 8 f16 (4 VGPR)
typedef __attribute__((ext_vector_type(4))) float facc;      // 4 f32 acc

// f16 2-plane split: x = h1 + h2/2048 (22 mantissa bits). Passes a1b1,
// a1b2, a2b1 kept; a2b2 (~2^-22 rel) dropped. Proven R13/R14 (absmax 0.0).
__device__ __forceinline__ void split2(float x, ushort& h1, ushort& h2) {
  const _Float16 a = (_Float16)x;
  const _Float16 b = (_Float16)((x - (float)a) * 2048.0f);
  union { _Float16 h; ushort u; } ua, ub;
  ua.h = a; ub.h = b;
  h1 = ua.u; h2 = ub.u;
}
#define INV2048 4.8828125e-4f    // 1/2048, exact

// Fast exp: v_exp_f32(x*log2e). ~2 ulp; exact at 0. Error class ~3e-7 ==
// proven-safe split noise (R13/R14 absmax 0.0).
__device__ __forceinline__ float fexp(float x) {
  return __builtin_amdgcn_exp2f(x * 1.4426950408889634f);
}

constexpr int GM = 4096, GN = 1024, GK = 1024;
constexpr int BM = 128, BK = 32;
constexpr int BKP = 40;                    // padded LDS k-dim (80 B rows)

// ---------------------------------------------------------------------------
// cvt_h2t: up to 3 weight matrices [1024][1024] f32 -> 2-plane f16 split,
// blocked-transposed [kTot/32][N=1024][32].
// ---------------------------------------------------------------------------
__global__ __launch_bounds__(256)
void cvt_h2t(const float* __restrict__ W0, const float* __restrict__ W1,
             const float* __restrict__ W2, ushort* __restrict__ P,
             int zstride, int zkoff, int kTot) {
  __shared__ float Ls[64][68];
  const int z = blockIdx.z;
  const float* W = (z == 0) ? W0 : (z == 1 ? W1 : W2);
  ushort* Pz = P + (size_t)z * zstride;
  const size_t PS = (size_t)kTot * GN;     // ushorts per plane
  const int t = threadIdx.x;
  const int k0 = blockIdx.x * 64, n0 = blockIdx.y * 64;
  const int r = t >> 4, c4 = (t & 15) << 2;
#pragma unroll
  for (int i = 0; i < 4; ++i)
    *(float4*)&Ls[r + i * 16][c4] =
        *(const float4*)(W + (size_t)(k0 + r + i * 16) * GN + n0 + c4);
  __syncthreads();
  const int n = t >> 2, kc = (t & 3) << 4;
  uint p1[8], p2[8];
#pragma unroll
  for (int jj = 0; jj < 8; ++jj) {
    const float x0 = Ls[kc + 2 * jj][n], x1 = Ls[kc + 2 * jj + 1][n];
    ushort a1, a2, b1, b2;
    split2(x0, a1, a2);
    split2(x1, b1, b2);
    p1[jj] = (uint)a1 | ((uint)b1 << 16);
    p2[jj] = (uint)a2 | ((uint)b2 << 16);
  }
  const int kk = k0 + kc + z * zkoff;
  ushort* d = Pz + (size_t)(kk >> 5) * (GN * 32) + (size_t)(n0 + n) * 32 + (kk & 31);
  *(uint4*)(d)          = *(uint4*)&p1[0];
  *(uint4*)(d + 8)      = *(uint4*)&p1[4];
  *(uint4*)(d + PS)     = *(uint4*)&p2[0];
  *(uint4*)(d + PS + 8) = *(uint4*)&p2[4];
}

// ---------------------------------------------------------------------------
// GEMM via 2-plane f16 MFMA (3 passes; AU8 spikes exact -> 2 passes).
// Tile 128x64, 4 waves, LDS 31 KB -> 3 blocks/CU.
// Per-matrix A pointers (A0/A1/A2 selected by mat = bx>>4) enable N-merged
// launches with DIFFERENT A (Wo+Wm) as well as shared-A (QKV, kvr).
// KTOT=2048: K-merged A (A0 for k<1024, Ak2 after) — gate stage.
// ---------------------------------------------------------------------------
template<int EPI, int AU8, int KTOT>
__global__ __launch_bounds__(256)
void gemm_k(const void* __restrict__ A0, const void* __restrict__ A1,
            const void* __restrict__ A2, const void* __restrict__ Ak2,
            const ushort* __restrict__ pB,
            float* __restrict__ C0, float* __restrict__ C1,
            float* __restrict__ C2) {
  constexpr size_t PS = (size_t)KTOT * GN;   // ushorts per plane
  __shared__ ushort As[2][BM][BKP];
  __shared__ ushort Bs[2][64][BKP];
  const int tid = threadIdx.x;
  const int n   = blockIdx.x;
  const int xcd = n & 7;
  const int idx = n >> 3;
  const int by  = xcd * 4 + (idx & 3);
  const int bx  = idx >> 2;
  const int mat = bx >> 4;
  const int row0 = by * BM;
  const int col0 = (bx & 15) * 64;
  const ushort* pBm = pB + (size_t)mat * 2 * PS;
  float* C = (mat == 0) ? C0 : (mat == 1 ? C1 : C2);
  const void* Abase = (mat == 0) ? A0 : (mat == 1 ? A1 : A2);

  const int sm  = tid & 127;
  const int sk0 = (tid >> 7) << 4;

  const int wave = tid >> 6;
  const int lane = tid & 63;
  const int wrow = (wave >> 1) * 64;
  const int wcol = (wave & 1) * 32;
  const int lrow = lane & 15;
  const int kof  = (lane >> 4) * 8;

  facc accM[4][2], accS[4][2];
#pragma unroll
  for (int i = 0; i < 4; ++i)
#pragma unroll
    for (int j = 0; j < 2; ++j) { accM[i][j] = (facc)0.f; accS[i][j] = (facc)0.f; }

  float av[16];
  uint4 a8raw;
  uint4 bregs[2];

  auto gloadA = [&](int K0) {
    const void* src = Abase; int k = K0;
    if (KTOT > 1024 && K0 >= 1024) { src = Ak2; k = K0 - 1024; }
    if (AU8) {
      a8raw = *(const uint4*)((const uint8_t*)src + (size_t)(row0 + sm) * 1024 + k + sk0);
    } else {
      const float* Ap = (const float*)src + (size_t)(row0 + sm) * 1024 + k + sk0;
      *(float4*)&av[0]  = *(const float4*)(Ap);
      *(float4*)&av[4]  = *(const float4*)(Ap + 4);
      *(float4*)&av[8]  = *(const float4*)(Ap + 8);
      *(float4*)&av[12] = *(const float4*)(Ap + 12);
    }
  };
  auto gloadB = [&](int K0) {
    const int kb = K0 >> 5;
#pragma unroll
    for (int j = 0; j < 2; ++j) {
      const int u = tid + 256 * j;
      const int q = u & 3, nn = (u >> 2) & 63, p = u >> 8;
      bregs[j] = *(const uint4*)(pBm + (size_t)p * PS + (size_t)kb * (GN * 32)
                                 + (size_t)(col0 + nn) * 32 + q * 8);
    }
  };
  auto swrite = [&]() {
    if (AU8) {
      const uint w4[4] = {a8raw.x, a8raw.y, a8raw.z, a8raw.w};
      uint pk[8];
#pragma unroll
      for (int i = 0; i < 8; ++i) {
        const uint b0 = (w4[i >> 1] >> ((i & 1) * 16)) & 0xFFu;
        const uint b1 = (w4[i >> 1] >> ((i & 1) * 16 + 8)) & 0xFFu;
        pk[i] = (b0 * 0x3C00u) | ((b1 * 0x3C00u) << 16);   // f16 1.0 = 0x3C00
      }
      *(uint4*)&As[0][sm][sk0]     = *(uint4*)&pk[0];
      *(uint4*)&As[0][sm][sk0 + 8] = *(uint4*)&pk[4];
    } else {
      uint q1[8], q2[8];
#pragma unroll
      for (int i = 0; i < 8; ++i) {
        ushort a1, a2, b1, b2;
        split2(av[2 * i], a1, a2);
        split2(av[2 * i + 1], b1, b2);
        q1[i] = (uint)a1 | ((uint)b1 << 16);
        q2[i] = (uint)a2 | ((uint)b2 << 16);
      }
      *(uint4*)&As[0][sm][sk0]     = *(uint4*)&q1[0];
      *(uint4*)&As[0][sm][sk0 + 8] = *(uint4*)&q1[4];
      *(uint4*)&As[1][sm][sk0]     = *(uint4*)&q2[0];
      *(uint4*)&As[1][sm][sk0 + 8] = *(uint4*)&q2[4];
    }
#pragma unroll
    for (int j = 0; j < 2; ++j) {
      const int u = tid + 256 * j;
      const int q = u & 3, nn = (u >> 2) & 63, p = u >> 8;
      *(uint4*)&Bs[p][nn][q * 8] = bregs[j];
    }
  };

  gloadA(0); gloadB(0);
  for (int k0 = 0; k0 < KTOT; k0 += BK) {
    __syncthreads();
    swrite();
    const int kn = k0 + BK;
    if (kn < KTOT) { gloadA(kn); gloadB(kn); }
    __syncthreads();
    hfrag fb1[2], fb2[2];
#pragma unroll
    for (int f = 0; f < 2; ++f) {
      fb1[f] = *(const hfrag*)&Bs[0][wcol + f * 16 + lrow][kof];
      fb2[f] = *(const hfrag*)&Bs[1][wcol + f * 16 + lrow][kof];
    }
#pragma unroll
    for (int mi = 0; mi < 4; ++mi) {
      const hfrag a1 = *(const hfrag*)&As[0][wrow + mi * 16 + lrow][kof];
      hfrag a2;
      if (!AU8) a2 = *(const hfrag*)&As[1][wrow + mi * 16 + lrow][kof];
#pragma unroll
      for (int ni = 0; ni < 2; ++ni)
        accM[mi][ni] = __builtin_amdgcn_mfma_f32_16x16x32_f16(a1, fb1[ni], accM[mi][ni], 0, 0, 0);
#pragma unroll
      for (int ni = 0; ni < 2; ++ni) {
        accS[mi][ni] = __builtin_amdgcn_mfma_f32_16x16x32_f16(a1, fb2[ni], accS[mi][ni], 0, 0, 0);
        if (!AU8)
          accS[mi][ni] = __builtin_amdgcn_mfma_f32_16x16x32_f16(a2, fb1[ni], accS[mi][ni], 0, 0, 0);
      }
    }
  }

  // epilogue: D frag col = lane&15, row = (lane>>4)*4 + reg (m89/m91).
#pragma unroll
  for (int mi = 0; mi < 4; ++mi) {
#pragma unroll
    for (int ni = 0; ni < 2; ++ni) {
      const int rbase = row0 + wrow + mi * 16 + (lane >> 4) * 4;
      const int cc    = col0 + wcol + ni * 16 + lrow;
      float* cp = C + (size_t)rbase * GN + cc;
#pragma unroll
      for (int r = 0; r < 4; ++r) {
        float v = accM[mi][ni][r] + accS[mi][ni][r] * INV2048;
        if (EPI == 1) v += cp[(size_t)r * GN];
        cp[(size_t)r * GN] = v;
      }
    }
  }
}

// ---------------------------------------------------------------------------
// Elementwise kernels
// ---------------------------------------------------------------------------
__device__ __forceinline__ float sigf(float z) { return 1.0f / (1.0f + expf(-z)); }

__global__ __launch_bounds__(256)
void gate_kernel(const float* __restrict__ x, const float* __restrict__ L,
                 const float* __restrict__ bg, float* __restrict__ out) {
  const int i4 = blockIdx.x * 256 + threadIdx.x;
  const float4 xv = ((const float4*)x)[i4];
  const float4 lv = ((const float4*)L)[i4];
  const float4 bv = ((const float4*)bg)[i4 & 255];
  float4 r;
  r.x = xv.x * (0.5f * sigf(lv.x + bv.x) + 0.5f);
  r.y = xv.y * (0.5f * sigf(lv.y + bv.y) + 0.5f);
  r.z = xv.z * (0.5f * sigf(lv.z + bv.z) + 0.5f);
  r.w = xv.w * (0.5f * sigf(lv.w + bv.w) + 0.5f);
  ((float4*)out)[i4] = r;
}

__global__ __launch_bounds__(256)
void mod_kernel(const float* __restrict__ a, const float* __restrict__ c,
                float* __restrict__ out) {
  const int i4 = blockIdx.x * 256 + threadIdx.x;
  const float4 av = ((const float4*)a)[i4];
  const float4 cv = ((const float4*)c)[i4];
  float4 r;
  r.x = av.x * (1.0f + tanhf(cv.x));
  r.y = av.y * (1.0f + tanhf(cv.y));
  r.z = av.z * (1.0f + tanhf(cv.z));
  r.w = av.w * (1.0f + tanhf(cv.w));
  ((float4*)out)[i4] = r;
}

__global__ __launch_bounds__(256)
void rmul_kernel(const float* __restrict__ rr, const float* __restrict__ wkv,
                 float* __restrict__ out) {
  const int i4 = blockIdx.x * 256 + threadIdx.x;
  const float4 rv = ((const float4*)rr)[i4];
  const float4 wv = ((const float4*)wkv)[i4];
  float4 r;
  r.x = sigf(rv.x) * wv.x;
  r.y = sigf(rv.y) * wv.y;
  r.z = sigf(rv.z) * wv.z;
  r.w = sigf(rv.w) * wv.w;
  ((float4*)out)[i4] = r;
}

// ---------------------------------------------------------------------------
// LIF scans: bit-exact op order; 32-deep load pipeline.
// ---------------------------------------------------------------------------
__global__ __launch_bounds__(64)
void lif_u8_kernel(const float* __restrict__ x, uint8_t* __restrict__ s) {
  const int c = blockIdx.x * 64 + threadIdx.x;
  const size_t off = (size_t)(c >> 10) * TDIM * DDIM + (c & 1023);
  const float* xp = x + off;
  uint8_t* sp = s + off;
  float u = 0.f;
  float cur[32];
#pragma unroll
  for (int i = 0; i < 32; ++i) cur[i] = xp[(size_t)i * DDIM];
  for (int t = 0; t < TDIM; t += 32) {
    float nxt[32];
    if (t + 32 < TDIM) {
#pragma unroll
      for (int i = 0; i < 32; ++i) nxt[i] = xp[(size_t)(t + 32 + i) * DDIM];
    }
#pragma unroll
    for (int i = 0; i < 32; ++i) {
      u = __fadd_rn(__fmul_rn(0.9f, u), cur[i]);
      const bool fire = (u >= 1.0f);
      sp[(size_t)(t + i) * DDIM] = fire ? 1 : 0;
      if (fire) u -= 1.0f;
    }
#pragma unroll
    for (int i = 0; i < 32; ++i) cur[i] = nxt[i];
  }
}

__global__ __launch_bounds__(64)
void lif_ip_kernel(float* __restrict__ x) {
  const int c = blockIdx.x * 64 + threadIdx.x;
  const size_t off = (size_t)(c >> 10) * TDIM * DDIM + (c & 1023);
  float* xp = x + off;
  float u = 0.f;
  float cur[32];
#pragma unroll
  for (int i = 0; i < 32; ++i) cur[i] = xp[(size_t)i * DDIM];
  for (int t = 0; t < TDIM; t += 32) {
    float nxt[32];
    if (t + 32 < TDIM) {
#pragma unroll
      for (int i = 0; i < 32; ++i) nxt[i] = xp[(size_t)(t + 32 + i) * DDIM];
    }
#pragma unroll
    for (int i = 0; i < 32; ++i) {
      u = __fadd_rn(__fmul_rn(0.9f, u), cur[i]);
      const float sv = (u >= 1.0f) ? 1.0f : 0.0f;
      xp[(size_t)(t + i) * DDIM] = sv;
      u -= sv;
    }
#pragma unroll
    for (int i = 0; i < 32; ++i) cur[i] = nxt[i];
  }
}

// ---------------------------------------------------------------------------
// RWKV recurrence: fast exp + rcp (proven R14); 16-deep load pipeline.
// ---------------------------------------------------------------------------
__global__ __launch_bounds__(64)
void rwkv_kernel(const float* __restrict__ k, const float* __restrict__ v,
                 const float* __restrict__ wd, const float* __restrict__ uf,
                 float* __restrict__ out) {
  const int c = blockIdx.x * 64 + threadIdx.x;
  const int d = c & 1023;
  const size_t off = (size_t)(c >> 10) * TDIM * DDIM + d;
  const float* kp = k + off;
  const float* vp = v + off;
  float* op = out + off;
  const float w = expf(wd[d]);
  const float u = uf[d];
  float aa = 0.f, bb = 0.f, pp = -1e30f;
  float kc[16], vc[16];
#pragma unroll
  for (int i = 0; i < 16; ++i) {
    kc[i] = kp[(size_t)i * DDIM];
    vc[i] = vp[(size_t)i * DDIM];
  }
  for (int t = 0; t < TDIM; t += 16) {
    float kn[16], vn[16];
    if (t + 16 < TDIM) {
#pragma unroll
      for (int i = 0; i < 16; ++i) {
        kn[i] = kp[(size_t)(t + 16 + i) * DDIM];
        vn[i] = vp[(size_t)(t + 16 + i) * DDIM];
      }
    }
#pragma unroll
    for (int i = 0; i < 16; ++i) {
      const float kt = kc[i], vt = vc[i];
      const float ww = __fadd_rn(u, kt);
      const float p  = fmaxf(pp, ww);
      float e1 = fexp(__fsub_rn(pp, p));
      float e2 = fexp(__fsub_rn(ww, p));
      const float num = __fadd_rn(__fmul_rn(e1, aa), __fmul_rn(e2, vt));
      const float den = __fadd_rn(__fmul_rn(e1, bb), e2);
      op[(size_t)(t + i) * DDIM] = num * __builtin_amdgcn_rcpf(den);
      const float ww2 = __fsub_rn(pp, w);
      const float p2  = fmaxf(ww2, kt);
      e1 = fexp(__fsub_rn(ww2, p2));
      e2 = fexp(__fsub_rn(kt, p2));
      aa = __fadd_rn(__fmul_rn(e1, aa), __fmul_rn(e2, vt));
      bb = __fadd_rn(__fmul_rn(e1, bb), e2);
      pp = p2;
    }
#pragma unroll
    for (int i = 0; i < 16; ++i) { kc[i] = kn[i]; vc[i] = vn[i]; }
  }
}

// ---------------------------------------------------------------------------
// MFMA flash attention — f16 2-plane split (3 passes), Vt key-rotation
// swizzle + K/V global prefetch (proven R12-R14). This round: softmax
// expf -> v_exp_f32 (same proven noise class).
// ---------------------------------------------------------------------------
__global__ __launch_bounds__(256)
void flash_attn(const float* __restrict__ Q, const float* __restrict__ K,
                const float* __restrict__ V, float* __restrict__ O) {
  __shared__ ushort Ks[2][32][136];    // [plane][key][kd]     17.4 KB
  __shared__ ushort Vt[2][128][40];    // [plane][d][key-slot] 20.5 KB
  __shared__ ushort Pl[4][2][16][40];  // [wave][plane][q][key] 10.2 KB
  const int tid = threadIdx.x;
  const int n    = blockIdx.x;
  const int xcd  = n & 7;
  const int idx  = n >> 3;
  const int qt   = idx & 15;
  const int grp4 = idx >> 4;
  const int p    = grp4 * 8 + xcd;
  const int b    = p >> 3, h = p & 7;
  const size_t base = ((size_t)b * TDIM) * DDIM + (size_t)h * DH;

  const int wave = tid >> 6;
  const int lane = tid & 63;
  const int lr   = lane & 15;
  const int g    = lane >> 4;
  const int sr   = tid >> 3;
  const int sc   = (tid & 7) * 16;
  const int vslot = (sr + 8 * (tid & 3)) & 31;   // rotated key slot

  // ---- prologue: Q -> register frags (2 planes x 4 ksteps) ----
  hfrag q1[4], q2[4];
  {
    const float* Qrow = Q + base + (size_t)(qt * 64 + wave * 16 + lr) * DDIM;
#pragma unroll
    for (int s = 0; s < 4; ++s) {
      const float4 f0 = *(const float4*)(Qrow + s * 32 + g * 8);
      const float4 f1 = *(const float4*)(Qrow + s * 32 + g * 8 + 4);
      const float qf[8] = {f0.x, f0.y, f0.z, f0.w, f1.x, f1.y, f1.z, f1.w};
      union { hfrag v; ushort u[8]; } u1, u2;
#pragma unroll
      for (int j = 0; j < 8; ++j) split2(qf[j], u1.u[j], u2.u[j]);
      q1[s] = u1.v; q2[s] = u2.v;
    }
  }

  facc oM[8], oS[8];
#pragma unroll
  for (int i = 0; i < 8; ++i) { oM[i] = (facc)0.f; oS[i] = (facc)0.f; }
  float m[4] = {-INFINITY, -INFINITY, -INFINITY, -INFINITY};
  float l[4] = {0.f, 0.f, 0.f, 0.f};
  const float ISC = 0.08838834764831845f;   // 1/sqrt(128)

  float kv[16], vv[16];
  auto gload = [&](int kt0) {
    const float* Kg = K + base + (size_t)(kt0 + sr) * DDIM + sc;
    const float* Vg = V + base + (size_t)(kt0 + sr) * DDIM + sc;
    *(float4*)&kv[0]  = *(const float4*)(Kg);
    *(float4*)&kv[4]  = *(const float4*)(Kg + 4);
    *(float4*)&kv[8]  = *(const float4*)(Kg + 8);
    *(float4*)&kv[12] = *(const float4*)(Kg + 12);
    *(float4*)&vv[0]  = *(const float4*)(Vg);
    *(float4*)&vv[4]  = *(const float4*)(Vg + 4);
    *(float4*)&vv[8]  = *(const float4*)(Vg + 8);
    *(float4*)&vv[12] = *(const float4*)(Vg + 12);
  };
  gload(0);

  for (int kt0 = 0; kt0 < TDIM; kt0 += 32) {
    __syncthreads();
    {
      uint w1[8], w2[8];
#pragma unroll
      for (int i = 0; i < 8; ++i) {
        ushort a1, a2, b1, b2;
        split2(kv[2 * i], a1, a2);
        split2(kv[2 * i + 1], b1, b2);
        w1[i] = (uint)a1 | ((uint)b1 << 16);
        w2[i] = (uint)a2 | ((uint)b2 << 16);
      }
      *(uint4*)&Ks[0][sr][sc]     = *(uint4*)&w1[0];
      *(uint4*)&Ks[0][sr][sc + 8] = *(uint4*)&w1[4];
      *(uint4*)&Ks[1][sr][sc]     = *(uint4*)&w2[0];
      *(uint4*)&Ks[1][sr][sc + 8] = *(uint4*)&w2[4];
#pragma unroll
      for (int i = 0; i < 16; ++i) {
        ushort a1, a2;
        split2(vv[i], a1, a2);
        Vt[0][sc + i][vslot] = a1;
        Vt[1][sc + i][vslot] = a2;
      }
    }
    if (kt0 + 32 < TDIM) gload(kt0 + 32);
    __syncthreads();

    // ---- QK^T: 3-pass split ----
    facc sM0 = (facc)0.f, sS0 = (facc)0.f, sM1 = (facc)0.f, sS1 = (facc)0.f;
#pragma unroll
    for (int s = 0; s < 4; ++s) {
      const int ko = s * 32 + g * 8;
      const hfrag kb10 = *(const hfrag*)&Ks[0][lr][ko];
      const hfrag kb11 = *(const hfrag*)&Ks[0][lr + 16][ko];
      const hfrag kb20 = *(const hfrag*)&Ks[1][lr][ko];
      const hfrag kb21 = *(const hfrag*)&Ks[1][lr + 16][ko];
      sM0 = __builtin_amdgcn_mfma_f32_16x16x32_f16(q1[s], kb10, sM0, 0, 0, 0);
      sS0 = __builtin_amdgcn_mfma_f32_16x16x32_f16(q1[s], kb20, sS0, 0, 0, 0);
      sS0 = __builtin_amdgcn_mfma_f32_16x16x32_f16(q2[s], kb10, sS0, 0, 0, 0);
      sM1 = __builtin_amdgcn_mfma_f32_16x16x32_f16(q1[s], kb11, sM1, 0, 0, 0);
      sS1 = __builtin_amdgcn_mfma_f32_16x16x32_f16(q1[s], kb21, sS1, 0, 0, 0);
      sS1 = __builtin_amdgcn_mfma_f32_16x16x32_f16(q2[s], kb11, sS1, 0, 0, 0);
    }

    // ---- online softmax (fast exp — proven noise class) ----
#pragma unroll
    for (int r = 0; r < 4; ++r) {
      const float sc0 = (sM0[r] + sS0[r] * INV2048) * ISC;
      const float sc1 = (sM1[r] + sS1[r] * INV2048) * ISC;
      float mx = fmaxf(sc0, sc1);
      mx = fmaxf(mx, __shfl_xor(mx, 1, 16));
      mx = fmaxf(mx, __shfl_xor(mx, 2, 16));
      mx = fmaxf(mx, __shfl_xor(mx, 4, 16));
      mx = fmaxf(mx, __shfl_xor(mx, 8, 16));
      const float mn = fmaxf(m[r], mx);
      const float rf = fexp(m[r] - mn);       // exp2(-inf)=0 on first tile
      const float p0 = fexp(sc0 - mn), p1 = fexp(sc1 - mn);
      float ps = p0 + p1;
      ps += __shfl_xor(ps, 1, 16);
      ps += __shfl_xor(ps, 2, 16);
      ps += __shfl_xor(ps, 4, 16);
      ps += __shfl_xor(ps, 8, 16);
      l[r] = l[r] * rf + ps;
      m[r] = mn;
#pragma unroll
      for (int nf = 0; nf < 8; ++nf) { oM[nf][r] *= rf; oS[nf][r] *= rf; }
      ushort a1, a2;
      split2(p0, a1, a2);
      Pl[wave][0][g * 4 + r][lr] = a1;
      Pl[wave][1][g * 4 + r][lr] = a2;
      split2(p1, a1, a2);
      Pl[wave][0][g * 4 + r][lr + 16] = a1;
      Pl[wave][1][g * 4 + r][lr + 16] = a2;
    }

    // ---- PV ----
    const hfrag pa1 = *(const hfrag*)&Pl[wave][0][lr][g * 8];
    const hfrag pa2 = *(const hfrag*)&Pl[wave][1][lr][g * 8];
#pragma unroll
    for (int nf = 0; nf < 8; ++nf) {
      const int vs = 8 * ((g + nf) & 3);
      const hfrag vb1 = *(const hfrag*)&Vt[0][nf * 16 + lr][vs];
      const hfrag vb2 = *(const hfrag*)&Vt[1][nf * 16 + lr][vs];
      oM[nf] = __builtin_amdgcn_mfma_f32_16x16x32_f16(pa1, vb1, oM[nf], 0, 0, 0);
      oS[nf] = __builtin_amdgcn_mfma_f32_16x16x32_f16(pa1, vb2, oS[nf], 0, 0, 0);
      oS[nf] = __builtin_amdgcn_mfma_f32_16x16x32_f16(pa2, vb1, oS[nf], 0, 0, 0);
    }
  }

  // ---- epilogue ----
  float* Og = O + base + (size_t)(qt * 64 + wave * 16) * DDIM;
#pragma unroll
  for (int r = 0; r < 4; ++r) {
    const float invl = 1.0f / l[r];
    float* orow = Og + (size_t)(g * 4 + r) * DDIM;
#pragma unroll
    for (int nf = 0; nf < 8; ++nf)
      orow[nf * 16 + lr] = (oM[nf][r] + oS[nf][r] * INV2048) * invl;
  }
}

// ---------------------------------------------------------------------------
// Final: y = lif2(f32) + spikes2(u8); LayerNorm; float32 store.
// ---------------------------------------------------------------------------
__global__ __launch_bounds__(256)
void ln_kernel(const float* __restrict__ a, const uint8_t* __restrict__ s8,
               const float* __restrict__ gamma, const float* __restrict__ beta,
               float* __restrict__ out) {
  const int row = blockIdx.x;
  const int tid = threadIdx.x;
  const size_t base = (size_t)row * DDIM;
  const float4 av = *(const float4*)(a + base + tid * 4);
  const uchar4 sv = *(const uchar4*)(s8 + base + tid * 4);
  const float y0 = av.x + (float)sv.x, y1 = av.y + (float)sv.y;
  const float y2 = av.z + (float)sv.z, y3 = av.w + (float)sv.w;
  float s = (y0 + y1) + (y2 + y3);
  float q = (y0 * y0 + y1 * y1) + (y2 * y2 + y3 * y3);
#pragma unroll
  for (int off = 1; off < 64; off <<= 1) {
    s += __shfl_xor(s, off);
    q += __shfl_xor(q, off);
  }
  __shared__ float red[8];
  const int wid = tid >> 6;
  if ((tid & 63) == 0) { red[wid * 2] = s; red[wid * 2 + 1] = q; }
  __syncthreads();
  const float ts = (red[0] + red[2]) + (red[4] + red[6]);
  const float tq = (red[1] + red[3]) + (red[5] + red[7]);
  const float mu  = ts * (1.0f / 1024.0f);
  const float var = tq * (1.0f / 1024.0f) - mu * mu;
  const float rs  = 1.0f / sqrtf(var + 1e-5f);
  const int d = tid * 4;
  const float4 gv  = *(const float4*)(gamma + d);
  const float4 btv = *(const float4*)(beta + d);
  float4 r;
  r.x = (y0 - mu) * rs * gv.x + btv.x;
  r.y = (y1 - mu) * rs * gv.y + btv.y;
  r.z = (y2 - mu) * rs * gv.z + btv.z;
  r.w = (y3 - mu) * rs * gv.w + btv.w;
  *(float4*)(out + base + d) = r;
}

// ---------------------------------------------------------------------------
// Workspace: 4 f32 (A,C,D,E) 67.1 MB + u8 spikes 4.2 MB + B planes 12 MB
// = 83.3 MB. (ws_size >= 83.9 MB proven by R1/R2: that layout produced
// bit-identical correct intermediates.)
// ---------------------------------------------------------------------------
extern "C" void kernel_launch(void* const* d_in, const int* in_sizes, int n_in,
                              void* d_out, int out_size, void* d_ws, size_t ws_size,
                              hipStream_t stream) {
  const float* x       = (const float*)d_in[0];
  const float* context = (const float*)d_in[1];
  const float* Wg  = (const float*)d_in[2];
  const float* bg  = (const float*)d_in[3];
  const float* Wc  = (const float*)d_in[4];
  const float* Wq  = (const float*)d_in[5];
  const float* Wk  = (const float*)d_in[6];
  const float* Wv  = (const float*)d_in[7];
  const float* Wo  = (const float*)d_in[8];
  const float* Wm  = (const float*)d_in[9];
  const float* rWk = (const float*)d_in[10];
  const float* rWv = (const float*)d_in[11];
  const float* rWr = (const float*)d_in[12];
  const float* rWo = (const float*)d_in[13];
  const float* wd  = (const float*)d_in[14];
  const float* uf  = (const float*)d_in[15];
  const float* gamma = (const float*)d_in[16];
  const float* beta  = (const float*)d_in[17];
  float* out = (float*)d_out;   // reference output dtype = float32

  float* w  = (float*)d_ws;
  float*   bA = w;
  float*   bC = w + 1 * NELEM;
  float*   bD = w + 2 * NELEM;
  float*   bE = w + 3 * NELEM;
  uint8_t* bS = (uint8_t*)(w + 4 * NELEM);                          // u8 spikes
  ushort*  pB = (ushort*)((uint8_t*)d_ws + 4 * NELEM * 4 + NELEM);  // B planes

  const dim3 ew(4096);
  constexpr int M1 = 1024 * 1024;   // ushorts per 1024-K plane

  // Stage 1: thalamic gate — single K=2048 GEMM over [x | context]
  cvt_h2t<<<dim3(16, 16, 2), 256, 0, stream>>>(Wg, Wc, nullptr, pB, 0, 1024, 2048);
  gemm_k<0, 0, 2048><<<512, 256, 0, stream>>>(x, nullptr, nullptr, context, pB,
                                              bA, nullptr, nullptr);
  gate_kernel<<<ew, 256, 0, stream>>>(x, bA, bg, bA);
  // Stage 2: LIF -> spikes2 (u8)
  lif_u8_kernel<<<64, 64, 0, stream>>>(bA, bS);
  // Stage 3: spike self-attention — Q,K,V one N-merged launch (shared A)
  cvt_h2t<<<dim3(16, 16, 3), 256, 0, stream>>>(Wq, Wk, Wv, pB, 2 * M1, 0, 1024);
  gemm_k<0, 1, 1024><<<1536, 256, 0, stream>>>(bS, bS, bS, nullptr, pB, bA, bC, bD);
  flash_attn<<<512, 256, 0, stream>>>(bA, bC, bD, bA);
  // Stage 3.5 + 4: Wo (A=attn_out) and Wm (A=context) in ONE launch
  cvt_h2t<<<dim3(16, 16, 2), 256, 0, stream>>>(Wo, Wm, nullptr, pB, 2 * M1, 0, 1024);
  gemm_k<0, 0, 1024><<<1024, 256, 0, stream>>>(bA, context, nullptr, nullptr, pB,
                                               bC, bE, nullptr);
  mod_kernel<<<ew, 256, 0, stream>>>(bC, bE, bD);          // bD = modulated
  // Stage 5: RWKV — k,v,r one 3-way N-merged launch (shared A = bD)
  cvt_h2t<<<dim3(16, 16, 3), 256, 0, stream>>>(rWk, rWv, rWr, pB, 2 * M1, 0, 1024);
  gemm_k<0, 0, 1024><<<1536, 256, 0, stream>>>(bD, bD, bD, nullptr, pB, bA, bC, bE);
  rwkv_kernel<<<64, 64, 0, stream>>>(bA, bC, wd, uf, bA);  // bA = wkv
  rmul_kernel<<<ew, 256, 0, stream>>>(bE, bA, bA);         // bA = sig(r)*wkv
  cvt_h2t<<<dim3(16, 16, 1), 256, 0, stream>>>(rWo, nullptr, nullptr, pB, 0, 0, 1024);
  gemm_k<0, 0, 1024><<<512, 256, 0, stream>>>(bA, nullptr, nullptr, nullptr, pB,
                                              bC, nullptr, nullptr);
  // Stage 6: output LIF (in-place) + residual + LayerNorm
  lif_ip_kernel<<<64, 64, 0, stream>>>(bC);
  ln_kernel<<<4096, 256, 0, stream>>>(bC, bS, gamma, beta, out);
}